// Round 4
// baseline (1877.200 us; speedup 1.0000x reference)
//
#include <hip/hip_runtime.h>
#include <stdint.h>

// ---------------------------------------------------------------------------
// Zorro-style multimodal transformer, B=4, N=1040 (512+512+16 fusion), D=1024,
// H=16, DH=64, L=4, FF=2730 gated-GELU; final LN + 4-token masked pool attn.
// bf16 MFMA GEMMs; block-mask flash attention (contiguous col ranges).
// R5: swapped-operand QK^T attention (S^T = mfma(K,Q)); LDS-free softmax.
// R7: gemm_bt 2-phase pipeline (T3 minimum): double-buffered [2][128x64] LDS
//     tiles, next-tile global_load_lds issued BEFORE current-tile ds_read+MFMA,
//     ONE barrier per BK=64 step. XOR column swizzle (q ^= row&7) applied to
//     pre-swizzled global source + fragment read (LDS dest stays linear).
// R8: identical resubmit (R7 bench was an infra failure, no kernel signal;
//     audit found no crash mechanism — same precedent as R5->R6).
// ---------------------------------------------------------------------------

#define DEV __device__ __forceinline__

typedef unsigned short u16;
typedef __attribute__((ext_vector_type(8))) __bf16 bf16x8;
typedef __attribute__((ext_vector_type(4))) float floatx4;

DEV u16 f2bf(float f) {
  union { float f; unsigned u; } v; v.f = f;
  return (u16)((v.u + 0x7fffu + ((v.u >> 16) & 1u)) >> 16);  // RNE
}
DEV float bf2f(u16 s) {
  union { unsigned u; float f; } v; v.u = ((unsigned)s) << 16;
  return v.f;
}

#define MFMA(a, b, c) __builtin_amdgcn_mfma_f32_16x16x32_bf16(a, b, c, 0, 0, 0)

DEV void gld16(const u16* g, u16* l) {
  __builtin_amdgcn_global_load_lds((__attribute__((address_space(1))) void*)g,
                                   (__attribute__((address_space(3))) void*)l,
                                   16, 0, 0);
}

// V^T column permutation: mfma k-slot (quad,e) holds logical kv
// pi(quad,e) = quad*4 + (e&3) + 16*(e>>2). sigma = pi^-1 maps kv offset j
// (within a 32 block) to its k-slot. Writing V[rb][d] at column
// (rb&~31)|sigma(rb&31) makes PV B-fragments contiguous b128 loads.
DEV int vperm32(int j) {
  return (((j >> 2) & 3) << 3) | (j & 3) | (((j >> 4) & 1) << 2);
}

// ---------------- constants ----------------
#define MREAL 4160   /* B*N = 4*1040 */
#define MPAD  4224   /* 33*128 */
#define NPAD  1056   /* 1040 padded to x32 */
#define FFP   2816   /* 2730 padded to x64 (split-K=2 -> 1408 = 22*64) */
#define FF2P  5632

// ---------------- weight conversion ----------------
// out[n*Kstride + k] = (k < Kin) ? bf16(in[k*N + n]) : 0    (B^T bf16 layout)
__global__ __launch_bounds__(256) void transpose_cvt(
    const float* __restrict__ in, u16* __restrict__ out,
    int Kin, int N, int Kstride) {
  __shared__ float tile[32][33];
  const int k0 = blockIdx.x * 32, n0 = blockIdx.y * 32;
  const int tx = threadIdx.x, ty = threadIdx.y;
#pragma unroll
  for (int i = 0; i < 4; i++) {
    int k = k0 + ty + i * 8;
    tile[ty + i * 8][tx] = (k < Kin) ? in[(int64_t)k * N + n0 + tx] : 0.f;
  }
  __syncthreads();
#pragma unroll
  for (int i = 0; i < 4; i++) {
    int n = n0 + ty + i * 8;
    int k = k0 + tx;
    if (k < Kstride) out[(int64_t)n * Kstride + k] = f2bf(tile[tx][ty + i * 8]);
  }
}

// ff_w1 [1024 x 5460] -> w1T [5632 x 1024] bf16 with val/gate 16-col interleave:
// out row r: vi = (r/32)*16 + r%16 ; gate if (r/16)&1 ; src col = gate? 2730+vi : vi
__global__ __launch_bounds__(256) void transpose_w1(
    const float* __restrict__ in, u16* __restrict__ out) {
  __shared__ float tile[32][33];
  const int k0 = blockIdx.x * 32;        // D dim
  const int r0 = blockIdx.y * 32;        // output-row dim
  const int tx = threadIdx.x, ty = threadIdx.y;
  const int vb = (r0 >> 5) << 4;         // = r0/2
  const int vi = vb + (tx & 15);
  const int c = (tx < 16) ? vi : 2730 + vi;
  const bool valid = vi < 2730;
#pragma unroll
  for (int i = 0; i < 4; i++) {
    int k = k0 + ty + i * 8;
    tile[ty + i * 8][tx] = valid ? in[(int64_t)k * 5460 + c] : 0.f;
  }
  __syncthreads();
#pragma unroll
  for (int i = 0; i < 4; i++) {
    int rl = ty + i * 8;
    out[(int64_t)(r0 + rl) * 1024 + k0 + tx] = f2bf(tile[tx][rl]);
  }
}

// ---------------- tokens assembly ----------------
__global__ __launch_bounds__(256) void build_tokens_k(
    const float* __restrict__ m0p, const float* __restrict__ m1p,
    const float* __restrict__ fus, float* __restrict__ tokens) {
  const int n = blockIdx.x, b = blockIdx.y, t = threadIdx.x;
  const float* src = (n < 512) ? m0p + ((int64_t)b * 512 + n) * 1024
                   : (n < 1024) ? m1p + ((int64_t)b * 512 + (n - 512)) * 1024
                                : fus + (int64_t)(n - 1024) * 1024;
  float4 v = ((const float4*)src)[t];
  ((float4*)(tokens + ((int64_t)b * 1040 + n) * 1024))[t] = v;
}

// ---------------- layernorm (f32 in, bf16 out) ----------------
__global__ __launch_bounds__(256) void ln_k(const float* __restrict__ x,
                                            const float* __restrict__ gamma,
                                            u16* __restrict__ out) {
  const int r = blockIdx.x, t = threadIdx.x;
  const float4 v = ((const float4*)(x + (int64_t)r * 1024))[t];
  float s = v.x + v.y + v.z + v.w;
  float q = v.x * v.x + v.y * v.y + v.z * v.z + v.w * v.w;
#pragma unroll
  for (int off = 32; off >= 1; off >>= 1) {
    s += __shfl_xor(s, off);
    q += __shfl_xor(q, off);
  }
  __shared__ float red[8];
  const int w = t >> 6, l = t & 63;
  if (l == 0) { red[w] = s; red[4 + w] = q; }
  __syncthreads();
  s = red[0] + red[1] + red[2] + red[3];
  q = red[4] + red[5] + red[6] + red[7];
  const float mu = s * (1.f / 1024.f);
  const float var = q * (1.f / 1024.f) - mu * mu;
  const float rs = rsqrtf(var + 1e-5f);
  const float4 g = ((const float4*)gamma)[t];
  u16* op = out + (int64_t)r * 1024 + t * 4;
  op[0] = f2bf((v.x - mu) * rs * g.x);
  op[1] = f2bf((v.y - mu) * rs * g.y);
  op[2] = f2bf((v.z - mu) * rs * g.z);
  op[3] = f2bf((v.w - mu) * rs * g.w);
}

// ---------------- MFMA GEMM: C[M,N] = A[M,K](bf16) @ Bt[N,K](bf16) ----------------
enum { EPI_QKV = 0, EPI_KV = 1, EPI_TOKADD = 2, EPI_GG = 3 };

// Kstr = row stride of A and Bt; per-z K-range = Kstr / gridDim.z (mult of 64).
// 2-phase pipeline: LDS tiles [2][128 rows][64 cols] per operand (64 KiB);
// next K-tile staged via global_load_lds BEFORE the current tile's
// ds_read+MFMA, one __syncthreads per K-step (drains vmcnt+lgkm).
// LDS col swizzle: 16B-column qphys = qlog ^ (row&7), applied by pre-swizzling
// the GLOBAL source column (LDS dest stays wave-linear) and on the read side.
template <int EPI>
__global__ __launch_bounds__(256) void gemm_bt(
    const u16* __restrict__ A, const u16* __restrict__ Bt,
    int Kstr, int Mreal,
    float* __restrict__ tokens, u16* __restrict__ oq, u16* __restrict__ ok,
    u16* __restrict__ ovT, u16* __restrict__ oh2) {
  __shared__ __align__(16) u16 lA[2][128 * 64];
  __shared__ __align__(16) u16 lB[2][128 * 64];
  const int t = threadIdx.x;
  const int w = t >> 6, l = t & 63;
  const int lane16 = l & 15, quad = l >> 4;
  const int m0 = blockIdx.y * 128, n0 = blockIdx.x * 128;
  const int wm = (w >> 1) * 64, wn = (w & 1) * 64;

  const int Klen = Kstr / gridDim.z;
  const int koff = blockIdx.z * Klen;

  const floatx4 fz = {0.f, 0.f, 0.f, 0.f};
  floatx4 acc[4][4];
#pragma unroll
  for (int i = 0; i < 4; i++)
#pragma unroll
    for (int j = 0; j < 4; j++) acc[i][j] = fz;

  // Staging: thread t -> row rowS = t>>3 (+ c*32), 16B col (t&7), pre-swizzled
  // source col so that lds[row][q] = A[row][ (q ^ (row&7))*8 .. +7 ].
  const int rowS = t >> 3;
  const int scol = (((t & 7) ^ (rowS & 7)) << 3);
  const u16* gAs = A + (int64_t)(m0 + rowS) * Kstr + koff + scol;
  const u16* gBs = Bt + (int64_t)(n0 + rowS) * Kstr + koff + scol;
  const int64_t csk = (int64_t)32 * Kstr;

  // Fragment-read swizzled 16B-column offsets (elements):
  const int rsw = lane16 & 7;
  const int cp0 = ((quad ^ rsw) << 3);        // k-substep 0 (k = quad*8)
  const int cp1 = (((quad + 4) ^ rsw) << 3);  // k-substep 1 (k = 32 + quad*8)

  auto stage = [&](int buf, int kt) {
    const u16* ga = gAs + kt;
    const u16* gb = gBs + kt;
    u16* la = &lA[buf][0] + t * 8;
    u16* lb = &lB[buf][0] + t * 8;
#pragma unroll
    for (int c = 0; c < 4; c++) {
      gld16(ga + c * csk, la + c * 2048);
      gld16(gb + c * csk, lb + c * 2048);
    }
  };

  stage(0, 0);
  __syncthreads();
  int cur = 0;
  for (int kt = 0; kt < Klen; kt += 64) {
    if (kt + 64 < Klen) stage(cur ^ 1, kt + 64);
    const u16* la = &lA[cur][0] + (wm + lane16) * 64;
    const u16* lb = &lB[cur][0] + (wn + lane16) * 64;
    bf16x8 af[4], bf[4];
#pragma unroll
    for (int i = 0; i < 4; i++) af[i] = *(const bf16x8*)(la + i * 16 * 64 + cp0);
#pragma unroll
    for (int j = 0; j < 4; j++) bf[j] = *(const bf16x8*)(lb + j * 16 * 64 + cp0);
#pragma unroll
    for (int i = 0; i < 4; i++)
#pragma unroll
      for (int j = 0; j < 4; j++) acc[i][j] = MFMA(af[i], bf[j], acc[i][j]);
#pragma unroll
    for (int i = 0; i < 4; i++) af[i] = *(const bf16x8*)(la + i * 16 * 64 + cp1);
#pragma unroll
    for (int j = 0; j < 4; j++) bf[j] = *(const bf16x8*)(lb + j * 16 * 64 + cp1);
#pragma unroll
    for (int i = 0; i < 4; i++)
#pragma unroll
      for (int j = 0; j < 4; j++) acc[i][j] = MFMA(af[i], bf[j], acc[i][j]);
    __syncthreads();
    cur ^= 1;
  }

  // Epilogues. C-layout: lane holds row = quad*4+reg, col = lane16 within frag.
  if constexpr (EPI == EPI_TOKADD) {
    const bool atomic = gridDim.z > 1;
#pragma unroll
    for (int i = 0; i < 4; i++) {
      const int mb = m0 + wm + i * 16 + quad * 4;
#pragma unroll
      for (int reg = 0; reg < 4; reg++) {
        const int m = mb + reg;
        if (m < Mreal) {
          float* tp = tokens + (int64_t)m * 1024;
#pragma unroll
          for (int j = 0; j < 4; j++) {
            const int n = n0 + wn + j * 16 + lane16;
            if (atomic) atomicAdd(tp + n, acc[i][j][reg]);
            else tp[n] += acc[i][j][reg];
          }
        }
      }
    }
  } else if constexpr (EPI == EPI_QKV) {
    // cols [0,1024): Q (scaled), [1024,2048): K, [2048,3072): V^T (permuted cols)
#pragma unroll
    for (int i = 0; i < 4; i++) {
      const int mb = m0 + wm + i * 16 + quad * 4;
#pragma unroll
      for (int reg = 0; reg < 4; reg++) {
        const int m = mb + reg;
        if (m < Mreal) {
          const int b = m / 1040, rb = m % 1040;
          const int rbp = (rb & ~31) | vperm32(rb & 31);
#pragma unroll
          for (int j = 0; j < 4; j++) {
            const int n = n0 + wn + j * 16 + lane16;
            const float v = acc[i][j][reg];
            if (n < 1024) {
              const int hd = n >> 6, d = n & 63;
              oq[(((int64_t)b * 16 + hd) * NPAD + rb) * 64 + d] = f2bf(v * 0.125f);
            } else if (n < 2048) {
              const int n2 = n - 1024;
              const int hd = n2 >> 6, d = n2 & 63;
              ok[(((int64_t)b * 16 + hd) * NPAD + rb) * 64 + d] = f2bf(v);
            } else {
              const int n2 = n - 2048;
              const int hd = n2 >> 6, d = n2 & 63;
              ovT[(((int64_t)b * 16 + hd) * 64 + d) * NPAD + rbp] = f2bf(v);
            }
          }
        }
      }
    }
  } else if constexpr (EPI == EPI_KV) {
#pragma unroll
    for (int i = 0; i < 4; i++) {
      const int mb = m0 + wm + i * 16 + quad * 4;
#pragma unroll
      for (int reg = 0; reg < 4; reg++) {
        const int m = mb + reg;
        if (m < Mreal) {
          const int b = m / 1040, rb = m % 1040;
          const int rbp = (rb & ~31) | vperm32(rb & 31);
#pragma unroll
          for (int j = 0; j < 4; j++) {
            const int n = n0 + wn + j * 16 + lane16;
            const float v = acc[i][j][reg];
            if (n < 1024) {
              const int hd = n >> 6, d = n & 63;
              ok[(((int64_t)b * 16 + hd) * NPAD + rb) * 64 + d] = f2bf(v);
            } else {
              const int n2 = n - 1024;
              const int hd = n2 >> 6, d = n2 & 63;
              ovT[(((int64_t)b * 16 + hd) * 64 + d) * NPAD + rbp] = f2bf(v);
            }
          }
        }
      }
    }
  } else {  // EPI_GG: cols are (val,gate) alternating 16-groups
#pragma unroll
    for (int i = 0; i < 4; i++) {
      const int mb = m0 + wm + i * 16 + quad * 4;
#pragma unroll
      for (int reg = 0; reg < 4; reg++) {
        const int m = mb + reg;
        u16* hp = oh2 + (int64_t)m * FFP;
#pragma unroll
        for (int j = 0; j < 4; j += 2) {
          const float val = acc[i][j][reg];
          const float g = acc[i][j + 1][reg];
          const float ge = 0.5f * g * (1.f + erff(g * 0.70710678118654752f));
          const int vi = (((n0 + wn + j * 16) >> 5) << 4) + lane16;
          hp[vi] = f2bf(val * ge);
        }
      }
    }
  }
}

// ---------------- block-mask flash attention (swapped QK^T, LDS-free) -------
// S^T = mfma(K, Q): lane (quad,lane16) holds S[kv = c0 + {quad*4+r, 16+quad*4+r}]
// [q = lane16]. Row stats are per-lane; reduce = in-lane tree + shfl_xor(16,32).
// P -> PV A-fragment is a pure register repack (k-slot (quad,e) <-> kv
// pi(quad,e) = quad*4+(e&3)+16*(e>>2)); V^T is stored with sigma=pi^-1
// permuted columns so B-fragments are contiguous b128 loads.
__global__ __launch_bounds__(256) void attn_k(const u16* __restrict__ qb,
                                              const u16* __restrict__ kb,
                                              const u16* __restrict__ vTb,
                                              u16* __restrict__ ao) {
  const int t = threadIdx.x, w = t >> 6, l = t & 63;
  const int lane16 = l & 15, quad = l >> 4;
  const int kvb = quad * 4;
  const int bh = blockIdx.y, b = bh >> 4, h = bh & 15;
  const int row0 = blockIdx.x * 64 + w * 16;
  if (row0 >= 1040) return;
  const int type = (row0 < 512) ? 0 : (row0 < 1024 ? 1 : 2);
  const int cbeg = (type == 1) ? 512 : 0;
  const int cend = (type == 0) ? 512 : (type == 1 ? 1024 : 1040);
  const int niter = (cend - cbeg + 31) >> 5;

  const u16* qp = qb + ((int64_t)bh * NPAD + row0 + lane16) * 64 + quad * 8;
  const bf16x8 a0 = *(const bf16x8*)qp;
  const bf16x8 a1 = *(const bf16x8*)(qp + 32);
  const u16* vbase = vTb + ((int64_t)bh * 64 + lane16) * NPAD + quad * 8;

  const floatx4 fz = {0.f, 0.f, 0.f, 0.f};
  floatx4 O[4] = {fz, fz, fz, fz};
  float mrow = -1e30f, lrow = 0.f;

  for (int it = 0; it < niter; ++it) {
    const int c0 = cbeg + it * 32;
    const u16* kp = kb + ((int64_t)bh * NPAD + c0 + lane16) * 64 + quad * 8;
    const bf16x8 b00 = *(const bf16x8*)kp;
    const bf16x8 b01 = *(const bf16x8*)(kp + 32);
    const bf16x8 b10 = *(const bf16x8*)(kp + 16 * 64);
    const bf16x8 b11 = *(const bf16x8*)(kp + 16 * 64 + 32);
    floatx4 s0 = MFMA(b00, a0, fz); s0 = MFMA(b01, a1, s0);
    floatx4 s1 = MFMA(b10, a0, fz); s1 = MFMA(b11, a1, s1);
    if (c0 + 32 > cend) {  // fusion tail mask (kv >= cend)
#pragma unroll
      for (int r = 0; r < 4; r++) {
        if (c0 + kvb + r >= cend) s0[r] = -1e30f;
        if (c0 + 16 + kvb + r >= cend) s1[r] = -1e30f;
      }
    }
    float tm = fmaxf(fmaxf(fmaxf(s0[0], s0[1]), fmaxf(s0[2], s0[3])),
                     fmaxf(fmaxf(s1[0], s1[1]), fmaxf(s1[2], s1[3])));
    tm = fmaxf(tm, __shfl_xor(tm, 16));
    tm = fmaxf(tm, __shfl_xor(tm, 32));
    if (!__all(tm <= mrow)) {  // exact skip: when taken-not, a_ == 1 exactly
      const float mn = fmaxf(mrow, tm);
      const float a_ = __expf(mrow - mn);
      mrow = mn;
      lrow *= a_;
      const float al0 = __shfl(a_, kvb + 0, 16);
      const float al1 = __shfl(a_, kvb + 1, 16);
      const float al2 = __shfl(a_, kvb + 2, 16);
      const float al3 = __shfl(a_, kvb + 3, 16);
#pragma unroll
      for (int dt = 0; dt < 4; dt++) {
        O[dt][0] *= al0; O[dt][1] *= al1; O[dt][2] *= al2; O[dt][3] *= al3;
      }
    }
    float p0[4], p1[4];
#pragma unroll
    for (int r = 0; r < 4; r++) {
      p0[r] = __expf(s0[r] - mrow);
      p1[r] = __expf(s1[r] - mrow);
    }
    float ps = ((p0[0] + p0[1]) + (p0[2] + p0[3])) +
               ((p1[0] + p1[1]) + (p1[2] + p1[3]));
    ps += __shfl_xor(ps, 16);
    ps += __shfl_xor(ps, 32);
    lrow += ps;
    union { bf16x8 v; u16 s[8]; } pf;
#pragma unroll
    for (int r = 0; r < 4; r++) {
      pf.s[r] = f2bf(p0[r]);
      pf.s[4 + r] = f2bf(p1[r]);
    }
#pragma unroll
    for (int dt = 0; dt < 4; dt++) {
      const bf16x8 bv = *(const bf16x8*)(vbase + (int64_t)dt * 16 * NPAD + c0);
      O[dt] = MFMA(pf.v, bv, O[dt]);
    }
  }
  float lr[4];
#pragma unroll
  for (int r = 0; r < 4; r++) lr[r] = __shfl(lrow, kvb + r, 16);
#pragma unroll
  for (int dt = 0; dt < 4; dt++)
#pragma unroll
    for (int r = 0; r < 4; r++) {
      const int row = row0 + kvb + r;
      ao[((int64_t)b * 1040 + row) * 1024 + h * 64 + dt * 16 + lane16] =
          f2bf(O[dt][r] / lr[r]);
    }
}

// ---------------- pool q: qP[16,1024] = return_tokens @ pool_wq * 0.125 ----------------
// rows 4..15 are zeroed (pool_attn pads q-rows to 16; keeps garbage out of the
// wave-uniform defer-max branch).
__global__ __launch_bounds__(256) void poolq_k(const float* __restrict__ rtk,
                                               const float* __restrict__ pwq,
                                               u16* __restrict__ qP) {
  const int r = blockIdx.y;
  const int n = blockIdx.x * 256 + threadIdx.x;
  if (r >= 4) { qP[(int64_t)r * 1024 + n] = 0; return; }
  const float* x = rtk + (int64_t)r * 1024;
  float acc = 0.f;
#pragma unroll 8
  for (int k = 0; k < 1024; k++) acc += x[k] * pwq[(int64_t)k * 1024 + n];
  qP[(int64_t)r * 1024 + n] = f2bf(acc * 0.125f);
}

// ---------------- pool attention: 1 wave per (b,h), 4 real q-rows ----------------
DEV bool pvalid(int r, int c) {
  if (r == 0) return c < 512;
  if (r == 1) return (c >= 512) && (c < 1024);
  if (r == 2) return (c >= 1024) && (c < 1040);
  return c < 1040;  // GLOBAL row + pad rows
}

__global__ __launch_bounds__(64) void pool_attn_k(const u16* __restrict__ qP,
                                                  const u16* __restrict__ kb,
                                                  const u16* __restrict__ vTb,
                                                  u16* __restrict__ po) {
  const int l = threadIdx.x;
  const int lane16 = l & 15, quad = l >> 4;
  const int kvb = quad * 4;
  const int bh = blockIdx.x, b = bh >> 4, h = bh & 15;
  const u16* qp = qP + (int64_t)lane16 * 1024 + h * 64 + quad * 8;
  const bf16x8 a0 = *(const bf16x8*)qp;
  const bf16x8 a1 = *(const bf16x8*)(qp + 32);
  const u16* vbase = vTb + ((int64_t)bh * 64 + lane16) * NPAD + quad * 8;
  const floatx4 fz = {0.f, 0.f, 0.f, 0.f};
  floatx4 O[4] = {fz, fz, fz, fz};
  float mrow = -1e30f, lrow = 0.f;
  for (int it = 0; it < 33; ++it) {
    const int c0 = it * 32;
    const u16* kp = kb + ((int64_t)bh * NPAD + c0 + lane16) * 64 + quad * 8;
    const bf16x8 b00 = *(const bf16x8*)kp;
    const bf16x8 b01 = *(const bf16x8*)(kp + 32);
    const bf16x8 b10 = *(const bf16x8*)(kp + 16 * 64);
    const bf16x8 b11 = *(const bf16x8*)(kp + 16 * 64 + 32);
    floatx4 s0 = MFMA(b00, a0, fz); s0 = MFMA(b01, a1, s0);
    floatx4 s1 = MFMA(b10, a0, fz); s1 = MFMA(b11, a1, s1);
#pragma unroll
    for (int r = 0; r < 4; r++) {
      if (!pvalid(lane16, c0 + kvb + r)) s0[r] = -1e30f;
      if (!pvalid(lane16, c0 + 16 + kvb + r)) s1[r] = -1e30f;
    }
    float tm = fmaxf(fmaxf(fmaxf(s0[0], s0[1]), fmaxf(s0[2], s0[3])),
                     fmaxf(fmaxf(s1[0], s1[1]), fmaxf(s1[2], s1[3])));
    tm = fmaxf(tm, __shfl_xor(tm, 16));
    tm = fmaxf(tm, __shfl_xor(tm, 32));
    if (!__all(tm <= mrow)) {
      const float mn = fmaxf(mrow, tm);
      const float a_ = __expf(mrow - mn);
      mrow = mn;
      lrow *= a_;
      const float al0 = __shfl(a_, kvb + 0, 16);
      const float al1 = __shfl(a_, kvb + 1, 16);
      const float al2 = __shfl(a_, kvb + 2, 16);
      const float al3 = __shfl(a_, kvb + 3, 16);
#pragma unroll
      for (int dt = 0; dt < 4; dt++) {
        O[dt][0] *= al0; O[dt][1] *= al1; O[dt][2] *= al2; O[dt][3] *= al3;
      }
    }
    float p0[4], p1[4];
#pragma unroll
    for (int r = 0; r < 4; r++) {
      p0[r] = __expf(s0[r] - mrow);
      p1[r] = __expf(s1[r] - mrow);
    }
    float ps = ((p0[0] + p0[1]) + (p0[2] + p0[3])) +
               ((p1[0] + p1[1]) + (p1[2] + p1[3]));
    ps += __shfl_xor(ps, 16);
    ps += __shfl_xor(ps, 32);
    lrow += ps;
    union { bf16x8 v; u16 s[8]; } pf;
#pragma unroll
    for (int r = 0; r < 4; r++) {
      pf.s[r] = f2bf(p0[r]);
      pf.s[4 + r] = f2bf(p1[r]);
    }
#pragma unroll
    for (int dt = 0; dt < 4; dt++) {
      const bf16x8 bv = *(const bf16x8*)(vbase + (int64_t)dt * 16 * NPAD + c0);
      O[dt] = MFMA(pf.v, bv, O[dt]);
    }
  }
  float lr[4];
#pragma unroll
  for (int r = 0; r < 4; r++) lr[r] = __shfl(lrow, r, 16);
  if (quad == 0) {  // output C rows quad*4+reg -> quad0 holds real rows 0..3
#pragma unroll
    for (int dt = 0; dt < 4; dt++)
#pragma unroll
      for (int r = 0; r < 4; r++)
        po[((int64_t)b * 4 + r) * 1024 + h * 64 + dt * 16 + lane16] =
            f2bf(O[dt][r] / lr[r]);
  }
}

// ---------------- final: out = poolO @ pool_wo + return_tokens ----------------
__global__ __launch_bounds__(256) void fout_k(const u16* __restrict__ po,
                                              const float* __restrict__ pwo,
                                              const float* __restrict__ rtk,
                                              float* __restrict__ out) {
  const int row = blockIdx.y;  // b*4 + r, 0..15
  const int n = blockIdx.x * 256 + threadIdx.x;
  const u16* x = po + (int64_t)row * 1024;
  float acc = 0.f;
#pragma unroll 8
  for (int k = 0; k < 1024; k++) acc += bf2f(x[k]) * pwo[(int64_t)k * 1024 + n];
  out[(int64_t)row * 1024 + n] = acc + rtk[(int64_t)(row & 3) * 1024 + n];
}

// ---------------------------------------------------------------------------
extern "C" void kernel_launch(void* const* d_in, const int* in_sizes, int n_in,
                              void* d_out, int out_size, void* d_ws, size_t ws_size,
                              hipStream_t stream) {
  (void)in_sizes; (void)n_in; (void)out_size; (void)ws_size;
  const float* m0p  = (const float*)d_in[0];
  const float* m1p  = (const float*)d_in[1];
  const float* fus  = (const float*)d_in[2];
  const float* rtk  = (const float*)d_in[3];
  const float* lng  = (const float*)d_in[4];
  const float* wq   = (const float*)d_in[5];
  const float* wkv  = (const float*)d_in[6];
  const float* wo   = (const float*)d_in[7];
  const float* w1   = (const float*)d_in[8];
  const float* w2   = (const float*)d_in[9];
  const float* pwq  = (const float*)d_in[10];
  const float* pwkv = (const float*)d_in[11];
  const float* pwo  = (const float*)d_in[12];
  const float* fg   = (const float*)d_in[13];
  float* out = (float*)d_out;

  char* p = (char*)d_ws;
  auto alloc = [&](size_t bytes) -> char* {
    char* r = p;
    p += (bytes + 255) & ~(size_t)255;
    return r;
  };
  // Total footprint ~64 MB.
  u16* warena = (u16*)alloc((size_t)FF2P * 1024 * 2);       // 11.5 MB, per-GEMM weights
  float* tokens = (float*)alloc((size_t)MREAL * 1024 * 4);  // 17.04 MB
  u16* hbuf  = (u16*)alloc((size_t)MPAD * 1024 * 2);        // 8.65 MB (LN out + attn out)
  u16* qb    = (u16*)alloc((size_t)64 * NPAD * 64 * 2);     // 8.65 MB
  u16* kbuf  = (u16*)alloc((size_t)64 * NPAD * 64 * 2);     // 8.65 MB
  u16* vTbuf = (u16*)alloc((size_t)64 * NPAD * 64 * 2);     // 8.65 MB
  u16* h2buf = qb;  // 23.8 MB alias over qb+kbuf+vTbuf (25.95 MB): dead between
                    // attn read and next layer's Q/KV writes; stale k/vT tail
                    // rows [1040,1056) are masked (-1e30) / multiplied by p=0.
  u16* qP    = (u16*)alloc((size_t)16 * 1024 * 2);
  u16* poolO = (u16*)alloc((size_t)16 * 1024 * 2);

  const dim3 tb(32, 8, 1);
  build_tokens_k<<<dim3(1040, 4), 256, 0, stream>>>(m0p, m1p, fus, tokens);

  for (int lyr = 0; lyr < 4; ++lyr) {
    ln_k<<<MREAL, 256, 0, stream>>>(tokens, lng + lyr * 1024, hbuf);
    // Merged QKV weight: arena rows [0,1024)=wq^T, [1024,3072)=wkv^T
    transpose_cvt<<<dim3(32, 32), tb, 0, stream>>>(
        wq + (int64_t)lyr * 1024 * 1024, warena, 1024, 1024, 1024);
    transpose_cvt<<<dim3(32, 64), tb, 0, stream>>>(
        wkv + (int64_t)lyr * 1024 * 2048, warena + (size_t)1024 * 1024, 1024, 2048, 1024);
    gemm_bt<EPI_QKV><<<dim3(24, 33), 256, 0, stream>>>(
        hbuf, warena, 1024, MREAL, nullptr, qb, kbuf, vTbuf, nullptr);
    attn_k<<<dim3(17, 64), 256, 0, stream>>>(qb, kbuf, vTbuf, hbuf);
    transpose_cvt<<<dim3(32, 32), tb, 0, stream>>>(
        wo + (int64_t)lyr * 1024 * 1024, warena, 1024, 1024, 1024);
    gemm_bt<EPI_TOKADD><<<dim3(8, 33, 2), 256, 0, stream>>>(
        hbuf, warena, 1024, MREAL, tokens, nullptr, nullptr, nullptr, nullptr);
    ln_k<<<MREAL, 256, 0, stream>>>(tokens, lng + lyr * 1024, hbuf);
    transpose_w1<<<dim3(32, FF2P / 32), tb, 0, stream>>>(
        w1 + (int64_t)lyr * 1024 * 5460, warena);
    gemm_bt<EPI_GG><<<dim3(FF2P / 128, 33), 256, 0, stream>>>(
        hbuf, warena, 1024, MREAL, nullptr, nullptr, nullptr, nullptr, h2buf);
    transpose_cvt<<<dim3(FFP / 32, 32), tb, 0, stream>>>(
        w2 + (int64_t)lyr * 2730 * 1024, warena, 2730, 1024, FFP);
    gemm_bt<EPI_TOKADD><<<dim3(8, 33, 2), 256, 0, stream>>>(
        h2buf, warena, FFP, MREAL, tokens, nullptr, nullptr, nullptr, nullptr);
  }

  ln_k<<<MREAL, 256, 0, stream>>>(tokens, fg, hbuf);
  transpose_cvt<<<dim3(32, 64), tb, 0, stream>>>(pwkv, warena, 1024, 2048, 1024);
  gemm_bt<EPI_KV><<<dim3(16, 33), 256, 0, stream>>>(
      hbuf, warena, 1024, MREAL, nullptr, nullptr, kbuf, vTbuf, nullptr);
  poolq_k<<<dim3(4, 16), 256, 0, stream>>>(rtk, pwq, qP);
  pool_attn_k<<<64, 64, 0, stream>>>(qP, kbuf, vTbuf, poolO);
  fout_k<<<dim3(4, 16), 256, 0, stream>>>(poolO, pwo, rtk, out);
}

// Round 6
// 1801.662 us; speedup vs baseline: 1.0419x; 1.0419x over previous
//
#include <hip/hip_runtime.h>
#include <stdint.h>

// ---------------------------------------------------------------------------
// Zorro-style multimodal transformer, B=4, N=1040 (512+512+16 fusion), D=1024,
// H=16, DH=64, L=4, FF=2730 gated-GELU; final LN + 4-token masked pool attn.
// bf16 MFMA GEMMs; block-mask flash attention (contiguous col ranges).
// R5: swapped-operand QK^T attention (S^T = mfma(K,Q)); LDS-free softmax.
// R7: gemm_bt 2-phase pipeline: double-buffered [2][128x64] LDS tiles, XOR
//     column swizzle both-sides (bank conflicts 2.97M -> 0, verified R8).
// R9: kill the atomic residual epilogue (R8 PMC: top kernels are TOKADD
//     gemms, WRITE=34MB tokens-RMW, 8.6M device-scope atomicAdds/dispatch,
//     all pipes <22% -> atomic serialization is the unbilled cost).
//     EPI_DELTA: per-z plain f32 delta stores (no atomics, no tokens fetch);
//     add_ln_k fuses tokens += d0(+d1) with the LN that always follows.
//     Workspace-guarded (mode 0 = legacy atomic path if ws too small).
// R10: identical resubmit (R9 bench was the recurring first-submit infra
//     flake; audit found no crash mechanism — precedent R5->R6, R7->R8).
// ---------------------------------------------------------------------------

#define DEV __device__ __forceinline__

typedef unsigned short u16;
typedef __attribute__((ext_vector_type(8))) __bf16 bf16x8;
typedef __attribute__((ext_vector_type(4))) float floatx4;

DEV u16 f2bf(float f) {
  union { float f; unsigned u; } v; v.f = f;
  return (u16)((v.u + 0x7fffu + ((v.u >> 16) & 1u)) >> 16);  // RNE
}
DEV float bf2f(u16 s) {
  union { unsigned u; float f; } v; v.u = ((unsigned)s) << 16;
  return v.f;
}

#define MFMA(a, b, c) __builtin_amdgcn_mfma_f32_16x16x32_bf16(a, b, c, 0, 0, 0)

DEV void gld16(const u16* g, u16* l) {
  __builtin_amdgcn_global_load_lds((__attribute__((address_space(1))) void*)g,
                                   (__attribute__((address_space(3))) void*)l,
                                   16, 0, 0);
}

// V^T column permutation: mfma k-slot (quad,e) holds logical kv
// pi(quad,e) = quad*4 + (e&3) + 16*(e>>2). sigma = pi^-1 maps kv offset j
// (within a 32 block) to its k-slot. Writing V[rb][d] at column
// (rb&~31)|sigma(rb&31) makes PV B-fragments contiguous b128 loads.
DEV int vperm32(int j) {
  return (((j >> 2) & 3) << 3) | (j & 3) | (((j >> 4) & 1) << 2);
}

// ---------------- constants ----------------
#define MREAL 4160   /* B*N = 4*1040 */
#define MPAD  4224   /* 33*128 */
#define NPAD  1056   /* 1040 padded to x32 */
#define FFP   2816   /* 2730 padded to x64 (split-K=2 -> 1408 = 22*64) */
#define FF2P  5632

// ---------------- weight conversion ----------------
// out[n*Kstride + k] = (k < Kin) ? bf16(in[k*N + n]) : 0    (B^T bf16 layout)
__global__ __launch_bounds__(256) void transpose_cvt(
    const float* __restrict__ in, u16* __restrict__ out,
    int Kin, int N, int Kstride) {
  __shared__ float tile[32][33];
  const int k0 = blockIdx.x * 32, n0 = blockIdx.y * 32;
  const int tx = threadIdx.x, ty = threadIdx.y;
#pragma unroll
  for (int i = 0; i < 4; i++) {
    int k = k0 + ty + i * 8;
    tile[ty + i * 8][tx] = (k < Kin) ? in[(int64_t)k * N + n0 + tx] : 0.f;
  }
  __syncthreads();
#pragma unroll
  for (int i = 0; i < 4; i++) {
    int n = n0 + ty + i * 8;
    int k = k0 + tx;
    if (k < Kstride) out[(int64_t)n * Kstride + k] = f2bf(tile[tx][ty + i * 8]);
  }
}

// ff_w1 [1024 x 5460] -> w1T [5632 x 1024] bf16 with val/gate 16-col interleave:
// out row r: vi = (r/32)*16 + r%16 ; gate if (r/16)&1 ; src col = gate? 2730+vi : vi
__global__ __launch_bounds__(256) void transpose_w1(
    const float* __restrict__ in, u16* __restrict__ out) {
  __shared__ float tile[32][33];
  const int k0 = blockIdx.x * 32;        // D dim
  const int r0 = blockIdx.y * 32;        // output-row dim
  const int tx = threadIdx.x, ty = threadIdx.y;
  const int vb = (r0 >> 5) << 4;         // = r0/2
  const int vi = vb + (tx & 15);
  const int c = (tx < 16) ? vi : 2730 + vi;
  const bool valid = vi < 2730;
#pragma unroll
  for (int i = 0; i < 4; i++) {
    int k = k0 + ty + i * 8;
    tile[ty + i * 8][tx] = valid ? in[(int64_t)k * 5460 + c] : 0.f;
  }
  __syncthreads();
#pragma unroll
  for (int i = 0; i < 4; i++) {
    int rl = ty + i * 8;
    out[(int64_t)(r0 + rl) * 1024 + k0 + tx] = f2bf(tile[tx][rl]);
  }
}

// ---------------- tokens assembly ----------------
__global__ __launch_bounds__(256) void build_tokens_k(
    const float* __restrict__ m0p, const float* __restrict__ m1p,
    const float* __restrict__ fus, float* __restrict__ tokens) {
  const int n = blockIdx.x, b = blockIdx.y, t = threadIdx.x;
  const float* src = (n < 512) ? m0p + ((int64_t)b * 512 + n) * 1024
                   : (n < 1024) ? m1p + ((int64_t)b * 512 + (n - 512)) * 1024
                                : fus + (int64_t)(n - 1024) * 1024;
  float4 v = ((const float4*)src)[t];
  ((float4*)(tokens + ((int64_t)b * 1040 + n) * 1024))[t] = v;
}

// ---------------- layernorm (f32 in, bf16 out) ----------------
__global__ __launch_bounds__(256) void ln_k(const float* __restrict__ x,
                                            const float* __restrict__ gamma,
                                            u16* __restrict__ out) {
  const int r = blockIdx.x, t = threadIdx.x;
  const float4 v = ((const float4*)(x + (int64_t)r * 1024))[t];
  float s = v.x + v.y + v.z + v.w;
  float q = v.x * v.x + v.y * v.y + v.z * v.z + v.w * v.w;
#pragma unroll
  for (int off = 32; off >= 1; off >>= 1) {
    s += __shfl_xor(s, off);
    q += __shfl_xor(q, off);
  }
  __shared__ float red[8];
  const int w = t >> 6, l = t & 63;
  if (l == 0) { red[w] = s; red[4 + w] = q; }
  __syncthreads();
  s = red[0] + red[1] + red[2] + red[3];
  q = red[4] + red[5] + red[6] + red[7];
  const float mu = s * (1.f / 1024.f);
  const float var = q * (1.f / 1024.f) - mu * mu;
  const float rs = rsqrtf(var + 1e-5f);
  const float4 g = ((const float4*)gamma)[t];
  u16* op = out + (int64_t)r * 1024 + t * 4;
  op[0] = f2bf((v.x - mu) * rs * g.x);
  op[1] = f2bf((v.y - mu) * rs * g.y);
  op[2] = f2bf((v.z - mu) * rs * g.z);
  op[3] = f2bf((v.w - mu) * rs * g.w);
}

// ---------------- fused residual-add + layernorm ----------------
// tokens += d0 (+ d1); optionally write tokens back; LN(tokens)*gamma -> out.
__global__ __launch_bounds__(256) void add_ln_k(
    float* __restrict__ x, const float* __restrict__ d0,
    const float* __restrict__ d1, const float* __restrict__ gamma,
    u16* __restrict__ out, int two, int writeback) {
  const int r = blockIdx.x, t = threadIdx.x;
  const int64_t off = (int64_t)r * 1024 + t * 4;
  float4 v = *(const float4*)(x + off);
  {
    const float4 a = *(const float4*)(d0 + off);
    v.x += a.x; v.y += a.y; v.z += a.z; v.w += a.w;
  }
  if (two) {
    const float4 a = *(const float4*)(d1 + off);
    v.x += a.x; v.y += a.y; v.z += a.z; v.w += a.w;
  }
  if (writeback) *(float4*)(x + off) = v;
  float s = v.x + v.y + v.z + v.w;
  float q = v.x * v.x + v.y * v.y + v.z * v.z + v.w * v.w;
#pragma unroll
  for (int off2 = 32; off2 >= 1; off2 >>= 1) {
    s += __shfl_xor(s, off2);
    q += __shfl_xor(q, off2);
  }
  __shared__ float red[8];
  const int w = t >> 6, l = t & 63;
  if (l == 0) { red[w] = s; red[4 + w] = q; }
  __syncthreads();
  s = red[0] + red[1] + red[2] + red[3];
  q = red[4] + red[5] + red[6] + red[7];
  const float mu = s * (1.f / 1024.f);
  const float var = q * (1.f / 1024.f) - mu * mu;
  const float rs = rsqrtf(var + 1e-5f);
  const float4 g = ((const float4*)gamma)[t];
  u16* op = out + (int64_t)r * 1024 + t * 4;
  op[0] = f2bf((v.x - mu) * rs * g.x);
  op[1] = f2bf((v.y - mu) * rs * g.y);
  op[2] = f2bf((v.z - mu) * rs * g.z);
  op[3] = f2bf((v.w - mu) * rs * g.w);
}

// ---------------- MFMA GEMM: C[M,N] = A[M,K](bf16) @ Bt[N,K](bf16) ----------------
enum { EPI_QKV = 0, EPI_KV = 1, EPI_TOKADD = 2, EPI_GG = 3, EPI_DELTA = 4 };

// Kstr = row stride of A and Bt; per-z K-range = Kstr / gridDim.z (mult of 64).
// 2-phase pipeline: LDS tiles [2][128 rows][64 cols] per operand (64 KiB);
// next K-tile staged via global_load_lds BEFORE the current tile's
// ds_read+MFMA, one __syncthreads per K-step (drains vmcnt+lgkm).
// LDS col swizzle: 16B-column qphys = qlog ^ (row&7), applied by pre-swizzling
// the GLOBAL source column (LDS dest stays wave-linear) and on the read side.
template <int EPI>
__global__ __launch_bounds__(256) void gemm_bt(
    const u16* __restrict__ A, const u16* __restrict__ Bt,
    int Kstr, int Mreal,
    float* __restrict__ tokens, u16* __restrict__ oq, u16* __restrict__ ok,
    u16* __restrict__ ovT, u16* __restrict__ oh2) {
  __shared__ __align__(16) u16 lA[2][128 * 64];
  __shared__ __align__(16) u16 lB[2][128 * 64];
  const int t = threadIdx.x;
  const int w = t >> 6, l = t & 63;
  const int lane16 = l & 15, quad = l >> 4;
  const int m0 = blockIdx.y * 128, n0 = blockIdx.x * 128;
  const int wm = (w >> 1) * 64, wn = (w & 1) * 64;

  const int Klen = Kstr / gridDim.z;
  const int koff = blockIdx.z * Klen;

  const floatx4 fz = {0.f, 0.f, 0.f, 0.f};
  floatx4 acc[4][4];
#pragma unroll
  for (int i = 0; i < 4; i++)
#pragma unroll
    for (int j = 0; j < 4; j++) acc[i][j] = fz;

  // Staging: thread t -> row rowS = t>>3 (+ c*32), 16B col (t&7), pre-swizzled
  // source col so that lds[row][q] = A[row][ (q ^ (row&7))*8 .. +7 ].
  const int rowS = t >> 3;
  const int scol = (((t & 7) ^ (rowS & 7)) << 3);
  const u16* gAs = A + (int64_t)(m0 + rowS) * Kstr + koff + scol;
  const u16* gBs = Bt + (int64_t)(n0 + rowS) * Kstr + koff + scol;
  const int64_t csk = (int64_t)32 * Kstr;

  // Fragment-read swizzled 16B-column offsets (elements):
  const int rsw = lane16 & 7;
  const int cp0 = ((quad ^ rsw) << 3);        // k-substep 0 (k = quad*8)
  const int cp1 = (((quad + 4) ^ rsw) << 3);  // k-substep 1 (k = 32 + quad*8)

  auto stage = [&](int buf, int kt) {
    const u16* ga = gAs + kt;
    const u16* gb = gBs + kt;
    u16* la = &lA[buf][0] + t * 8;
    u16* lb = &lB[buf][0] + t * 8;
#pragma unroll
    for (int c = 0; c < 4; c++) {
      gld16(ga + c * csk, la + c * 2048);
      gld16(gb + c * csk, lb + c * 2048);
    }
  };

  stage(0, 0);
  __syncthreads();
  int cur = 0;
  for (int kt = 0; kt < Klen; kt += 64) {
    if (kt + 64 < Klen) stage(cur ^ 1, kt + 64);
    const u16* la = &lA[cur][0] + (wm + lane16) * 64;
    const u16* lb = &lB[cur][0] + (wn + lane16) * 64;
    bf16x8 af[4], bf[4];
#pragma unroll
    for (int i = 0; i < 4; i++) af[i] = *(const bf16x8*)(la + i * 16 * 64 + cp0);
#pragma unroll
    for (int j = 0; j < 4; j++) bf[j] = *(const bf16x8*)(lb + j * 16 * 64 + cp0);
#pragma unroll
    for (int i = 0; i < 4; i++)
#pragma unroll
      for (int j = 0; j < 4; j++) acc[i][j] = MFMA(af[i], bf[j], acc[i][j]);
#pragma unroll
    for (int i = 0; i < 4; i++) af[i] = *(const bf16x8*)(la + i * 16 * 64 + cp1);
#pragma unroll
    for (int j = 0; j < 4; j++) bf[j] = *(const bf16x8*)(lb + j * 16 * 64 + cp1);
#pragma unroll
    for (int i = 0; i < 4; i++)
#pragma unroll
      for (int j = 0; j < 4; j++) acc[i][j] = MFMA(af[i], bf[j], acc[i][j]);
    __syncthreads();
    cur ^= 1;
  }

  // Epilogues. C-layout: lane holds row = quad*4+reg, col = lane16 within frag.
  if constexpr (EPI == EPI_TOKADD) {
    const bool atomic = gridDim.z > 1;
#pragma unroll
    for (int i = 0; i < 4; i++) {
      const int mb = m0 + wm + i * 16 + quad * 4;
#pragma unroll
      for (int reg = 0; reg < 4; reg++) {
        const int m = mb + reg;
        if (m < Mreal) {
          float* tp = tokens + (int64_t)m * 1024;
#pragma unroll
          for (int j = 0; j < 4; j++) {
            const int n = n0 + wn + j * 16 + lane16;
            if (atomic) atomicAdd(tp + n, acc[i][j][reg]);
            else tp[n] += acc[i][j][reg];
          }
        }
      }
    }
  } else if constexpr (EPI == EPI_DELTA) {
    // Plain f32 partial-sum store into per-z delta buffer (no atomics).
    float* dp = tokens + (int64_t)blockIdx.z * MREAL * 1024;
#pragma unroll
    for (int i = 0; i < 4; i++) {
      const int mb = m0 + wm + i * 16 + quad * 4;
#pragma unroll
      for (int reg = 0; reg < 4; reg++) {
        const int m = mb + reg;
        if (m < Mreal) {
          float* tp = dp + (int64_t)m * 1024;
#pragma unroll
          for (int j = 0; j < 4; j++) {
            const int n = n0 + wn + j * 16 + lane16;
            tp[n] = acc[i][j][reg];
          }
        }
      }
    }
  } else if constexpr (EPI == EPI_QKV) {
    // cols [0,1024): Q (scaled), [1024,2048): K, [2048,3072): V^T (permuted cols)
#pragma unroll
    for (int i = 0; i < 4; i++) {
      const int mb = m0 + wm + i * 16 + quad * 4;
#pragma unroll
      for (int reg = 0; reg < 4; reg++) {
        const int m = mb + reg;
        if (m < Mreal) {
          const int b = m / 1040, rb = m % 1040;
          const int rbp = (rb & ~31) | vperm32(rb & 31);
#pragma unroll
          for (int j = 0; j < 4; j++) {
            const int n = n0 + wn + j * 16 + lane16;
            const float v = acc[i][j][reg];
            if (n < 1024) {
              const int hd = n >> 6, d = n & 63;
              oq[(((int64_t)b * 16 + hd) * NPAD + rb) * 64 + d] = f2bf(v * 0.125f);
            } else if (n < 2048) {
              const int n2 = n - 1024;
              const int hd = n2 >> 6, d = n2 & 63;
              ok[(((int64_t)b * 16 + hd) * NPAD + rb) * 64 + d] = f2bf(v);
            } else {
              const int n2 = n - 2048;
              const int hd = n2 >> 6, d = n2 & 63;
              ovT[(((int64_t)b * 16 + hd) * 64 + d) * NPAD + rbp] = f2bf(v);
            }
          }
        }
      }
    }
  } else if constexpr (EPI == EPI_KV) {
#pragma unroll
    for (int i = 0; i < 4; i++) {
      const int mb = m0 + wm + i * 16 + quad * 4;
#pragma unroll
      for (int reg = 0; reg < 4; reg++) {
        const int m = mb + reg;
        if (m < Mreal) {
          const int b = m / 1040, rb = m % 1040;
          const int rbp = (rb & ~31) | vperm32(rb & 31);
#pragma unroll
          for (int j = 0; j < 4; j++) {
            const int n = n0 + wn + j * 16 + lane16;
            const float v = acc[i][j][reg];
            if (n < 1024) {
              const int hd = n >> 6, d = n & 63;
              ok[(((int64_t)b * 16 + hd) * NPAD + rb) * 64 + d] = f2bf(v);
            } else {
              const int n2 = n - 1024;
              const int hd = n2 >> 6, d = n2 & 63;
              ovT[(((int64_t)b * 16 + hd) * 64 + d) * NPAD + rbp] = f2bf(v);
            }
          }
        }
      }
    }
  } else {  // EPI_GG: cols are (val,gate) alternating 16-groups
#pragma unroll
    for (int i = 0; i < 4; i++) {
      const int mb = m0 + wm + i * 16 + quad * 4;
#pragma unroll
      for (int reg = 0; reg < 4; reg++) {
        const int m = mb + reg;
        u16* hp = oh2 + (int64_t)m * FFP;
#pragma unroll
        for (int j = 0; j < 4; j += 2) {
          const float val = acc[i][j][reg];
          const float g = acc[i][j + 1][reg];
          const float ge = 0.5f * g * (1.f + erff(g * 0.70710678118654752f));
          const int vi = (((n0 + wn + j * 16) >> 5) << 4) + lane16;
          hp[vi] = f2bf(val * ge);
        }
      }
    }
  }
}

// ---------------- block-mask flash attention (swapped QK^T, LDS-free) -------
// S^T = mfma(K, Q): lane (quad,lane16) holds S[kv = c0 + {quad*4+r, 16+quad*4+r}]
// [q = lane16]. Row stats are per-lane; reduce = in-lane tree + shfl_xor(16,32).
// P -> PV A-fragment is a pure register repack (k-slot (quad,e) <-> kv
// pi(quad,e) = quad*4+(e&3)+16*(e>>2)); V^T is stored with sigma=pi^-1
// permuted columns so B-fragments are contiguous b128 loads.
__global__ __launch_bounds__(256) void attn_k(const u16* __restrict__ qb,
                                              const u16* __restrict__ kb,
                                              const u16* __restrict__ vTb,
                                              u16* __restrict__ ao) {
  const int t = threadIdx.x, w = t >> 6, l = t & 63;
  const int lane16 = l & 15, quad = l >> 4;
  const int kvb = quad * 4;
  const int bh = blockIdx.y, b = bh >> 4, h = bh & 15;
  const int row0 = blockIdx.x * 64 + w * 16;
  if (row0 >= 1040) return;
  const int type = (row0 < 512) ? 0 : (row0 < 1024 ? 1 : 2);
  const int cbeg = (type == 1) ? 512 : 0;
  const int cend = (type == 0) ? 512 : (type == 1 ? 1024 : 1040);
  const int niter = (cend - cbeg + 31) >> 5;

  const u16* qp = qb + ((int64_t)bh * NPAD + row0 + lane16) * 64 + quad * 8;
  const bf16x8 a0 = *(const bf16x8*)qp;
  const bf16x8 a1 = *(const bf16x8*)(qp + 32);
  const u16* vbase = vTb + ((int64_t)bh * 64 + lane16) * NPAD + quad * 8;

  const floatx4 fz = {0.f, 0.f, 0.f, 0.f};
  floatx4 O[4] = {fz, fz, fz, fz};
  float mrow = -1e30f, lrow = 0.f;

  for (int it = 0; it < niter; ++it) {
    const int c0 = cbeg + it * 32;
    const u16* kp = kb + ((int64_t)bh * NPAD + c0 + lane16) * 64 + quad * 8;
    const bf16x8 b00 = *(const bf16x8*)kp;
    const bf16x8 b01 = *(const bf16x8*)(kp + 32);
    const bf16x8 b10 = *(const bf16x8*)(kp + 16 * 64);
    const bf16x8 b11 = *(const bf16x8*)(kp + 16 * 64 + 32);
    floatx4 s0 = MFMA(b00, a0, fz); s0 = MFMA(b01, a1, s0);
    floatx4 s1 = MFMA(b10, a0, fz); s1 = MFMA(b11, a1, s1);
    if (c0 + 32 > cend) {  // fusion tail mask (kv >= cend)
#pragma unroll
      for (int r = 0; r < 4; r++) {
        if (c0 + kvb + r >= cend) s0[r] = -1e30f;
        if (c0 + 16 + kvb + r >= cend) s1[r] = -1e30f;
      }
    }
    float tm = fmaxf(fmaxf(fmaxf(s0[0], s0[1]), fmaxf(s0[2], s0[3])),
                     fmaxf(fmaxf(s1[0], s1[1]), fmaxf(s1[2], s1[3])));
    tm = fmaxf(tm, __shfl_xor(tm, 16));
    tm = fmaxf(tm, __shfl_xor(tm, 32));
    if (!__all(tm <= mrow)) {  // exact skip: when taken-not, a_ == 1 exactly
      const float mn = fmaxf(mrow, tm);
      const float a_ = __expf(mrow - mn);
      mrow = mn;
      lrow *= a_;
      const float al0 = __shfl(a_, kvb + 0, 16);
      const float al1 = __shfl(a_, kvb + 1, 16);
      const float al2 = __shfl(a_, kvb + 2, 16);
      const float al3 = __shfl(a_, kvb + 3, 16);
#pragma unroll
      for (int dt = 0; dt < 4; dt++) {
        O[dt][0] *= al0; O[dt][1] *= al1; O[dt][2] *= al2; O[dt][3] *= al3;
      }
    }
    float p0[4], p1[4];
#pragma unroll
    for (int r = 0; r < 4; r++) {
      p0[r] = __expf(s0[r] - mrow);
      p1[r] = __expf(s1[r] - mrow);
    }
    float ps = ((p0[0] + p0[1]) + (p0[2] + p0[3])) +
               ((p1[0] + p1[1]) + (p1[2] + p1[3]));
    ps += __shfl_xor(ps, 16);
    ps += __shfl_xor(ps, 32);
    lrow += ps;
    union { bf16x8 v; u16 s[8]; } pf;
#pragma unroll
    for (int r = 0; r < 4; r++) {
      pf.s[r] = f2bf(p0[r]);
      pf.s[4 + r] = f2bf(p1[r]);
    }
#pragma unroll
    for (int dt = 0; dt < 4; dt++) {
      const bf16x8 bv = *(const bf16x8*)(vbase + (int64_t)dt * 16 * NPAD + c0);
      O[dt] = MFMA(pf.v, bv, O[dt]);
    }
  }
  float lr[4];
#pragma unroll
  for (int r = 0; r < 4; r++) lr[r] = __shfl(lrow, kvb + r, 16);
#pragma unroll
  for (int dt = 0; dt < 4; dt++)
#pragma unroll
    for (int r = 0; r < 4; r++) {
      const int row = row0 + kvb + r;
      ao[((int64_t)b * 1040 + row) * 1024 + h * 64 + dt * 16 + lane16] =
          f2bf(O[dt][r] / lr[r]);
    }
}

// ---------------- pool q: qP[16,1024] = return_tokens @ pool_wq * 0.125 ----------------
// rows 4..15 are zeroed (pool_attn pads q-rows to 16; keeps garbage out of the
// wave-uniform defer-max branch).
__global__ __launch_bounds__(256) void poolq_k(const float* __restrict__ rtk,
                                               const float* __restrict__ pwq,
                                               u16* __restrict__ qP) {
  const int r = blockIdx.y;
  const int n = blockIdx.x * 256 + threadIdx.x;
  if (r >= 4) { qP[(int64_t)r * 1024 + n] = 0; return; }
  const float* x = rtk + (int64_t)r * 1024;
  float acc = 0.f;
#pragma unroll 8
  for (int k = 0; k < 1024; k++) acc += x[k] * pwq[(int64_t)k * 1024 + n];
  qP[(int64_t)r * 1024 + n] = f2bf(acc * 0.125f);
}

// ---------------- pool attention: 1 wave per (b,h), 4 real q-rows ----------------
DEV bool pvalid(int r, int c) {
  if (r == 0) return c < 512;
  if (r == 1) return (c >= 512) && (c < 1024);
  if (r == 2) return (c >= 1024) && (c < 1040);
  return c < 1040;  // GLOBAL row + pad rows
}

__global__ __launch_bounds__(64) void pool_attn_k(const u16* __restrict__ qP,
                                                  const u16* __restrict__ kb,
                                                  const u16* __restrict__ vTb,
                                                  u16* __restrict__ po) {
  const int l = threadIdx.x;
  const int lane16 = l & 15, quad = l >> 4;
  const int kvb = quad * 4;
  const int bh = blockIdx.x, b = bh >> 4, h = bh & 15;
  const u16* qp = qP + (int64_t)lane16 * 1024 + h * 64 + quad * 8;
  const bf16x8 a0 = *(const bf16x8*)qp;
  const bf16x8 a1 = *(const bf16x8*)(qp + 32);
  const u16* vbase = vTb + ((int64_t)bh * 64 + lane16) * NPAD + quad * 8;
  const floatx4 fz = {0.f, 0.f, 0.f, 0.f};
  floatx4 O[4] = {fz, fz, fz, fz};
  float mrow = -1e30f, lrow = 0.f;
  for (int it = 0; it < 33; ++it) {
    const int c0 = it * 32;
    const u16* kp = kb + ((int64_t)bh * NPAD + c0 + lane16) * 64 + quad * 8;
    const bf16x8 b00 = *(const bf16x8*)kp;
    const bf16x8 b01 = *(const bf16x8*)(kp + 32);
    const bf16x8 b10 = *(const bf16x8*)(kp + 16 * 64);
    const bf16x8 b11 = *(const bf16x8*)(kp + 16 * 64 + 32);
    floatx4 s0 = MFMA(b00, a0, fz); s0 = MFMA(b01, a1, s0);
    floatx4 s1 = MFMA(b10, a0, fz); s1 = MFMA(b11, a1, s1);
#pragma unroll
    for (int r = 0; r < 4; r++) {
      if (!pvalid(lane16, c0 + kvb + r)) s0[r] = -1e30f;
      if (!pvalid(lane16, c0 + 16 + kvb + r)) s1[r] = -1e30f;
    }
    float tm = fmaxf(fmaxf(fmaxf(s0[0], s0[1]), fmaxf(s0[2], s0[3])),
                     fmaxf(fmaxf(s1[0], s1[1]), fmaxf(s1[2], s1[3])));
    tm = fmaxf(tm, __shfl_xor(tm, 16));
    tm = fmaxf(tm, __shfl_xor(tm, 32));
    if (!__all(tm <= mrow)) {
      const float mn = fmaxf(mrow, tm);
      const float a_ = __expf(mrow - mn);
      mrow = mn;
      lrow *= a_;
      const float al0 = __shfl(a_, kvb + 0, 16);
      const float al1 = __shfl(a_, kvb + 1, 16);
      const float al2 = __shfl(a_, kvb + 2, 16);
      const float al3 = __shfl(a_, kvb + 3, 16);
#pragma unroll
      for (int dt = 0; dt < 4; dt++) {
        O[dt][0] *= al0; O[dt][1] *= al1; O[dt][2] *= al2; O[dt][3] *= al3;
      }
    }
    float p0[4], p1[4];
#pragma unroll
    for (int r = 0; r < 4; r++) {
      p0[r] = __expf(s0[r] - mrow);
      p1[r] = __expf(s1[r] - mrow);
    }
    float ps = ((p0[0] + p0[1]) + (p0[2] + p0[3])) +
               ((p1[0] + p1[1]) + (p1[2] + p1[3]));
    ps += __shfl_xor(ps, 16);
    ps += __shfl_xor(ps, 32);
    lrow += ps;
    union { bf16x8 v; u16 s[8]; } pf;
#pragma unroll
    for (int r = 0; r < 4; r++) {
      pf.s[r] = f2bf(p0[r]);
      pf.s[4 + r] = f2bf(p1[r]);
    }
#pragma unroll
    for (int dt = 0; dt < 4; dt++) {
      const bf16x8 bv = *(const bf16x8*)(vbase + (int64_t)dt * 16 * NPAD + c0);
      O[dt] = MFMA(pf.v, bv, O[dt]);
    }
  }
  float lr[4];
#pragma unroll
  for (int r = 0; r < 4; r++) lr[r] = __shfl(lrow, r, 16);
  if (quad == 0) {  // output C rows quad*4+reg -> quad0 holds real rows 0..3
#pragma unroll
    for (int dt = 0; dt < 4; dt++)
#pragma unroll
      for (int r = 0; r < 4; r++)
        po[((int64_t)b * 4 + r) * 1024 + h * 64 + dt * 16 + lane16] =
            f2bf(O[dt][r] / lr[r]);
  }
}

// ---------------- final: out = poolO @ pool_wo + return_tokens ----------------
__global__ __launch_bounds__(256) void fout_k(const u16* __restrict__ po,
                                              const float* __restrict__ pwo,
                                              const float* __restrict__ rtk,
                                              float* __restrict__ out) {
  const int row = blockIdx.y;  // b*4 + r, 0..15
  const int n = blockIdx.x * 256 + threadIdx.x;
  const u16* x = po + (int64_t)row * 1024;
  float acc = 0.f;
#pragma unroll 8
  for (int k = 0; k < 1024; k++) acc += bf2f(x[k]) * pwo[(int64_t)k * 1024 + n];
  out[(int64_t)row * 1024 + n] = acc + rtk[(int64_t)(row & 3) * 1024 + n];
}

// ---------------------------------------------------------------------------
extern "C" void kernel_launch(void* const* d_in, const int* in_sizes, int n_in,
                              void* d_out, int out_size, void* d_ws, size_t ws_size,
                              hipStream_t stream) {
  (void)in_sizes; (void)n_in; (void)out_size;
  const float* m0p  = (const float*)d_in[0];
  const float* m1p  = (const float*)d_in[1];
  const float* fus  = (const float*)d_in[2];
  const float* rtk  = (const float*)d_in[3];
  const float* lng  = (const float*)d_in[4];
  const float* wq   = (const float*)d_in[5];
  const float* wkv  = (const float*)d_in[6];
  const float* wo   = (const float*)d_in[7];
  const float* w1   = (const float*)d_in[8];
  const float* w2   = (const float*)d_in[9];
  const float* pwq  = (const float*)d_in[10];
  const float* pwkv = (const float*)d_in[11];
  const float* pwo  = (const float*)d_in[12];
  const float* fg   = (const float*)d_in[13];
  float* out = (float*)d_out;

  char* p = (char*)d_ws;
  auto alloc = [&](size_t bytes) -> char* {
    char* r = p;
    p += (bytes + 255) & ~(size_t)255;
    return r;
  };
  // Base footprint ~63.3 MB (identical layout to R8).
  u16* warena = (u16*)alloc((size_t)FF2P * 1024 * 2);       // 11.5 MB, per-GEMM weights
  float* tokens = (float*)alloc((size_t)MREAL * 1024 * 4);  // 17.04 MB
  u16* hbuf  = (u16*)alloc((size_t)MPAD * 1024 * 2);        // 8.65 MB (LN out + attn out)
  u16* qb    = (u16*)alloc((size_t)64 * NPAD * 64 * 2);     // 8.65 MB
  u16* kbuf  = (u16*)alloc((size_t)64 * NPAD * 64 * 2);     // 8.65 MB
  u16* vTbuf = (u16*)alloc((size_t)64 * NPAD * 64 * 2);     // 8.65 MB
  u16* h2buf = qb;  // 23.8 MB alias over qb+kbuf+vTbuf (25.95 MB): dead between
                    // attn read and next layer's Q/KV writes; stale k/vT tail
                    // rows [1040,1056) are masked (-1e30) / multiplied by p=0.
  u16* qP    = (u16*)alloc((size_t)16 * 1024 * 2);
  u16* poolO = (u16*)alloc((size_t)16 * 1024 * 2);

  // Residual-delta buffers (mode 2: two z-slices; mode 1: one; mode 0: legacy
  // atomic path). Chosen by available workspace — no risk if ws is tight.
  const size_t DELTA_BYTES = (size_t)MREAL * 1024 * 4;  // 17.04 MB
  const size_t base_used = (size_t)(p - (char*)d_ws);
  int mode = 0;
  float* d0 = nullptr;
  float* d1 = nullptr;
  if (ws_size >= base_used + 2 * DELTA_BYTES + 1024) {
    mode = 2;
    d0 = (float*)alloc(2 * DELTA_BYTES);
    d1 = d0 + (size_t)MREAL * 1024;  // contiguous: blockIdx.z indexes it
  } else if (ws_size >= base_used + DELTA_BYTES + 1024) {
    mode = 1;
    d0 = (float*)alloc(DELTA_BYTES);
    d1 = d0;  // unused (two=0)
  }

  const dim3 tb(32, 8, 1);
  build_tokens_k<<<dim3(1040, 4), 256, 0, stream>>>(m0p, m1p, fus, tokens);

  if (mode) {
    const int zz = mode;  // split-K factor for residual GEMMs
    const int two = (mode == 2);
    for (int lyr = 0; lyr < 4; ++lyr) {
      if (lyr == 0)
        ln_k<<<MREAL, 256, 0, stream>>>(tokens, lng, hbuf);
      else  // fold previous layer's FF2 delta into tokens + this pre-attn LN
        add_ln_k<<<MREAL, 256, 0, stream>>>(tokens, d0, d1, lng + lyr * 1024,
                                            hbuf, two, 1);
      transpose_cvt<<<dim3(32, 32), tb, 0, stream>>>(
          wq + (int64_t)lyr * 1024 * 1024, warena, 1024, 1024, 1024);
      transpose_cvt<<<dim3(32, 64), tb, 0, stream>>>(
          wkv + (int64_t)lyr * 1024 * 2048, warena + (size_t)1024 * 1024, 1024, 2048, 1024);
      gemm_bt<EPI_QKV><<<dim3(24, 33), 256, 0, stream>>>(
          hbuf, warena, 1024, MREAL, nullptr, qb, kbuf, vTbuf, nullptr);
      attn_k<<<dim3(17, 64), 256, 0, stream>>>(qb, kbuf, vTbuf, hbuf);
      transpose_cvt<<<dim3(32, 32), tb, 0, stream>>>(
          wo + (int64_t)lyr * 1024 * 1024, warena, 1024, 1024, 1024);
      gemm_bt<EPI_DELTA><<<dim3(8, 33, zz), 256, 0, stream>>>(
          hbuf, warena, 1024, MREAL, d0, nullptr, nullptr, nullptr, nullptr);
      add_ln_k<<<MREAL, 256, 0, stream>>>(tokens, d0, d1, lng + lyr * 1024,
                                          hbuf, two, 1);
      transpose_w1<<<dim3(32, FF2P / 32), tb, 0, stream>>>(
          w1 + (int64_t)lyr * 1024 * 5460, warena);
      gemm_bt<EPI_GG><<<dim3(FF2P / 128, 33), 256, 0, stream>>>(
          hbuf, warena, 1024, MREAL, nullptr, nullptr, nullptr, nullptr, h2buf);
      transpose_cvt<<<dim3(FFP / 32, 32), tb, 0, stream>>>(
          w2 + (int64_t)lyr * 2730 * 1024, warena, 2730, 1024, FFP);
      gemm_bt<EPI_DELTA><<<dim3(8, 33, zz), 256, 0, stream>>>(
          h2buf, warena, FFP, MREAL, d0, nullptr, nullptr, nullptr, nullptr);
    }
    // final: fold last FF2 delta + final LN (tokens dead after -> no writeback)
    add_ln_k<<<MREAL, 256, 0, stream>>>(tokens, d0, d1, fg, hbuf, two, 0);
  } else {
    for (int lyr = 0; lyr < 4; ++lyr) {
      ln_k<<<MREAL, 256, 0, stream>>>(tokens, lng + lyr * 1024, hbuf);
      transpose_cvt<<<dim3(32, 32), tb, 0, stream>>>(
          wq + (int64_t)lyr * 1024 * 1024, warena, 1024, 1024, 1024);
      transpose_cvt<<<dim3(32, 64), tb, 0, stream>>>(
          wkv + (int64_t)lyr * 1024 * 2048, warena + (size_t)1024 * 1024, 1024, 2048, 1024);
      gemm_bt<EPI_QKV><<<dim3(24, 33), 256, 0, stream>>>(
          hbuf, warena, 1024, MREAL, nullptr, qb, kbuf, vTbuf, nullptr);
      attn_k<<<dim3(17, 64), 256, 0, stream>>>(qb, kbuf, vTbuf, hbuf);
      transpose_cvt<<<dim3(32, 32), tb, 0, stream>>>(
          wo + (int64_t)lyr * 1024 * 1024, warena, 1024, 1024, 1024);
      gemm_bt<EPI_TOKADD><<<dim3(8, 33, 2), 256, 0, stream>>>(
          hbuf, warena, 1024, MREAL, tokens, nullptr, nullptr, nullptr, nullptr);
      ln_k<<<MREAL, 256, 0, stream>>>(tokens, lng + lyr * 1024, hbuf);
      transpose_w1<<<dim3(32, FF2P / 32), tb, 0, stream>>>(
          w1 + (int64_t)lyr * 1024 * 5460, warena);
      gemm_bt<EPI_GG><<<dim3(FF2P / 128, 33), 256, 0, stream>>>(
          hbuf, warena, 1024, MREAL, nullptr, nullptr, nullptr, nullptr, h2buf);
      transpose_cvt<<<dim3(FFP / 32, 32), tb, 0, stream>>>(
          w2 + (int64_t)lyr * 2730 * 1024, warena, 2730, 1024, FFP);
      gemm_bt<EPI_TOKADD><<<dim3(8, 33, 2), 256, 0, stream>>>(
          h2buf, warena, FFP, MREAL, tokens, nullptr, nullptr, nullptr, nullptr);
    }
    ln_k<<<MREAL, 256, 0, stream>>>(tokens, fg, hbuf);
  }

  transpose_cvt<<<dim3(32, 64), tb, 0, stream>>>(pwkv, warena, 1024, 2048, 1024);
  gemm_bt<EPI_KV><<<dim3(16, 33), 256, 0, stream>>>(
      hbuf, warena, 1024, MREAL, nullptr, nullptr, kbuf, vTbuf, nullptr);
  poolq_k<<<dim3(4, 16), 256, 0, stream>>>(rtk, pwq, qP);
  pool_attn_k<<<64, 64, 0, stream>>>(qP, kbuf, vTbuf, poolO);
  fout_k<<<dim3(4, 16), 256, 0, stream>>>(poolO, pwo, rtk, out);
}

// Round 7
// 1766.537 us; speedup vs baseline: 1.0626x; 1.0199x over previous
//
#include <hip/hip_runtime.h>
#include <stdint.h>

// ---------------------------------------------------------------------------
// Zorro-style multimodal transformer, B=4, N=1040 (512+512+16 fusion), D=1024,
// H=16, DH=64, L=4, FF=2730 gated-GELU; final LN + 4-token masked pool attn.
// bf16 MFMA GEMMs; block-mask flash attention (contiguous col ranges).
// R5: swapped-operand QK^T attention (S^T = mfma(K,Q)); LDS-free softmax.
// R7: gemm_bt 2-phase pipeline: double-buffered [2][128x64] LDS tiles, XOR
//     column swizzle both-sides (bank conflicts 2.97M -> 0, verified R8).
// R9: EPI_DELTA + add_ln_k kill the atomic residual epilogue (-75 us).
// R11: grouped block-order remap (G=4 supertiles) in gemm_bt. R10 PMC:
//     top GEMMs at 102us with ALL pipes idle (Mfma 10%, VALU 12%, HBM 8%)
//     and R4/R7 occupancy+pipeline changes null -> bound is panel re-read
//     traffic (FF1: 760 MB logical) thrashing per-XCD L2 and riding the
//     ~10-15 TB/s L3. Supertile order shrinks per-XCD working set to <4MB
//     L2 -> ~4x less L3 traffic. Pure bijective index remap, no sync change.
// ---------------------------------------------------------------------------

#define DEV __device__ __forceinline__

typedef unsigned short u16;
typedef __attribute__((ext_vector_type(8))) __bf16 bf16x8;
typedef __attribute__((ext_vector_type(4))) float floatx4;

DEV u16 f2bf(float f) {
  union { float f; unsigned u; } v; v.f = f;
  return (u16)((v.u + 0x7fffu + ((v.u >> 16) & 1u)) >> 16);  // RNE
}
DEV float bf2f(u16 s) {
  union { unsigned u; float f; } v; v.u = ((unsigned)s) << 16;
  return v.f;
}

#define MFMA(a, b, c) __builtin_amdgcn_mfma_f32_16x16x32_bf16(a, b, c, 0, 0, 0)

DEV void gld16(const u16* g, u16* l) {
  __builtin_amdgcn_global_load_lds((__attribute__((address_space(1))) void*)g,
                                   (__attribute__((address_space(3))) void*)l,
                                   16, 0, 0);
}

// V^T column permutation: mfma k-slot (quad,e) holds logical kv
// pi(quad,e) = quad*4 + (e&3) + 16*(e>>2). sigma = pi^-1 maps kv offset j
// (within a 32 block) to its k-slot. Writing V[rb][d] at column
// (rb&~31)|sigma(rb&31) makes PV B-fragments contiguous b128 loads.
DEV int vperm32(int j) {
  return (((j >> 2) & 3) << 3) | (j & 3) | (((j >> 4) & 1) << 2);
}

// ---------------- constants ----------------
#define MREAL 4160   /* B*N = 4*1040 */
#define MPAD  4224   /* 33*128 */
#define NPAD  1056   /* 1040 padded to x32 */
#define FFP   2816   /* 2730 padded to x64 (split-K=2 -> 1408 = 22*64) */
#define FF2P  5632

// ---------------- weight conversion ----------------
// out[n*Kstride + k] = (k < Kin) ? bf16(in[k*N + n]) : 0    (B^T bf16 layout)
__global__ __launch_bounds__(256) void transpose_cvt(
    const float* __restrict__ in, u16* __restrict__ out,
    int Kin, int N, int Kstride) {
  __shared__ float tile[32][33];
  const int k0 = blockIdx.x * 32, n0 = blockIdx.y * 32;
  const int tx = threadIdx.x, ty = threadIdx.y;
#pragma unroll
  for (int i = 0; i < 4; i++) {
    int k = k0 + ty + i * 8;
    tile[ty + i * 8][tx] = (k < Kin) ? in[(int64_t)k * N + n0 + tx] : 0.f;
  }
  __syncthreads();
#pragma unroll
  for (int i = 0; i < 4; i++) {
    int n = n0 + ty + i * 8;
    int k = k0 + tx;
    if (k < Kstride) out[(int64_t)n * Kstride + k] = f2bf(tile[tx][ty + i * 8]);
  }
}

// ff_w1 [1024 x 5460] -> w1T [5632 x 1024] bf16 with val/gate 16-col interleave:
// out row r: vi = (r/32)*16 + r%16 ; gate if (r/16)&1 ; src col = gate? 2730+vi : vi
__global__ __launch_bounds__(256) void transpose_w1(
    const float* __restrict__ in, u16* __restrict__ out) {
  __shared__ float tile[32][33];
  const int k0 = blockIdx.x * 32;        // D dim
  const int r0 = blockIdx.y * 32;        // output-row dim
  const int tx = threadIdx.x, ty = threadIdx.y;
  const int vb = (r0 >> 5) << 4;         // = r0/2
  const int vi = vb + (tx & 15);
  const int c = (tx < 16) ? vi : 2730 + vi;
  const bool valid = vi < 2730;
#pragma unroll
  for (int i = 0; i < 4; i++) {
    int k = k0 + ty + i * 8;
    tile[ty + i * 8][tx] = valid ? in[(int64_t)k * 5460 + c] : 0.f;
  }
  __syncthreads();
#pragma unroll
  for (int i = 0; i < 4; i++) {
    int rl = ty + i * 8;
    out[(int64_t)(r0 + rl) * 1024 + k0 + tx] = f2bf(tile[tx][rl]);
  }
}

// ---------------- tokens assembly ----------------
__global__ __launch_bounds__(256) void build_tokens_k(
    const float* __restrict__ m0p, const float* __restrict__ m1p,
    const float* __restrict__ fus, float* __restrict__ tokens) {
  const int n = blockIdx.x, b = blockIdx.y, t = threadIdx.x;
  const float* src = (n < 512) ? m0p + ((int64_t)b * 512 + n) * 1024
                   : (n < 1024) ? m1p + ((int64_t)b * 512 + (n - 512)) * 1024
                                : fus + (int64_t)(n - 1024) * 1024;
  float4 v = ((const float4*)src)[t];
  ((float4*)(tokens + ((int64_t)b * 1040 + n) * 1024))[t] = v;
}

// ---------------- layernorm (f32 in, bf16 out) ----------------
__global__ __launch_bounds__(256) void ln_k(const float* __restrict__ x,
                                            const float* __restrict__ gamma,
                                            u16* __restrict__ out) {
  const int r = blockIdx.x, t = threadIdx.x;
  const float4 v = ((const float4*)(x + (int64_t)r * 1024))[t];
  float s = v.x + v.y + v.z + v.w;
  float q = v.x * v.x + v.y * v.y + v.z * v.z + v.w * v.w;
#pragma unroll
  for (int off = 32; off >= 1; off >>= 1) {
    s += __shfl_xor(s, off);
    q += __shfl_xor(q, off);
  }
  __shared__ float red[8];
  const int w = t >> 6, l = t & 63;
  if (l == 0) { red[w] = s; red[4 + w] = q; }
  __syncthreads();
  s = red[0] + red[1] + red[2] + red[3];
  q = red[4] + red[5] + red[6] + red[7];
  const float mu = s * (1.f / 1024.f);
  const float var = q * (1.f / 1024.f) - mu * mu;
  const float rs = rsqrtf(var + 1e-5f);
  const float4 g = ((const float4*)gamma)[t];
  u16* op = out + (int64_t)r * 1024 + t * 4;
  op[0] = f2bf((v.x - mu) * rs * g.x);
  op[1] = f2bf((v.y - mu) * rs * g.y);
  op[2] = f2bf((v.z - mu) * rs * g.z);
  op[3] = f2bf((v.w - mu) * rs * g.w);
}

// ---------------- fused residual-add + layernorm ----------------
// tokens += d0 (+ d1); optionally write tokens back; LN(tokens)*gamma -> out.
__global__ __launch_bounds__(256) void add_ln_k(
    float* __restrict__ x, const float* __restrict__ d0,
    const float* __restrict__ d1, const float* __restrict__ gamma,
    u16* __restrict__ out, int two, int writeback) {
  const int r = blockIdx.x, t = threadIdx.x;
  const int64_t off = (int64_t)r * 1024 + t * 4;
  float4 v = *(const float4*)(x + off);
  {
    const float4 a = *(const float4*)(d0 + off);
    v.x += a.x; v.y += a.y; v.z += a.z; v.w += a.w;
  }
  if (two) {
    const float4 a = *(const float4*)(d1 + off);
    v.x += a.x; v.y += a.y; v.z += a.z; v.w += a.w;
  }
  if (writeback) *(float4*)(x + off) = v;
  float s = v.x + v.y + v.z + v.w;
  float q = v.x * v.x + v.y * v.y + v.z * v.z + v.w * v.w;
#pragma unroll
  for (int off2 = 32; off2 >= 1; off2 >>= 1) {
    s += __shfl_xor(s, off2);
    q += __shfl_xor(q, off2);
  }
  __shared__ float red[8];
  const int w = t >> 6, l = t & 63;
  if (l == 0) { red[w] = s; red[4 + w] = q; }
  __syncthreads();
  s = red[0] + red[1] + red[2] + red[3];
  q = red[4] + red[5] + red[6] + red[7];
  const float mu = s * (1.f / 1024.f);
  const float var = q * (1.f / 1024.f) - mu * mu;
  const float rs = rsqrtf(var + 1e-5f);
  const float4 g = ((const float4*)gamma)[t];
  u16* op = out + (int64_t)r * 1024 + t * 4;
  op[0] = f2bf((v.x - mu) * rs * g.x);
  op[1] = f2bf((v.y - mu) * rs * g.y);
  op[2] = f2bf((v.z - mu) * rs * g.z);
  op[3] = f2bf((v.w - mu) * rs * g.w);
}

// ---------------- MFMA GEMM: C[M,N] = A[M,K](bf16) @ Bt[N,K](bf16) ----------------
enum { EPI_QKV = 0, EPI_KV = 1, EPI_TOKADD = 2, EPI_GG = 3, EPI_DELTA = 4 };

// Kstr = row stride of A and Bt; per-z K-range = Kstr / gridDim.z (mult of 64).
// 2-phase pipeline: LDS tiles [2][128 rows][64 cols] per operand (64 KiB);
// next K-tile staged via global_load_lds BEFORE the current tile's
// ds_read+MFMA, one __syncthreads per K-step (drains vmcnt+lgkm).
// LDS col swizzle: 16B-column qphys = qlog ^ (row&7), applied by pre-swizzling
// the GLOBAL source column (LDS dest stays wave-linear) and on the read side.
// R11 block-order remap: linear wg id -> (bx,by) in supertiles of G=4
// B-panels x all M-rows, so concurrently-resident blocks share a small
// panel working set that fits per-XCD L2 (4 MB).
template <int EPI>
__global__ __launch_bounds__(256) void gemm_bt(
    const u16* __restrict__ A, const u16* __restrict__ Bt,
    int Kstr, int Mreal,
    float* __restrict__ tokens, u16* __restrict__ oq, u16* __restrict__ ok,
    u16* __restrict__ ovT, u16* __restrict__ oh2) {
  __shared__ __align__(16) u16 lA[2][128 * 64];
  __shared__ __align__(16) u16 lB[2][128 * 64];
  const int t = threadIdx.x;
  const int w = t >> 6, l = t & 63;
  const int lane16 = l & 15, quad = l >> 4;

  // ---- grouped block-order remap (bijective) ----
  const int nbx = gridDim.x, nby = gridDim.y;
  const int lin = blockIdx.y * nbx + blockIdx.x;
  const int ngf = nbx >> 2;            // full groups of G=4
  const int base = ngf * 4 * nby;
  int bx, by;
  if (lin < base) {
    const int g = lin / (nby * 4);
    const int r = lin - g * nby * 4;
    bx = (g << 2) + (r & 3);
    by = r >> 2;
  } else {  // tail group (nbx % 4 != 0) — unused for our shapes, kept safe
    const int W = nbx - (ngf << 2);
    const int r = lin - base;
    bx = (ngf << 2) + r % W;
    by = r / W;
  }
  const int m0 = by * 128, n0 = bx * 128;
  const int wm = (w >> 1) * 64, wn = (w & 1) * 64;

  const int Klen = Kstr / gridDim.z;
  const int koff = blockIdx.z * Klen;

  const floatx4 fz = {0.f, 0.f, 0.f, 0.f};
  floatx4 acc[4][4];
#pragma unroll
  for (int i = 0; i < 4; i++)
#pragma unroll
    for (int j = 0; j < 4; j++) acc[i][j] = fz;

  // Staging: thread t -> row rowS = t>>3 (+ c*32), 16B col (t&7), pre-swizzled
  // source col so that lds[row][q] = A[row][ (q ^ (row&7))*8 .. +7 ].
  const int rowS = t >> 3;
  const int scol = (((t & 7) ^ (rowS & 7)) << 3);
  const u16* gAs = A + (int64_t)(m0 + rowS) * Kstr + koff + scol;
  const u16* gBs = Bt + (int64_t)(n0 + rowS) * Kstr + koff + scol;
  const int64_t csk = (int64_t)32 * Kstr;

  // Fragment-read swizzled 16B-column offsets (elements):
  const int rsw = lane16 & 7;
  const int cp0 = ((quad ^ rsw) << 3);        // k-substep 0 (k = quad*8)
  const int cp1 = (((quad + 4) ^ rsw) << 3);  // k-substep 1 (k = 32 + quad*8)

  auto stage = [&](int buf, int kt) {
    const u16* ga = gAs + kt;
    const u16* gb = gBs + kt;
    u16* la = &lA[buf][0] + t * 8;
    u16* lb = &lB[buf][0] + t * 8;
#pragma unroll
    for (int c = 0; c < 4; c++) {
      gld16(ga + c * csk, la + c * 2048);
      gld16(gb + c * csk, lb + c * 2048);
    }
  };

  stage(0, 0);
  __syncthreads();
  int cur = 0;
  for (int kt = 0; kt < Klen; kt += 64) {
    if (kt + 64 < Klen) stage(cur ^ 1, kt + 64);
    const u16* la = &lA[cur][0] + (wm + lane16) * 64;
    const u16* lb = &lB[cur][0] + (wn + lane16) * 64;
    bf16x8 af[4], bf[4];
#pragma unroll
    for (int i = 0; i < 4; i++) af[i] = *(const bf16x8*)(la + i * 16 * 64 + cp0);
#pragma unroll
    for (int j = 0; j < 4; j++) bf[j] = *(const bf16x8*)(lb + j * 16 * 64 + cp0);
#pragma unroll
    for (int i = 0; i < 4; i++)
#pragma unroll
      for (int j = 0; j < 4; j++) acc[i][j] = MFMA(af[i], bf[j], acc[i][j]);
#pragma unroll
    for (int i = 0; i < 4; i++) af[i] = *(const bf16x8*)(la + i * 16 * 64 + cp1);
#pragma unroll
    for (int j = 0; j < 4; j++) bf[j] = *(const bf16x8*)(lb + j * 16 * 64 + cp1);
#pragma unroll
    for (int i = 0; i < 4; i++)
#pragma unroll
      for (int j = 0; j < 4; j++) acc[i][j] = MFMA(af[i], bf[j], acc[i][j]);
    __syncthreads();
    cur ^= 1;
  }

  // Epilogues. C-layout: lane holds row = quad*4+reg, col = lane16 within frag.
  if constexpr (EPI == EPI_TOKADD) {
    const bool atomic = gridDim.z > 1;
#pragma unroll
    for (int i = 0; i < 4; i++) {
      const int mb = m0 + wm + i * 16 + quad * 4;
#pragma unroll
      for (int reg = 0; reg < 4; reg++) {
        const int m = mb + reg;
        if (m < Mreal) {
          float* tp = tokens + (int64_t)m * 1024;
#pragma unroll
          for (int j = 0; j < 4; j++) {
            const int n = n0 + wn + j * 16 + lane16;
            if (atomic) atomicAdd(tp + n, acc[i][j][reg]);
            else tp[n] += acc[i][j][reg];
          }
        }
      }
    }
  } else if constexpr (EPI == EPI_DELTA) {
    // Plain f32 partial-sum store into per-z delta buffer (no atomics).
    float* dp = tokens + (int64_t)blockIdx.z * MREAL * 1024;
#pragma unroll
    for (int i = 0; i < 4; i++) {
      const int mb = m0 + wm + i * 16 + quad * 4;
#pragma unroll
      for (int reg = 0; reg < 4; reg++) {
        const int m = mb + reg;
        if (m < Mreal) {
          float* tp = dp + (int64_t)m * 1024;
#pragma unroll
          for (int j = 0; j < 4; j++) {
            const int n = n0 + wn + j * 16 + lane16;
            tp[n] = acc[i][j][reg];
          }
        }
      }
    }
  } else if constexpr (EPI == EPI_QKV) {
    // cols [0,1024): Q (scaled), [1024,2048): K, [2048,3072): V^T (permuted cols)
#pragma unroll
    for (int i = 0; i < 4; i++) {
      const int mb = m0 + wm + i * 16 + quad * 4;
#pragma unroll
      for (int reg = 0; reg < 4; reg++) {
        const int m = mb + reg;
        if (m < Mreal) {
          const int b = m / 1040, rb = m % 1040;
          const int rbp = (rb & ~31) | vperm32(rb & 31);
#pragma unroll
          for (int j = 0; j < 4; j++) {
            const int n = n0 + wn + j * 16 + lane16;
            const float v = acc[i][j][reg];
            if (n < 1024) {
              const int hd = n >> 6, d = n & 63;
              oq[(((int64_t)b * 16 + hd) * NPAD + rb) * 64 + d] = f2bf(v * 0.125f);
            } else if (n < 2048) {
              const int n2 = n - 1024;
              const int hd = n2 >> 6, d = n2 & 63;
              ok[(((int64_t)b * 16 + hd) * NPAD + rb) * 64 + d] = f2bf(v);
            } else {
              const int n2 = n - 2048;
              const int hd = n2 >> 6, d = n2 & 63;
              ovT[(((int64_t)b * 16 + hd) * 64 + d) * NPAD + rbp] = f2bf(v);
            }
          }
        }
      }
    }
  } else if constexpr (EPI == EPI_KV) {
#pragma unroll
    for (int i = 0; i < 4; i++) {
      const int mb = m0 + wm + i * 16 + quad * 4;
#pragma unroll
      for (int reg = 0; reg < 4; reg++) {
        const int m = mb + reg;
        if (m < Mreal) {
          const int b = m / 1040, rb = m % 1040;
          const int rbp = (rb & ~31) | vperm32(rb & 31);
#pragma unroll
          for (int j = 0; j < 4; j++) {
            const int n = n0 + wn + j * 16 + lane16;
            const float v = acc[i][j][reg];
            if (n < 1024) {
              const int hd = n >> 6, d = n & 63;
              ok[(((int64_t)b * 16 + hd) * NPAD + rb) * 64 + d] = f2bf(v);
            } else {
              const int n2 = n - 1024;
              const int hd = n2 >> 6, d = n2 & 63;
              ovT[(((int64_t)b * 16 + hd) * 64 + d) * NPAD + rbp] = f2bf(v);
            }
          }
        }
      }
    }
  } else {  // EPI_GG: cols are (val,gate) alternating 16-groups
#pragma unroll
    for (int i = 0; i < 4; i++) {
      const int mb = m0 + wm + i * 16 + quad * 4;
#pragma unroll
      for (int reg = 0; reg < 4; reg++) {
        const int m = mb + reg;
        u16* hp = oh2 + (int64_t)m * FFP;
#pragma unroll
        for (int j = 0; j < 4; j += 2) {
          const float val = acc[i][j][reg];
          const float g = acc[i][j + 1][reg];
          const float ge = 0.5f * g * (1.f + erff(g * 0.70710678118654752f));
          const int vi = (((n0 + wn + j * 16) >> 5) << 4) + lane16;
          hp[vi] = f2bf(val * ge);
        }
      }
    }
  }
}

// ---------------- block-mask flash attention (swapped QK^T, LDS-free) -------
// S^T = mfma(K, Q): lane (quad,lane16) holds S[kv = c0 + {quad*4+r, 16+quad*4+r}]
// [q = lane16]. Row stats are per-lane; reduce = in-lane tree + shfl_xor(16,32).
// P -> PV A-fragment is a pure register repack (k-slot (quad,e) <-> kv
// pi(quad,e) = quad*4+(e&3)+16*(e>>2)); V^T is stored with sigma=pi^-1
// permuted columns so B-fragments are contiguous b128 loads.
__global__ __launch_bounds__(256) void attn_k(const u16* __restrict__ qb,
                                              const u16* __restrict__ kb,
                                              const u16* __restrict__ vTb,
                                              u16* __restrict__ ao) {
  const int t = threadIdx.x, w = t >> 6, l = t & 63;
  const int lane16 = l & 15, quad = l >> 4;
  const int kvb = quad * 4;
  const int bh = blockIdx.y, b = bh >> 4, h = bh & 15;
  const int row0 = blockIdx.x * 64 + w * 16;
  if (row0 >= 1040) return;
  const int type = (row0 < 512) ? 0 : (row0 < 1024 ? 1 : 2);
  const int cbeg = (type == 1) ? 512 : 0;
  const int cend = (type == 0) ? 512 : (type == 1 ? 1024 : 1040);
  const int niter = (cend - cbeg + 31) >> 5;

  const u16* qp = qb + ((int64_t)bh * NPAD + row0 + lane16) * 64 + quad * 8;
  const bf16x8 a0 = *(const bf16x8*)qp;
  const bf16x8 a1 = *(const bf16x8*)(qp + 32);
  const u16* vbase = vTb + ((int64_t)bh * 64 + lane16) * NPAD + quad * 8;

  const floatx4 fz = {0.f, 0.f, 0.f, 0.f};
  floatx4 O[4] = {fz, fz, fz, fz};
  float mrow = -1e30f, lrow = 0.f;

  for (int it = 0; it < niter; ++it) {
    const int c0 = cbeg + it * 32;
    const u16* kp = kb + ((int64_t)bh * NPAD + c0 + lane16) * 64 + quad * 8;
    const bf16x8 b00 = *(const bf16x8*)kp;
    const bf16x8 b01 = *(const bf16x8*)(kp + 32);
    const bf16x8 b10 = *(const bf16x8*)(kp + 16 * 64);
    const bf16x8 b11 = *(const bf16x8*)(kp + 16 * 64 + 32);
    floatx4 s0 = MFMA(b00, a0, fz); s0 = MFMA(b01, a1, s0);
    floatx4 s1 = MFMA(b10, a0, fz); s1 = MFMA(b11, a1, s1);
    if (c0 + 32 > cend) {  // fusion tail mask (kv >= cend)
#pragma unroll
      for (int r = 0; r < 4; r++) {
        if (c0 + kvb + r >= cend) s0[r] = -1e30f;
        if (c0 + 16 + kvb + r >= cend) s1[r] = -1e30f;
      }
    }
    float tm = fmaxf(fmaxf(fmaxf(s0[0], s0[1]), fmaxf(s0[2], s0[3])),
                     fmaxf(fmaxf(s1[0], s1[1]), fmaxf(s1[2], s1[3])));
    tm = fmaxf(tm, __shfl_xor(tm, 16));
    tm = fmaxf(tm, __shfl_xor(tm, 32));
    if (!__all(tm <= mrow)) {  // exact skip: when taken-not, a_ == 1 exactly
      const float mn = fmaxf(mrow, tm);
      const float a_ = __expf(mrow - mn);
      mrow = mn;
      lrow *= a_;
      const float al0 = __shfl(a_, kvb + 0, 16);
      const float al1 = __shfl(a_, kvb + 1, 16);
      const float al2 = __shfl(a_, kvb + 2, 16);
      const float al3 = __shfl(a_, kvb + 3, 16);
#pragma unroll
      for (int dt = 0; dt < 4; dt++) {
        O[dt][0] *= al0; O[dt][1] *= al1; O[dt][2] *= al2; O[dt][3] *= al3;
      }
    }
    float p0[4], p1[4];
#pragma unroll
    for (int r = 0; r < 4; r++) {
      p0[r] = __expf(s0[r] - mrow);
      p1[r] = __expf(s1[r] - mrow);
    }
    float ps = ((p0[0] + p0[1]) + (p0[2] + p0[3])) +
               ((p1[0] + p1[1]) + (p1[2] + p1[3]));
    ps += __shfl_xor(ps, 16);
    ps += __shfl_xor(ps, 32);
    lrow += ps;
    union { bf16x8 v; u16 s[8]; } pf;
#pragma unroll
    for (int r = 0; r < 4; r++) {
      pf.s[r] = f2bf(p0[r]);
      pf.s[4 + r] = f2bf(p1[r]);
    }
#pragma unroll
    for (int dt = 0; dt < 4; dt++) {
      const bf16x8 bv = *(const bf16x8*)(vbase + (int64_t)dt * 16 * NPAD + c0);
      O[dt] = MFMA(pf.v, bv, O[dt]);
    }
  }
  float lr[4];
#pragma unroll
  for (int r = 0; r < 4; r++) lr[r] = __shfl(lrow, kvb + r, 16);
#pragma unroll
  for (int dt = 0; dt < 4; dt++)
#pragma unroll
    for (int r = 0; r < 4; r++) {
      const int row = row0 + kvb + r;
      ao[((int64_t)b * 1040 + row) * 1024 + h * 64 + dt * 16 + lane16] =
          f2bf(O[dt][r] / lr[r]);
    }
}

// ---------------- pool q: qP[16,1024] = return_tokens @ pool_wq * 0.125 ----------------
// rows 4..15 are zeroed (pool_attn pads q-rows to 16; keeps garbage out of the
// wave-uniform defer-max branch).
__global__ __launch_bounds__(256) void poolq_k(const float* __restrict__ rtk,
                                               const float* __restrict__ pwq,
                                               u16* __restrict__ qP) {
  const int r = blockIdx.y;
  const int n = blockIdx.x * 256 + threadIdx.x;
  if (r >= 4) { qP[(int64_t)r * 1024 + n] = 0; return; }
  const float* x = rtk + (int64_t)r * 1024;
  float acc = 0.f;
#pragma unroll 8
  for (int k = 0; k < 1024; k++) acc += x[k] * pwq[(int64_t)k * 1024 + n];
  qP[(int64_t)r * 1024 + n] = f2bf(acc * 0.125f);
}

// ---------------- pool attention: 1 wave per (b,h), 4 real q-rows ----------------
DEV bool pvalid(int r, int c) {
  if (r == 0) return c < 512;
  if (r == 1) return (c >= 512) && (c < 1024);
  if (r == 2) return (c >= 1024) && (c < 1040);
  return c < 1040;  // GLOBAL row + pad rows
}

__global__ __launch_bounds__(64) void pool_attn_k(const u16* __restrict__ qP,
                                                  const u16* __restrict__ kb,
                                                  const u16* __restrict__ vTb,
                                                  u16* __restrict__ po) {
  const int l = threadIdx.x;
  const int lane16 = l & 15, quad = l >> 4;
  const int kvb = quad * 4;
  const int bh = blockIdx.x, b = bh >> 4, h = bh & 15;
  const u16* qp = qP + (int64_t)lane16 * 1024 + h * 64 + quad * 8;
  const bf16x8 a0 = *(const bf16x8*)qp;
  const bf16x8 a1 = *(const bf16x8*)(qp + 32);
  const u16* vbase = vTb + ((int64_t)bh * 64 + lane16) * NPAD + quad * 8;
  const floatx4 fz = {0.f, 0.f, 0.f, 0.f};
  floatx4 O[4] = {fz, fz, fz, fz};
  float mrow = -1e30f, lrow = 0.f;
  for (int it = 0; it < 33; ++it) {
    const int c0 = it * 32;
    const u16* kp = kb + ((int64_t)bh * NPAD + c0 + lane16) * 64 + quad * 8;
    const bf16x8 b00 = *(const bf16x8*)kp;
    const bf16x8 b01 = *(const bf16x8*)(kp + 32);
    const bf16x8 b10 = *(const bf16x8*)(kp + 16 * 64);
    const bf16x8 b11 = *(const bf16x8*)(kp + 16 * 64 + 32);
    floatx4 s0 = MFMA(b00, a0, fz); s0 = MFMA(b01, a1, s0);
    floatx4 s1 = MFMA(b10, a0, fz); s1 = MFMA(b11, a1, s1);
#pragma unroll
    for (int r = 0; r < 4; r++) {
      if (!pvalid(lane16, c0 + kvb + r)) s0[r] = -1e30f;
      if (!pvalid(lane16, c0 + 16 + kvb + r)) s1[r] = -1e30f;
    }
    float tm = fmaxf(fmaxf(fmaxf(s0[0], s0[1]), fmaxf(s0[2], s0[3])),
                     fmaxf(fmaxf(s1[0], s1[1]), fmaxf(s1[2], s1[3])));
    tm = fmaxf(tm, __shfl_xor(tm, 16));
    tm = fmaxf(tm, __shfl_xor(tm, 32));
    if (!__all(tm <= mrow)) {
      const float mn = fmaxf(mrow, tm);
      const float a_ = __expf(mrow - mn);
      mrow = mn;
      lrow *= a_;
      const float al0 = __shfl(a_, kvb + 0, 16);
      const float al1 = __shfl(a_, kvb + 1, 16);
      const float al2 = __shfl(a_, kvb + 2, 16);
      const float al3 = __shfl(a_, kvb + 3, 16);
#pragma unroll
      for (int dt = 0; dt < 4; dt++) {
        O[dt][0] *= al0; O[dt][1] *= al1; O[dt][2] *= al2; O[dt][3] *= al3;
      }
    }
    float p0[4], p1[4];
#pragma unroll
    for (int r = 0; r < 4; r++) {
      p0[r] = __expf(s0[r] - mrow);
      p1[r] = __expf(s1[r] - mrow);
    }
    float ps = ((p0[0] + p0[1]) + (p0[2] + p0[3])) +
               ((p1[0] + p1[1]) + (p1[2] + p1[3]));
    ps += __shfl_xor(ps, 16);
    ps += __shfl_xor(ps, 32);
    lrow += ps;
    union { bf16x8 v; u16 s[8]; } pf;
#pragma unroll
    for (int r = 0; r < 4; r++) {
      pf.s[r] = f2bf(p0[r]);
      pf.s[4 + r] = f2bf(p1[r]);
    }
#pragma unroll
    for (int dt = 0; dt < 4; dt++) {
      const bf16x8 bv = *(const bf16x8*)(vbase + (int64_t)dt * 16 * NPAD + c0);
      O[dt] = MFMA(pf.v, bv, O[dt]);
    }
  }
  float lr[4];
#pragma unroll
  for (int r = 0; r < 4; r++) lr[r] = __shfl(lrow, r, 16);
  if (quad == 0) {  // output C rows quad*4+reg -> quad0 holds real rows 0..3
#pragma unroll
    for (int dt = 0; dt < 4; dt++)
#pragma unroll
      for (int r = 0; r < 4; r++)
        po[((int64_t)b * 4 + r) * 1024 + h * 64 + dt * 16 + lane16] =
            f2bf(O[dt][r] / lr[r]);
  }
}

// ---------------- final: out = poolO @ pool_wo + return_tokens ----------------
__global__ __launch_bounds__(256) void fout_k(const u16* __restrict__ po,
                                              const float* __restrict__ pwo,
                                              const float* __restrict__ rtk,
                                              float* __restrict__ out) {
  const int row = blockIdx.y;  // b*4 + r, 0..15
  const int n = blockIdx.x * 256 + threadIdx.x;
  const u16* x = po + (int64_t)row * 1024;
  float acc = 0.f;
#pragma unroll 8
  for (int k = 0; k < 1024; k++) acc += bf2f(x[k]) * pwo[(int64_t)k * 1024 + n];
  out[(int64_t)row * 1024 + n] = acc + rtk[(int64_t)(row & 3) * 1024 + n];
}

// ---------------------------------------------------------------------------
extern "C" void kernel_launch(void* const* d_in, const int* in_sizes, int n_in,
                              void* d_out, int out_size, void* d_ws, size_t ws_size,
                              hipStream_t stream) {
  (void)in_sizes; (void)n_in; (void)out_size;
  const float* m0p  = (const float*)d_in[0];
  const float* m1p  = (const float*)d_in[1];
  const float* fus  = (const float*)d_in[2];
  const float* rtk  = (const float*)d_in[3];
  const float* lng  = (const float*)d_in[4];
  const float* wq   = (const float*)d_in[5];
  const float* wkv  = (const float*)d_in[6];
  const float* wo   = (const float*)d_in[7];
  const float* w1   = (const float*)d_in[8];
  const float* w2   = (const float*)d_in[9];
  const float* pwq  = (const float*)d_in[10];
  const float* pwkv = (const float*)d_in[11];
  const float* pwo  = (const float*)d_in[12];
  const float* fg   = (const float*)d_in[13];
  float* out = (float*)d_out;

  char* p = (char*)d_ws;
  auto alloc = [&](size_t bytes) -> char* {
    char* r = p;
    p += (bytes + 255) & ~(size_t)255;
    return r;
  };
  // Base footprint ~63.3 MB (identical layout to R8).
  u16* warena = (u16*)alloc((size_t)FF2P * 1024 * 2);       // 11.5 MB, per-GEMM weights
  float* tokens = (float*)alloc((size_t)MREAL * 1024 * 4);  // 17.04 MB
  u16* hbuf  = (u16*)alloc((size_t)MPAD * 1024 * 2);        // 8.65 MB (LN out + attn out)
  u16* qb    = (u16*)alloc((size_t)64 * NPAD * 64 * 2);     // 8.65 MB
  u16* kbuf  = (u16*)alloc((size_t)64 * NPAD * 64 * 2);     // 8.65 MB
  u16* vTbuf = (u16*)alloc((size_t)64 * NPAD * 64 * 2);     // 8.65 MB
  u16* h2buf = qb;  // 23.8 MB alias over qb+kbuf+vTbuf (25.95 MB): dead between
                    // attn read and next layer's Q/KV writes; stale k/vT tail
                    // rows [1040,1056) are masked (-1e30) / multiplied by p=0.
  u16* qP    = (u16*)alloc((size_t)16 * 1024 * 2);
  u16* poolO = (u16*)alloc((size_t)16 * 1024 * 2);

  // Residual-delta buffers (mode 2: two z-slices; mode 1: one; mode 0: legacy
  // atomic path). Chosen by available workspace — no risk if ws is tight.
  const size_t DELTA_BYTES = (size_t)MREAL * 1024 * 4;  // 17.04 MB
  const size_t base_used = (size_t)(p - (char*)d_ws);
  int mode = 0;
  float* d0 = nullptr;
  float* d1 = nullptr;
  if (ws_size >= base_used + 2 * DELTA_BYTES + 1024) {
    mode = 2;
    d0 = (float*)alloc(2 * DELTA_BYTES);
    d1 = d0 + (size_t)MREAL * 1024;  // contiguous: blockIdx.z indexes it
  } else if (ws_size >= base_used + DELTA_BYTES + 1024) {
    mode = 1;
    d0 = (float*)alloc(DELTA_BYTES);
    d1 = d0;  // unused (two=0)
  }

  const dim3 tb(32, 8, 1);
  build_tokens_k<<<dim3(1040, 4), 256, 0, stream>>>(m0p, m1p, fus, tokens);

  if (mode) {
    const int zz = mode;  // split-K factor for residual GEMMs
    const int two = (mode == 2);
    for (int lyr = 0; lyr < 4; ++lyr) {
      if (lyr == 0)
        ln_k<<<MREAL, 256, 0, stream>>>(tokens, lng, hbuf);
      else  // fold previous layer's FF2 delta into tokens + this pre-attn LN
        add_ln_k<<<MREAL, 256, 0, stream>>>(tokens, d0, d1, lng + lyr * 1024,
                                            hbuf, two, 1);
      transpose_cvt<<<dim3(32, 32), tb, 0, stream>>>(
          wq + (int64_t)lyr * 1024 * 1024, warena, 1024, 1024, 1024);
      transpose_cvt<<<dim3(32, 64), tb, 0, stream>>>(
          wkv + (int64_t)lyr * 1024 * 2048, warena + (size_t)1024 * 1024, 1024, 2048, 1024);
      gemm_bt<EPI_QKV><<<dim3(24, 33), 256, 0, stream>>>(
          hbuf, warena, 1024, MREAL, nullptr, qb, kbuf, vTbuf, nullptr);
      attn_k<<<dim3(17, 64), 256, 0, stream>>>(qb, kbuf, vTbuf, hbuf);
      transpose_cvt<<<dim3(32, 32), tb, 0, stream>>>(
          wo + (int64_t)lyr * 1024 * 1024, warena, 1024, 1024, 1024);
      gemm_bt<EPI_DELTA><<<dim3(8, 33, zz), 256, 0, stream>>>(
          hbuf, warena, 1024, MREAL, d0, nullptr, nullptr, nullptr, nullptr);
      add_ln_k<<<MREAL, 256, 0, stream>>>(tokens, d0, d1, lng + lyr * 1024,
                                          hbuf, two, 1);
      transpose_w1<<<dim3(32, FF2P / 32), tb, 0, stream>>>(
          w1 + (int64_t)lyr * 1024 * 5460, warena);
      gemm_bt<EPI_GG><<<dim3(FF2P / 128, 33), 256, 0, stream>>>(
          hbuf, warena, 1024, MREAL, nullptr, nullptr, nullptr, nullptr, h2buf);
      transpose_cvt<<<dim3(FFP / 32, 32), tb, 0, stream>>>(
          w2 + (int64_t)lyr * 2730 * 1024, warena, 2730, 1024, FFP);
      gemm_bt<EPI_DELTA><<<dim3(8, 33, zz), 256, 0, stream>>>(
          h2buf, warena, FFP, MREAL, d0, nullptr, nullptr, nullptr, nullptr);
    }
    // final: fold last FF2 delta + final LN (tokens dead after -> no writeback)
    add_ln_k<<<MREAL, 256, 0, stream>>>(tokens, d0, d1, fg, hbuf, two, 0);
  } else {
    for (int lyr = 0; lyr < 4; ++lyr) {
      ln_k<<<MREAL, 256, 0, stream>>>(tokens, lng + lyr * 1024, hbuf);
      transpose_cvt<<<dim3(32, 32), tb, 0, stream>>>(
          wq + (int64_t)lyr * 1024 * 1024, warena, 1024, 1024, 1024);
      transpose_cvt<<<dim3(32, 64), tb, 0, stream>>>(
          wkv + (int64_t)lyr * 1024 * 2048, warena + (size_t)1024 * 1024, 1024, 2048, 1024);
      gemm_bt<EPI_QKV><<<dim3(24, 33), 256, 0, stream>>>(
          hbuf, warena, 1024, MREAL, nullptr, qb, kbuf, vTbuf, nullptr);
      attn_k<<<dim3(17, 64), 256, 0, stream>>>(qb, kbuf, vTbuf, hbuf);
      transpose_cvt<<<dim3(32, 32), tb, 0, stream>>>(
          wo + (int64_t)lyr * 1024 * 1024, warena, 1024, 1024, 1024);
      gemm_bt<EPI_TOKADD><<<dim3(8, 33, 2), 256, 0, stream>>>(
          hbuf, warena, 1024, MREAL, tokens, nullptr, nullptr, nullptr, nullptr);
      ln_k<<<MREAL, 256, 0, stream>>>(tokens, lng + lyr * 1024, hbuf);
      transpose_w1<<<dim3(32, FF2P / 32), tb, 0, stream>>>(
          w1 + (int64_t)lyr * 1024 * 5460, warena);
      gemm_bt<EPI_GG><<<dim3(FF2P / 128, 33), 256, 0, stream>>>(
          hbuf, warena, 1024, MREAL, nullptr, nullptr, nullptr, nullptr, h2buf);
      transpose_cvt<<<dim3(FFP / 32, 32), tb, 0, stream>>>(
          w2 + (int64_t)lyr * 2730 * 1024, warena, 2730, 1024, FFP);
      gemm_bt<EPI_TOKADD><<<dim3(8, 33, 2), 256, 0, stream>>>(
          h2buf, warena, FFP, MREAL, tokens, nullptr, nullptr, nullptr, nullptr);
    }
    ln_k<<<MREAL, 256, 0, stream>>>(tokens, fg, hbuf);
  }

  transpose_cvt<<<dim3(32, 64), tb, 0, stream>>>(pwkv, warena, 1024, 2048, 1024);
  gemm_bt<EPI_KV><<<dim3(16, 33), 256, 0, stream>>>(
      hbuf, warena, 1024, MREAL, nullptr, nullptr, kbuf, vTbuf, nullptr);
  poolq_k<<<dim3(4, 16), 256, 0, stream>>>(rtk, pwq, qP);
  pool_attn_k<<<64, 64, 0, stream>>>(qP, kbuf, vTbuf, poolO);
  fout_k<<<dim3(4, 16), 256, 0, stream>>>(poolO, pwo, rtk, out);
}

// Round 8
// 1702.508 us; speedup vs baseline: 1.1026x; 1.0376x over previous
//
#include <hip/hip_runtime.h>
#include <stdint.h>

// ---------------------------------------------------------------------------
// Zorro-style multimodal transformer, B=4, N=1040 (512+512+16 fusion), D=1024,
// H=16, DH=64, L=4, FF=2730 gated-GELU; final LN + 4-token masked pool attn.
// bf16 MFMA GEMMs; block-mask flash attention (contiguous col ranges).
// R5: swapped-operand QK^T attention (S^T = mfma(K,Q)); LDS-free softmax.
// R7: gemm_bt 2-phase pipeline: double-buffered [2][128x64] LDS tiles, XOR
//     column swizzle both-sides (bank conflicts 2.97M -> 0, verified R8).
// R9: EPI_DELTA + add_ln_k kill the atomic residual epilogue (-75 us).
// R11: grouped block-order remap (G=4 supertiles): GG 102->77us, Mfma 10->26%.
// R12: 512-thread gemm_bt (8 waves/block, wave tile 64x32, acc[4][2]).
//     R11 PMC: Occupancy 19% (64KB LDS -> 2 blocks/CU = 8 waves cap) with
//     Mfma 26 / VALU 33 / HBM 23 -> latency-bound on thin wave supply.
//     Same tile, same LDS+swizzle; waves/CU 8->16 (cap 25%->50%).
// ---------------------------------------------------------------------------

#define DEV __device__ __forceinline__

typedef unsigned short u16;
typedef __attribute__((ext_vector_type(8))) __bf16 bf16x8;
typedef __attribute__((ext_vector_type(4))) float floatx4;

DEV u16 f2bf(float f) {
  union { float f; unsigned u; } v; v.f = f;
  return (u16)((v.u + 0x7fffu + ((v.u >> 16) & 1u)) >> 16);  // RNE
}
DEV float bf2f(u16 s) {
  union { unsigned u; float f; } v; v.u = ((unsigned)s) << 16;
  return v.f;
}

#define MFMA(a, b, c) __builtin_amdgcn_mfma_f32_16x16x32_bf16(a, b, c, 0, 0, 0)

DEV void gld16(const u16* g, u16* l) {
  __builtin_amdgcn_global_load_lds((__attribute__((address_space(1))) void*)g,
                                   (__attribute__((address_space(3))) void*)l,
                                   16, 0, 0);
}

// V^T column permutation: mfma k-slot (quad,e) holds logical kv
// pi(quad,e) = quad*4 + (e&3) + 16*(e>>2). sigma = pi^-1 maps kv offset j
// (within a 32 block) to its k-slot. Writing V[rb][d] at column
// (rb&~31)|sigma(rb&31) makes PV B-fragments contiguous b128 loads.
DEV int vperm32(int j) {
  return (((j >> 2) & 3) << 3) | (j & 3) | (((j >> 4) & 1) << 2);
}

// ---------------- constants ----------------
#define MREAL 4160   /* B*N = 4*1040 */
#define MPAD  4224   /* 33*128 */
#define NPAD  1056   /* 1040 padded to x32 */
#define FFP   2816   /* 2730 padded to x64 (split-K=2 -> 1408 = 22*64) */
#define FF2P  5632

// ---------------- weight conversion ----------------
// out[n*Kstride + k] = (k < Kin) ? bf16(in[k*N + n]) : 0    (B^T bf16 layout)
__global__ __launch_bounds__(256) void transpose_cvt(
    const float* __restrict__ in, u16* __restrict__ out,
    int Kin, int N, int Kstride) {
  __shared__ float tile[32][33];
  const int k0 = blockIdx.x * 32, n0 = blockIdx.y * 32;
  const int tx = threadIdx.x, ty = threadIdx.y;
#pragma unroll
  for (int i = 0; i < 4; i++) {
    int k = k0 + ty + i * 8;
    tile[ty + i * 8][tx] = (k < Kin) ? in[(int64_t)k * N + n0 + tx] : 0.f;
  }
  __syncthreads();
#pragma unroll
  for (int i = 0; i < 4; i++) {
    int n = n0 + ty + i * 8;
    int k = k0 + tx;
    if (k < Kstride) out[(int64_t)n * Kstride + k] = f2bf(tile[tx][ty + i * 8]);
  }
}

// ff_w1 [1024 x 5460] -> w1T [5632 x 1024] bf16 with val/gate 16-col interleave:
// out row r: vi = (r/32)*16 + r%16 ; gate if (r/16)&1 ; src col = gate? 2730+vi : vi
__global__ __launch_bounds__(256) void transpose_w1(
    const float* __restrict__ in, u16* __restrict__ out) {
  __shared__ float tile[32][33];
  const int k0 = blockIdx.x * 32;        // D dim
  const int r0 = blockIdx.y * 32;        // output-row dim
  const int tx = threadIdx.x, ty = threadIdx.y;
  const int vb = (r0 >> 5) << 4;         // = r0/2
  const int vi = vb + (tx & 15);
  const int c = (tx < 16) ? vi : 2730 + vi;
  const bool valid = vi < 2730;
#pragma unroll
  for (int i = 0; i < 4; i++) {
    int k = k0 + ty + i * 8;
    tile[ty + i * 8][tx] = valid ? in[(int64_t)k * 5460 + c] : 0.f;
  }
  __syncthreads();
#pragma unroll
  for (int i = 0; i < 4; i++) {
    int rl = ty + i * 8;
    out[(int64_t)(r0 + rl) * 1024 + k0 + tx] = f2bf(tile[tx][rl]);
  }
}

// ---------------- tokens assembly ----------------
__global__ __launch_bounds__(256) void build_tokens_k(
    const float* __restrict__ m0p, const float* __restrict__ m1p,
    const float* __restrict__ fus, float* __restrict__ tokens) {
  const int n = blockIdx.x, b = blockIdx.y, t = threadIdx.x;
  const float* src = (n < 512) ? m0p + ((int64_t)b * 512 + n) * 1024
                   : (n < 1024) ? m1p + ((int64_t)b * 512 + (n - 512)) * 1024
                                : fus + (int64_t)(n - 1024) * 1024;
  float4 v = ((const float4*)src)[t];
  ((float4*)(tokens + ((int64_t)b * 1040 + n) * 1024))[t] = v;
}

// ---------------- layernorm (f32 in, bf16 out) ----------------
__global__ __launch_bounds__(256) void ln_k(const float* __restrict__ x,
                                            const float* __restrict__ gamma,
                                            u16* __restrict__ out) {
  const int r = blockIdx.x, t = threadIdx.x;
  const float4 v = ((const float4*)(x + (int64_t)r * 1024))[t];
  float s = v.x + v.y + v.z + v.w;
  float q = v.x * v.x + v.y * v.y + v.z * v.z + v.w * v.w;
#pragma unroll
  for (int off = 32; off >= 1; off >>= 1) {
    s += __shfl_xor(s, off);
    q += __shfl_xor(q, off);
  }
  __shared__ float red[8];
  const int w = t >> 6, l = t & 63;
  if (l == 0) { red[w] = s; red[4 + w] = q; }
  __syncthreads();
  s = red[0] + red[1] + red[2] + red[3];
  q = red[4] + red[5] + red[6] + red[7];
  const float mu = s * (1.f / 1024.f);
  const float var = q * (1.f / 1024.f) - mu * mu;
  const float rs = rsqrtf(var + 1e-5f);
  const float4 g = ((const float4*)gamma)[t];
  u16* op = out + (int64_t)r * 1024 + t * 4;
  op[0] = f2bf((v.x - mu) * rs * g.x);
  op[1] = f2bf((v.y - mu) * rs * g.y);
  op[2] = f2bf((v.z - mu) * rs * g.z);
  op[3] = f2bf((v.w - mu) * rs * g.w);
}

// ---------------- fused residual-add + layernorm ----------------
// tokens += d0 (+ d1); optionally write tokens back; LN(tokens)*gamma -> out.
__global__ __launch_bounds__(256) void add_ln_k(
    float* __restrict__ x, const float* __restrict__ d0,
    const float* __restrict__ d1, const float* __restrict__ gamma,
    u16* __restrict__ out, int two, int writeback) {
  const int r = blockIdx.x, t = threadIdx.x;
  const int64_t off = (int64_t)r * 1024 + t * 4;
  float4 v = *(const float4*)(x + off);
  {
    const float4 a = *(const float4*)(d0 + off);
    v.x += a.x; v.y += a.y; v.z += a.z; v.w += a.w;
  }
  if (two) {
    const float4 a = *(const float4*)(d1 + off);
    v.x += a.x; v.y += a.y; v.z += a.z; v.w += a.w;
  }
  if (writeback) *(float4*)(x + off) = v;
  float s = v.x + v.y + v.z + v.w;
  float q = v.x * v.x + v.y * v.y + v.z * v.z + v.w * v.w;
#pragma unroll
  for (int off2 = 32; off2 >= 1; off2 >>= 1) {
    s += __shfl_xor(s, off2);
    q += __shfl_xor(q, off2);
  }
  __shared__ float red[8];
  const int w = t >> 6, l = t & 63;
  if (l == 0) { red[w] = s; red[4 + w] = q; }
  __syncthreads();
  s = red[0] + red[1] + red[2] + red[3];
  q = red[4] + red[5] + red[6] + red[7];
  const float mu = s * (1.f / 1024.f);
  const float var = q * (1.f / 1024.f) - mu * mu;
  const float rs = rsqrtf(var + 1e-5f);
  const float4 g = ((const float4*)gamma)[t];
  u16* op = out + (int64_t)r * 1024 + t * 4;
  op[0] = f2bf((v.x - mu) * rs * g.x);
  op[1] = f2bf((v.y - mu) * rs * g.y);
  op[2] = f2bf((v.z - mu) * rs * g.z);
  op[3] = f2bf((v.w - mu) * rs * g.w);
}

// ---------------- MFMA GEMM: C[M,N] = A[M,K](bf16) @ Bt[N,K](bf16) ----------------
enum { EPI_QKV = 0, EPI_KV = 1, EPI_TOKADD = 2, EPI_GG = 3, EPI_DELTA = 4 };

// 512 threads = 8 waves (2M x 4N), wave tile 64x32, acc[4][2].
// Kstr = row stride of A and Bt; per-z K-range = Kstr / gridDim.z (mult of 64).
// 2-phase pipeline: LDS tiles [2][128 rows][64 cols] per operand (64 KiB);
// next K-tile staged via global_load_lds BEFORE the current tile's
// ds_read+MFMA, one __syncthreads per K-step (drains vmcnt+lgkm).
// LDS col swizzle: 16B-column qphys = qlog ^ (row&7), applied by pre-swizzling
// the GLOBAL source column (LDS dest stays wave-linear) and on the read side.
// Grouped block-order remap: linear wg id -> (bx,by) in supertiles of G=4
// B-panels x all M-rows (per-XCD L2 working-set fit).
template <int EPI>
__global__ __launch_bounds__(512) void gemm_bt(
    const u16* __restrict__ A, const u16* __restrict__ Bt,
    int Kstr, int Mreal,
    float* __restrict__ tokens, u16* __restrict__ oq, u16* __restrict__ ok,
    u16* __restrict__ ovT, u16* __restrict__ oh2) {
  __shared__ __align__(16) u16 lA[2][128 * 64];
  __shared__ __align__(16) u16 lB[2][128 * 64];
  const int t = threadIdx.x;
  const int w = t >> 6, l = t & 63;
  const int lane16 = l & 15, quad = l >> 4;

  // ---- grouped block-order remap (bijective) ----
  const int nbx = gridDim.x, nby = gridDim.y;
  const int lin = blockIdx.y * nbx + blockIdx.x;
  const int ngf = nbx >> 2;            // full groups of G=4
  const int base = ngf * 4 * nby;
  int bx, by;
  if (lin < base) {
    const int g = lin / (nby * 4);
    const int r = lin - g * nby * 4;
    bx = (g << 2) + (r & 3);
    by = r >> 2;
  } else {  // tail group (nbx % 4 != 0) — unused for our shapes, kept safe
    const int W = nbx - (ngf << 2);
    const int r = lin - base;
    bx = (ngf << 2) + r % W;
    by = r / W;
  }
  const int m0 = by * 128, n0 = bx * 128;
  const int wm = (w >> 2) * 64, wn = (w & 3) * 32;  // wave tile 64x32

  const int Klen = Kstr / gridDim.z;
  const int koff = blockIdx.z * Klen;

  const floatx4 fz = {0.f, 0.f, 0.f, 0.f};
  floatx4 acc[4][2];
#pragma unroll
  for (int i = 0; i < 4; i++)
#pragma unroll
    for (int j = 0; j < 2; j++) acc[i][j] = fz;

  // Staging (512 thr): thread t -> rows rowS=t>>3 and rowS+64, 16B col (t&7),
  // pre-swizzled source col so lds[row][q] = A[row][ (q ^ (row&7))*8 .. +7 ]
  // ((row+64)&7 == row&7, so one scol serves both rows).
  const int rowS = t >> 3;
  const int scol = (((t & 7) ^ (rowS & 7)) << 3);
  const u16* gAs = A + (int64_t)(m0 + rowS) * Kstr + koff + scol;
  const u16* gBs = Bt + (int64_t)(n0 + rowS) * Kstr + koff + scol;
  const int64_t rsk64 = (int64_t)64 * Kstr;

  // Fragment-read swizzled 16B-column offsets (elements):
  const int rsw = lane16 & 7;
  const int cp0 = ((quad ^ rsw) << 3);        // k-substep 0 (k = quad*8)
  const int cp1 = (((quad + 4) ^ rsw) << 3);  // k-substep 1 (k = 32 + quad*8)

  auto stage = [&](int buf, int kt) {
    const u16* ga = gAs + kt;
    const u16* gb = gBs + kt;
    u16* la = &lA[buf][0] + t * 8;
    u16* lb = &lB[buf][0] + t * 8;
    gld16(ga, la);
    gld16(ga + rsk64, la + 4096);
    gld16(gb, lb);
    gld16(gb + rsk64, lb + 4096);
  };

  stage(0, 0);
  __syncthreads();
  int cur = 0;
  for (int kt = 0; kt < Klen; kt += 64) {
    if (kt + 64 < Klen) stage(cur ^ 1, kt + 64);
    const u16* la = &lA[cur][0] + (wm + lane16) * 64;
    const u16* lb = &lB[cur][0] + (wn + lane16) * 64;
    bf16x8 af[4], bf[2];
#pragma unroll
    for (int i = 0; i < 4; i++) af[i] = *(const bf16x8*)(la + i * 16 * 64 + cp0);
#pragma unroll
    for (int j = 0; j < 2; j++) bf[j] = *(const bf16x8*)(lb + j * 16 * 64 + cp0);
#pragma unroll
    for (int i = 0; i < 4; i++)
#pragma unroll
      for (int j = 0; j < 2; j++) acc[i][j] = MFMA(af[i], bf[j], acc[i][j]);
#pragma unroll
    for (int i = 0; i < 4; i++) af[i] = *(const bf16x8*)(la + i * 16 * 64 + cp1);
#pragma unroll
    for (int j = 0; j < 2; j++) bf[j] = *(const bf16x8*)(lb + j * 16 * 64 + cp1);
#pragma unroll
    for (int i = 0; i < 4; i++)
#pragma unroll
      for (int j = 0; j < 2; j++) acc[i][j] = MFMA(af[i], bf[j], acc[i][j]);
    __syncthreads();
    cur ^= 1;
  }

  // Epilogues. C-layout: lane holds row = quad*4+reg, col = lane16 within frag.
  if constexpr (EPI == EPI_TOKADD) {
    const bool atomic = gridDim.z > 1;
#pragma unroll
    for (int i = 0; i < 4; i++) {
      const int mb = m0 + wm + i * 16 + quad * 4;
#pragma unroll
      for (int reg = 0; reg < 4; reg++) {
        const int m = mb + reg;
        if (m < Mreal) {
          float* tp = tokens + (int64_t)m * 1024;
#pragma unroll
          for (int j = 0; j < 2; j++) {
            const int n = n0 + wn + j * 16 + lane16;
            if (atomic) atomicAdd(tp + n, acc[i][j][reg]);
            else tp[n] += acc[i][j][reg];
          }
        }
      }
    }
  } else if constexpr (EPI == EPI_DELTA) {
    // Plain f32 partial-sum store into per-z delta buffer (no atomics).
    float* dp = tokens + (int64_t)blockIdx.z * MREAL * 1024;
#pragma unroll
    for (int i = 0; i < 4; i++) {
      const int mb = m0 + wm + i * 16 + quad * 4;
#pragma unroll
      for (int reg = 0; reg < 4; reg++) {
        const int m = mb + reg;
        if (m < Mreal) {
          float* tp = dp + (int64_t)m * 1024;
#pragma unroll
          for (int j = 0; j < 2; j++) {
            const int n = n0 + wn + j * 16 + lane16;
            tp[n] = acc[i][j][reg];
          }
        }
      }
    }
  } else if constexpr (EPI == EPI_QKV) {
    // cols [0,1024): Q (scaled), [1024,2048): K, [2048,3072): V^T (permuted cols)
#pragma unroll
    for (int i = 0; i < 4; i++) {
      const int mb = m0 + wm + i * 16 + quad * 4;
#pragma unroll
      for (int reg = 0; reg < 4; reg++) {
        const int m = mb + reg;
        if (m < Mreal) {
          const int b = m / 1040, rb = m % 1040;
          const int rbp = (rb & ~31) | vperm32(rb & 31);
#pragma unroll
          for (int j = 0; j < 2; j++) {
            const int n = n0 + wn + j * 16 + lane16;
            const float v = acc[i][j][reg];
            if (n < 1024) {
              const int hd = n >> 6, d = n & 63;
              oq[(((int64_t)b * 16 + hd) * NPAD + rb) * 64 + d] = f2bf(v * 0.125f);
            } else if (n < 2048) {
              const int n2 = n - 1024;
              const int hd = n2 >> 6, d = n2 & 63;
              ok[(((int64_t)b * 16 + hd) * NPAD + rb) * 64 + d] = f2bf(v);
            } else {
              const int n2 = n - 2048;
              const int hd = n2 >> 6, d = n2 & 63;
              ovT[(((int64_t)b * 16 + hd) * 64 + d) * NPAD + rbp] = f2bf(v);
            }
          }
        }
      }
    }
  } else if constexpr (EPI == EPI_KV) {
#pragma unroll
    for (int i = 0; i < 4; i++) {
      const int mb = m0 + wm + i * 16 + quad * 4;
#pragma unroll
      for (int reg = 0; reg < 4; reg++) {
        const int m = mb + reg;
        if (m < Mreal) {
          const int b = m / 1040, rb = m % 1040;
          const int rbp = (rb & ~31) | vperm32(rb & 31);
#pragma unroll
          for (int j = 0; j < 2; j++) {
            const int n = n0 + wn + j * 16 + lane16;
            const float v = acc[i][j][reg];
            if (n < 1024) {
              const int hd = n >> 6, d = n & 63;
              ok[(((int64_t)b * 16 + hd) * NPAD + rb) * 64 + d] = f2bf(v);
            } else {
              const int n2 = n - 1024;
              const int hd = n2 >> 6, d = n2 & 63;
              ovT[(((int64_t)b * 16 + hd) * 64 + d) * NPAD + rbp] = f2bf(v);
            }
          }
        }
      }
    }
  } else {  // EPI_GG: cols are (val,gate) alternating 16-groups; wave tile has
            // exactly one (val,gate) pair: j=0 val, j=1 gate (wn multiple of 32)
#pragma unroll
    for (int i = 0; i < 4; i++) {
      const int mb = m0 + wm + i * 16 + quad * 4;
#pragma unroll
      for (int reg = 0; reg < 4; reg++) {
        const int m = mb + reg;
        u16* hp = oh2 + (int64_t)m * FFP;
        const float val = acc[i][0][reg];
        const float g = acc[i][1][reg];
        const float ge = 0.5f * g * (1.f + erff(g * 0.70710678118654752f));
        const int vi = (((n0 + wn) >> 5) << 4) + lane16;
        hp[vi] = f2bf(val * ge);
      }
    }
  }
}

// ---------------- block-mask flash attention (swapped QK^T, LDS-free) -------
// S^T = mfma(K, Q): lane (quad,lane16) holds S[kv = c0 + {quad*4+r, 16+quad*4+r}]
// [q = lane16]. Row stats are per-lane; reduce = in-lane tree + shfl_xor(16,32).
// P -> PV A-fragment is a pure register repack (k-slot (quad,e) <-> kv
// pi(quad,e) = quad*4+(e&3)+16*(e>>2)); V^T is stored with sigma=pi^-1
// permuted columns so B-fragments are contiguous b128 loads.
__global__ __launch_bounds__(256) void attn_k(const u16* __restrict__ qb,
                                              const u16* __restrict__ kb,
                                              const u16* __restrict__ vTb,
                                              u16* __restrict__ ao) {
  const int t = threadIdx.x, w = t >> 6, l = t & 63;
  const int lane16 = l & 15, quad = l >> 4;
  const int kvb = quad * 4;
  const int bh = blockIdx.y, b = bh >> 4, h = bh & 15;
  const int row0 = blockIdx.x * 64 + w * 16;
  if (row0 >= 1040) return;
  const int type = (row0 < 512) ? 0 : (row0 < 1024 ? 1 : 2);
  const int cbeg = (type == 1) ? 512 : 0;
  const int cend = (type == 0) ? 512 : (type == 1 ? 1024 : 1040);
  const int niter = (cend - cbeg + 31) >> 5;

  const u16* qp = qb + ((int64_t)bh * NPAD + row0 + lane16) * 64 + quad * 8;
  const bf16x8 a0 = *(const bf16x8*)qp;
  const bf16x8 a1 = *(const bf16x8*)(qp + 32);
  const u16* vbase = vTb + ((int64_t)bh * 64 + lane16) * NPAD + quad * 8;

  const floatx4 fz = {0.f, 0.f, 0.f, 0.f};
  floatx4 O[4] = {fz, fz, fz, fz};
  float mrow = -1e30f, lrow = 0.f;

  for (int it = 0; it < niter; ++it) {
    const int c0 = cbeg + it * 32;
    const u16* kp = kb + ((int64_t)bh * NPAD + c0 + lane16) * 64 + quad * 8;
    const bf16x8 b00 = *(const bf16x8*)kp;
    const bf16x8 b01 = *(const bf16x8*)(kp + 32);
    const bf16x8 b10 = *(const bf16x8*)(kp + 16 * 64);
    const bf16x8 b11 = *(const bf16x8*)(kp + 16 * 64 + 32);
    floatx4 s0 = MFMA(b00, a0, fz); s0 = MFMA(b01, a1, s0);
    floatx4 s1 = MFMA(b10, a0, fz); s1 = MFMA(b11, a1, s1);
    if (c0 + 32 > cend) {  // fusion tail mask (kv >= cend)
#pragma unroll
      for (int r = 0; r < 4; r++) {
        if (c0 + kvb + r >= cend) s0[r] = -1e30f;
        if (c0 + 16 + kvb + r >= cend) s1[r] = -1e30f;
      }
    }
    float tm = fmaxf(fmaxf(fmaxf(s0[0], s0[1]), fmaxf(s0[2], s0[3])),
                     fmaxf(fmaxf(s1[0], s1[1]), fmaxf(s1[2], s1[3])));
    tm = fmaxf(tm, __shfl_xor(tm, 16));
    tm = fmaxf(tm, __shfl_xor(tm, 32));
    if (!__all(tm <= mrow)) {  // exact skip: when taken-not, a_ == 1 exactly
      const float mn = fmaxf(mrow, tm);
      const float a_ = __expf(mrow - mn);
      mrow = mn;
      lrow *= a_;
      const float al0 = __shfl(a_, kvb + 0, 16);
      const float al1 = __shfl(a_, kvb + 1, 16);
      const float al2 = __shfl(a_, kvb + 2, 16);
      const float al3 = __shfl(a_, kvb + 3, 16);
#pragma unroll
      for (int dt = 0; dt < 4; dt++) {
        O[dt][0] *= al0; O[dt][1] *= al1; O[dt][2] *= al2; O[dt][3] *= al3;
      }
    }
    float p0[4], p1[4];
#pragma unroll
    for (int r = 0; r < 4; r++) {
      p0[r] = __expf(s0[r] - mrow);
      p1[r] = __expf(s1[r] - mrow);
    }
    float ps = ((p0[0] + p0[1]) + (p0[2] + p0[3])) +
               ((p1[0] + p1[1]) + (p1[2] + p1[3]));
    ps += __shfl_xor(ps, 16);
    ps += __shfl_xor(ps, 32);
    lrow += ps;
    union { bf16x8 v; u16 s[8]; } pf;
#pragma unroll
    for (int r = 0; r < 4; r++) {
      pf.s[r] = f2bf(p0[r]);
      pf.s[4 + r] = f2bf(p1[r]);
    }
#pragma unroll
    for (int dt = 0; dt < 4; dt++) {
      const bf16x8 bv = *(const bf16x8*)(vbase + (int64_t)dt * 16 * NPAD + c0);
      O[dt] = MFMA(pf.v, bv, O[dt]);
    }
  }
  float lr[4];
#pragma unroll
  for (int r = 0; r < 4; r++) lr[r] = __shfl(lrow, kvb + r, 16);
#pragma unroll
  for (int dt = 0; dt < 4; dt++)
#pragma unroll
    for (int r = 0; r < 4; r++) {
      const int row = row0 + kvb + r;
      ao[((int64_t)b * 1040 + row) * 1024 + h * 64 + dt * 16 + lane16] =
          f2bf(O[dt][r] / lr[r]);
    }
}

// ---------------- pool q: qP[16,1024] = return_tokens @ pool_wq * 0.125 ----------------
// rows 4..15 are zeroed (pool_attn pads q-rows to 16; keeps garbage out of the
// wave-uniform defer-max branch).
__global__ __launch_bounds__(256) void poolq_k(const float* __restrict__ rtk,
                                               const float* __restrict__ pwq,
                                               u16* __restrict__ qP) {
  const int r = blockIdx.y;
  const int n = blockIdx.x * 256 + threadIdx.x;
  if (r >= 4) { qP[(int64_t)r * 1024 + n] = 0; return; }
  const float* x = rtk + (int64_t)r * 1024;
  float acc = 0.f;
#pragma unroll 8
  for (int k = 0; k < 1024; k++) acc += x[k] * pwq[(int64_t)k * 1024 + n];
  qP[(int64_t)r * 1024 + n] = f2bf(acc * 0.125f);
}

// ---------------- pool attention: 1 wave per (b,h), 4 real q-rows ----------------
DEV bool pvalid(int r, int c) {
  if (r == 0) return c < 512;
  if (r == 1) return (c >= 512) && (c < 1024);
  if (r == 2) return (c >= 1024) && (c < 1040);
  return c < 1040;  // GLOBAL row + pad rows
}

__global__ __launch_bounds__(64) void pool_attn_k(const u16* __restrict__ qP,
                                                  const u16* __restrict__ kb,
                                                  const u16* __restrict__ vTb,
                                                  u16* __restrict__ po) {
  const int l = threadIdx.x;
  const int lane16 = l & 15, quad = l >> 4;
  const int kvb = quad * 4;
  const int bh = blockIdx.x, b = bh >> 4, h = bh & 15;
  const u16* qp = qP + (int64_t)lane16 * 1024 + h * 64 + quad * 8;
  const bf16x8 a0 = *(const bf16x8*)qp;
  const bf16x8 a1 = *(const bf16x8*)(qp + 32);
  const u16* vbase = vTb + ((int64_t)bh * 64 + lane16) * NPAD + quad * 8;
  const floatx4 fz = {0.f, 0.f, 0.f, 0.f};
  floatx4 O[4] = {fz, fz, fz, fz};
  float mrow = -1e30f, lrow = 0.f;
  for (int it = 0; it < 33; ++it) {
    const int c0 = it * 32;
    const u16* kp = kb + ((int64_t)bh * NPAD + c0 + lane16) * 64 + quad * 8;
    const bf16x8 b00 = *(const bf16x8*)kp;
    const bf16x8 b01 = *(const bf16x8*)(kp + 32);
    const bf16x8 b10 = *(const bf16x8*)(kp + 16 * 64);
    const bf16x8 b11 = *(const bf16x8*)(kp + 16 * 64 + 32);
    floatx4 s0 = MFMA(b00, a0, fz); s0 = MFMA(b01, a1, s0);
    floatx4 s1 = MFMA(b10, a0, fz); s1 = MFMA(b11, a1, s1);
#pragma unroll
    for (int r = 0; r < 4; r++) {
      if (!pvalid(lane16, c0 + kvb + r)) s0[r] = -1e30f;
      if (!pvalid(lane16, c0 + 16 + kvb + r)) s1[r] = -1e30f;
    }
    float tm = fmaxf(fmaxf(fmaxf(s0[0], s0[1]), fmaxf(s0[2], s0[3])),
                     fmaxf(fmaxf(s1[0], s1[1]), fmaxf(s1[2], s1[3])));
    tm = fmaxf(tm, __shfl_xor(tm, 16));
    tm = fmaxf(tm, __shfl_xor(tm, 32));
    if (!__all(tm <= mrow)) {
      const float mn = fmaxf(mrow, tm);
      const float a_ = __expf(mrow - mn);
      mrow = mn;
      lrow *= a_;
      const float al0 = __shfl(a_, kvb + 0, 16);
      const float al1 = __shfl(a_, kvb + 1, 16);
      const float al2 = __shfl(a_, kvb + 2, 16);
      const float al3 = __shfl(a_, kvb + 3, 16);
#pragma unroll
      for (int dt = 0; dt < 4; dt++) {
        O[dt][0] *= al0; O[dt][1] *= al1; O[dt][2] *= al2; O[dt][3] *= al3;
      }
    }
    float p0[4], p1[4];
#pragma unroll
    for (int r = 0; r < 4; r++) {
      p0[r] = __expf(s0[r] - mrow);
      p1[r] = __expf(s1[r] - mrow);
    }
    float ps = ((p0[0] + p0[1]) + (p0[2] + p0[3])) +
               ((p1[0] + p1[1]) + (p1[2] + p1[3]));
    ps += __shfl_xor(ps, 16);
    ps += __shfl_xor(ps, 32);
    lrow += ps;
    union { bf16x8 v; u16 s[8]; } pf;
#pragma unroll
    for (int r = 0; r < 4; r++) {
      pf.s[r] = f2bf(p0[r]);
      pf.s[4 + r] = f2bf(p1[r]);
    }
#pragma unroll
    for (int dt = 0; dt < 4; dt++) {
      const bf16x8 bv = *(const bf16x8*)(vbase + (int64_t)dt * 16 * NPAD + c0);
      O[dt] = MFMA(pf.v, bv, O[dt]);
    }
  }
  float lr[4];
#pragma unroll
  for (int r = 0; r < 4; r++) lr[r] = __shfl(lrow, r, 16);
  if (quad == 0) {  // output C rows quad*4+reg -> quad0 holds real rows 0..3
#pragma unroll
    for (int dt = 0; dt < 4; dt++)
#pragma unroll
      for (int r = 0; r < 4; r++)
        po[((int64_t)b * 4 + r) * 1024 + h * 64 + dt * 16 + lane16] =
            f2bf(O[dt][r] / lr[r]);
  }
}

// ---------------- final: out = poolO @ pool_wo + return_tokens ----------------
__global__ __launch_bounds__(256) void fout_k(const u16* __restrict__ po,
                                              const float* __restrict__ pwo,
                                              const float* __restrict__ rtk,
                                              float* __restrict__ out) {
  const int row = blockIdx.y;  // b*4 + r, 0..15
  const int n = blockIdx.x * 256 + threadIdx.x;
  const u16* x = po + (int64_t)row * 1024;
  float acc = 0.f;
#pragma unroll 8
  for (int k = 0; k < 1024; k++) acc += bf2f(x[k]) * pwo[(int64_t)k * 1024 + n];
  out[(int64_t)row * 1024 + n] = acc + rtk[(int64_t)(row & 3) * 1024 + n];
}

// ---------------------------------------------------------------------------
extern "C" void kernel_launch(void* const* d_in, const int* in_sizes, int n_in,
                              void* d_out, int out_size, void* d_ws, size_t ws_size,
                              hipStream_t stream) {
  (void)in_sizes; (void)n_in; (void)out_size;
  const float* m0p  = (const float*)d_in[0];
  const float* m1p  = (const float*)d_in[1];
  const float* fus  = (const float*)d_in[2];
  const float* rtk  = (const float*)d_in[3];
  const float* lng  = (const float*)d_in[4];
  const float* wq   = (const float*)d_in[5];
  const float* wkv  = (const float*)d_in[6];
  const float* wo   = (const float*)d_in[7];
  const float* w1   = (const float*)d_in[8];
  const float* w2   = (const float*)d_in[9];
  const float* pwq  = (const float*)d_in[10];
  const float* pwkv = (const float*)d_in[11];
  const float* pwo  = (const float*)d_in[12];
  const float* fg   = (const float*)d_in[13];
  float* out = (float*)d_out;

  char* p = (char*)d_ws;
  auto alloc = [&](size_t bytes) -> char* {
    char* r = p;
    p += (bytes + 255) & ~(size_t)255;
    return r;
  };
  // Base footprint ~63.3 MB (identical layout to R8).
  u16* warena = (u16*)alloc((size_t)FF2P * 1024 * 2);       // 11.5 MB, per-GEMM weights
  float* tokens = (float*)alloc((size_t)MREAL * 1024 * 4);  // 17.04 MB
  u16* hbuf  = (u16*)alloc((size_t)MPAD * 1024 * 2);        // 8.65 MB (LN out + attn out)
  u16* qb    = (u16*)alloc((size_t)64 * NPAD * 64 * 2);     // 8.65 MB
  u16* kbuf  = (u16*)alloc((size_t)64 * NPAD * 64 * 2);     // 8.65 MB
  u16* vTbuf = (u16*)alloc((size_t)64 * NPAD * 64 * 2);     // 8.65 MB
  u16* h2buf = qb;  // 23.8 MB alias over qb+kbuf+vTbuf (25.95 MB): dead between
                    // attn read and next layer's Q/KV writes; stale k/vT tail
                    // rows [1040,1056) are masked (-1e30) / multiplied by p=0.
  u16* qP    = (u16*)alloc((size_t)16 * 1024 * 2);
  u16* poolO = (u16*)alloc((size_t)16 * 1024 * 2);

  // Residual-delta buffers (mode 2: two z-slices; mode 1: one; mode 0: legacy
  // atomic path). Chosen by available workspace — no risk if ws is tight.
  const size_t DELTA_BYTES = (size_t)MREAL * 1024 * 4;  // 17.04 MB
  const size_t base_used = (size_t)(p - (char*)d_ws);
  int mode = 0;
  float* d0 = nullptr;
  float* d1 = nullptr;
  if (ws_size >= base_used + 2 * DELTA_BYTES + 1024) {
    mode = 2;
    d0 = (float*)alloc(2 * DELTA_BYTES);
    d1 = d0 + (size_t)MREAL * 1024;  // contiguous: blockIdx.z indexes it
  } else if (ws_size >= base_used + DELTA_BYTES + 1024) {
    mode = 1;
    d0 = (float*)alloc(DELTA_BYTES);
    d1 = d0;  // unused (two=0)
  }

  const dim3 tb(32, 8, 1);
  build_tokens_k<<<dim3(1040, 4), 256, 0, stream>>>(m0p, m1p, fus, tokens);

  if (mode) {
    const int zz = mode;  // split-K factor for residual GEMMs
    const int two = (mode == 2);
    for (int lyr = 0; lyr < 4; ++lyr) {
      if (lyr == 0)
        ln_k<<<MREAL, 256, 0, stream>>>(tokens, lng, hbuf);
      else  // fold previous layer's FF2 delta into tokens + this pre-attn LN
        add_ln_k<<<MREAL, 256, 0, stream>>>(tokens, d0, d1, lng + lyr * 1024,
                                            hbuf, two, 1);
      transpose_cvt<<<dim3(32, 32), tb, 0, stream>>>(
          wq + (int64_t)lyr * 1024 * 1024, warena, 1024, 1024, 1024);
      transpose_cvt<<<dim3(32, 64), tb, 0, stream>>>(
          wkv + (int64_t)lyr * 1024 * 2048, warena + (size_t)1024 * 1024, 1024, 2048, 1024);
      gemm_bt<EPI_QKV><<<dim3(24, 33), 512, 0, stream>>>(
          hbuf, warena, 1024, MREAL, nullptr, qb, kbuf, vTbuf, nullptr);
      attn_k<<<dim3(17, 64), 256, 0, stream>>>(qb, kbuf, vTbuf, hbuf);
      transpose_cvt<<<dim3(32, 32), tb, 0, stream>>>(
          wo + (int64_t)lyr * 1024 * 1024, warena, 1024, 1024, 1024);
      gemm_bt<EPI_DELTA><<<dim3(8, 33, zz), 512, 0, stream>>>(
          hbuf, warena, 1024, MREAL, d0, nullptr, nullptr, nullptr, nullptr);
      add_ln_k<<<MREAL, 256, 0, stream>>>(tokens, d0, d1, lng + lyr * 1024,
                                          hbuf, two, 1);
      transpose_w1<<<dim3(32, FF2P / 32), tb, 0, stream>>>(
          w1 + (int64_t)lyr * 1024 * 5460, warena);
      gemm_bt<EPI_GG><<<dim3(FF2P / 128, 33), 512, 0, stream>>>(
          hbuf, warena, 1024, MREAL, nullptr, nullptr, nullptr, nullptr, h2buf);
      transpose_cvt<<<dim3(FFP / 32, 32), tb, 0, stream>>>(
          w2 + (int64_t)lyr * 2730 * 1024, warena, 2730, 1024, FFP);
      gemm_bt<EPI_DELTA><<<dim3(8, 33, zz), 512, 0, stream>>>(
          h2buf, warena, FFP, MREAL, d0, nullptr, nullptr, nullptr, nullptr);
    }
    // final: fold last FF2 delta + final LN (tokens dead after -> no writeback)
    add_ln_k<<<MREAL, 256, 0, stream>>>(tokens, d0, d1, fg, hbuf, two, 0);
  } else {
    for (int lyr = 0; lyr < 4; ++lyr) {
      ln_k<<<MREAL, 256, 0, stream>>>(tokens, lng + lyr * 1024, hbuf);
      transpose_cvt<<<dim3(32, 32), tb, 0, stream>>>(
          wq + (int64_t)lyr * 1024 * 1024, warena, 1024, 1024, 1024);
      transpose_cvt<<<dim3(32, 64), tb, 0, stream>>>(
          wkv + (int64_t)lyr * 1024 * 2048, warena + (size_t)1024 * 1024, 1024, 2048, 1024);
      gemm_bt<EPI_QKV><<<dim3(24, 33), 512, 0, stream>>>(
          hbuf, warena, 1024, MREAL, nullptr, qb, kbuf, vTbuf, nullptr);
      attn_k<<<dim3(17, 64), 256, 0, stream>>>(qb, kbuf, vTbuf, hbuf);
      transpose_cvt<<<dim3(32, 32), tb, 0, stream>>>(
          wo + (int64_t)lyr * 1024 * 1024, warena, 1024, 1024, 1024);
      gemm_bt<EPI_TOKADD><<<dim3(8, 33, 2), 512, 0, stream>>>(
          hbuf, warena, 1024, MREAL, tokens, nullptr, nullptr, nullptr, nullptr);
      ln_k<<<MREAL, 256, 0, stream>>>(tokens, lng + lyr * 1024, hbuf);
      transpose_w1<<<dim3(32, FF2P / 32), tb, 0, stream>>>(
          w1 + (int64_t)lyr * 1024 * 5460, warena);
      gemm_bt<EPI_GG><<<dim3(FF2P / 128, 33), 512, 0, stream>>>(
          hbuf, warena, 1024, MREAL, nullptr, nullptr, nullptr, nullptr, h2buf);
      transpose_cvt<<<dim3(FFP / 32, 32), tb, 0, stream>>>(
          w2 + (int64_t)lyr * 2730 * 1024, warena, 2730, 1024, FFP);
      gemm_bt<EPI_TOKADD><<<dim3(8, 33, 2), 512, 0, stream>>>(
          h2buf, warena, FFP, MREAL, tokens, nullptr, nullptr, nullptr, nullptr);
    }
    ln_k<<<MREAL, 256, 0, stream>>>(tokens, fg, hbuf);
  }

  transpose_cvt<<<dim3(32, 64), tb, 0, stream>>>(pwkv, warena, 1024, 2048, 1024);
  gemm_bt<EPI_KV><<<dim3(16, 33), 512, 0, stream>>>(
      hbuf, warena, 1024, MREAL, nullptr, nullptr, kbuf, vTbuf, nullptr);
  poolq_k<<<dim3(4, 16), 256, 0, stream>>>(rtk, pwq, qP);
  pool_attn_k<<<64, 64, 0, stream>>>(qP, kbuf, vTbuf, poolO);
  fout_k<<<dim3(4, 16), 256, 0, stream>>>(poolO, pwo, rtk, out);
}

// Round 10
// 1581.146 us; speedup vs baseline: 1.1872x; 1.0768x over previous
//
#include <hip/hip_runtime.h>
#include <stdint.h>

// ---------------------------------------------------------------------------
// Zorro-style multimodal transformer, B=4, N=1040 (512+512+16 fusion), D=1024,
// H=16, DH=64, L=4, FF=2730 gated-GELU; final LN + 4-token masked pool attn.
// bf16 MFMA GEMMs; block-mask flash attention (contiguous col ranges).
// R5: swapped-operand QK^T attention (S^T = mfma(K,Q)); LDS-free softmax.
// R7: gemm_bt 2-phase pipeline: double-buffered [2][128x64] LDS tiles, XOR
//     column swizzle both-sides (bank conflicts 2.97M -> 0, verified R8).
// R9: EPI_DELTA + add_ln_k kill the atomic residual epilogue (-75 us).
// R11: grouped block-order remap (G=4 supertiles): GG 102->77us, Mfma 10->26%.
// R12: 512-thread gemm_bt (8 waves, wave tile 64x32): total 1767->1703.
// R13: split-K tail matvecs. R12 PMC: top dispatch is fout_k @71us, 60 GB/s,
//     VALU 2%, Occ 2.6% -- 64-block grid with serial 1024-deep K loop, pure
//     latency exposure (poolq_k is its twin). fout/poolq -> 8-slice split-K
//     partials (512 blocks) + tiny reduce; ~140us -> ~10us predicted.
// R14: identical resubmit (R13 bench was the recurring first-submit infra
//     flake; audit found no crash mechanism — precedent R5/R7/R9 resubmits).
// ---------------------------------------------------------------------------

#define DEV __device__ __forceinline__

typedef unsigned short u16;
typedef __attribute__((ext_vector_type(8))) __bf16 bf16x8;
typedef __attribute__((ext_vector_type(4))) float floatx4;

DEV u16 f2bf(float f) {
  union { float f; unsigned u; } v; v.f = f;
  return (u16)((v.u + 0x7fffu + ((v.u >> 16) & 1u)) >> 16);  // RNE
}
DEV float bf2f(u16 s) {
  union { unsigned u; float f; } v; v.u = ((unsigned)s) << 16;
  return v.f;
}

#define MFMA(a, b, c) __builtin_amdgcn_mfma_f32_16x16x32_bf16(a, b, c, 0, 0, 0)

DEV void gld16(const u16* g, u16* l) {
  __builtin_amdgcn_global_load_lds((__attribute__((address_space(1))) void*)g,
                                   (__attribute__((address_space(3))) void*)l,
                                   16, 0, 0);
}

// V^T column permutation: mfma k-slot (quad,e) holds logical kv
// pi(quad,e) = quad*4 + (e&3) + 16*(e>>2). sigma = pi^-1 maps kv offset j
// (within a 32 block) to its k-slot. Writing V[rb][d] at column
// (rb&~31)|sigma(rb&31) makes PV B-fragments contiguous b128 loads.
DEV int vperm32(int j) {
  return (((j >> 2) & 3) << 3) | (j & 3) | (((j >> 4) & 1) << 2);
}

// ---------------- constants ----------------
#define MREAL 4160   /* B*N = 4*1040 */
#define MPAD  4224   /* 33*128 */
#define NPAD  1056   /* 1040 padded to x32 */
#define FFP   2816   /* 2730 padded to x64 (split-K=2 -> 1408 = 22*64) */
#define FF2P  5632

// ---------------- weight conversion ----------------
// out[n*Kstride + k] = (k < Kin) ? bf16(in[k*N + n]) : 0    (B^T bf16 layout)
__global__ __launch_bounds__(256) void transpose_cvt(
    const float* __restrict__ in, u16* __restrict__ out,
    int Kin, int N, int Kstride) {
  __shared__ float tile[32][33];
  const int k0 = blockIdx.x * 32, n0 = blockIdx.y * 32;
  const int tx = threadIdx.x, ty = threadIdx.y;
#pragma unroll
  for (int i = 0; i < 4; i++) {
    int k = k0 + ty + i * 8;
    tile[ty + i * 8][tx] = (k < Kin) ? in[(int64_t)k * N + n0 + tx] : 0.f;
  }
  __syncthreads();
#pragma unroll
  for (int i = 0; i < 4; i++) {
    int n = n0 + ty + i * 8;
    int k = k0 + tx;
    if (k < Kstride) out[(int64_t)n * Kstride + k] = f2bf(tile[tx][ty + i * 8]);
  }
}

// ff_w1 [1024 x 5460] -> w1T [5632 x 1024] bf16 with val/gate 16-col interleave:
// out row r: vi = (r/32)*16 + r%16 ; gate if (r/16)&1 ; src col = gate? 2730+vi : vi
__global__ __launch_bounds__(256) void transpose_w1(
    const float* __restrict__ in, u16* __restrict__ out) {
  __shared__ float tile[32][33];
  const int k0 = blockIdx.x * 32;        // D dim
  const int r0 = blockIdx.y * 32;        // output-row dim
  const int tx = threadIdx.x, ty = threadIdx.y;
  const int vb = (r0 >> 5) << 4;         // = r0/2
  const int vi = vb + (tx & 15);
  const int c = (tx < 16) ? vi : 2730 + vi;
  const bool valid = vi < 2730;
#pragma unroll
  for (int i = 0; i < 4; i++) {
    int k = k0 + ty + i * 8;
    tile[ty + i * 8][tx] = valid ? in[(int64_t)k * 5460 + c] : 0.f;
  }
  __syncthreads();
#pragma unroll
  for (int i = 0; i < 4; i++) {
    int rl = ty + i * 8;
    out[(int64_t)(r0 + rl) * 1024 + k0 + tx] = f2bf(tile[tx][rl]);
  }
}

// ---------------- tokens assembly ----------------
__global__ __launch_bounds__(256) void build_tokens_k(
    const float* __restrict__ m0p, const float* __restrict__ m1p,
    const float* __restrict__ fus, float* __restrict__ tokens) {
  const int n = blockIdx.x, b = blockIdx.y, t = threadIdx.x;
  const float* src = (n < 512) ? m0p + ((int64_t)b * 512 + n) * 1024
                   : (n < 1024) ? m1p + ((int64_t)b * 512 + (n - 512)) * 1024
                                : fus + (int64_t)(n - 1024) * 1024;
  float4 v = ((const float4*)src)[t];
  ((float4*)(tokens + ((int64_t)b * 1040 + n) * 1024))[t] = v;
}

// ---------------- layernorm (f32 in, bf16 out) ----------------
__global__ __launch_bounds__(256) void ln_k(const float* __restrict__ x,
                                            const float* __restrict__ gamma,
                                            u16* __restrict__ out) {
  const int r = blockIdx.x, t = threadIdx.x;
  const float4 v = ((const float4*)(x + (int64_t)r * 1024))[t];
  float s = v.x + v.y + v.z + v.w;
  float q = v.x * v.x + v.y * v.y + v.z * v.z + v.w * v.w;
#pragma unroll
  for (int off = 32; off >= 1; off >>= 1) {
    s += __shfl_xor(s, off);
    q += __shfl_xor(q, off);
  }
  __shared__ float red[8];
  const int w = t >> 6, l = t & 63;
  if (l == 0) { red[w] = s; red[4 + w] = q; }
  __syncthreads();
  s = red[0] + red[1] + red[2] + red[3];
  q = red[4] + red[5] + red[6] + red[7];
  const float mu = s * (1.f / 1024.f);
  const float var = q * (1.f / 1024.f) - mu * mu;
  const float rs = rsqrtf(var + 1e-5f);
  const float4 g = ((const float4*)gamma)[t];
  u16* op = out + (int64_t)r * 1024 + t * 4;
  op[0] = f2bf((v.x - mu) * rs * g.x);
  op[1] = f2bf((v.y - mu) * rs * g.y);
  op[2] = f2bf((v.z - mu) * rs * g.z);
  op[3] = f2bf((v.w - mu) * rs * g.w);
}

// ---------------- fused residual-add + layernorm ----------------
// tokens += d0 (+ d1); optionally write tokens back; LN(tokens)*gamma -> out.
__global__ __launch_bounds__(256) void add_ln_k(
    float* __restrict__ x, const float* __restrict__ d0,
    const float* __restrict__ d1, const float* __restrict__ gamma,
    u16* __restrict__ out, int two, int writeback) {
  const int r = blockIdx.x, t = threadIdx.x;
  const int64_t off = (int64_t)r * 1024 + t * 4;
  float4 v = *(const float4*)(x + off);
  {
    const float4 a = *(const float4*)(d0 + off);
    v.x += a.x; v.y += a.y; v.z += a.z; v.w += a.w;
  }
  if (two) {
    const float4 a = *(const float4*)(d1 + off);
    v.x += a.x; v.y += a.y; v.z += a.z; v.w += a.w;
  }
  if (writeback) *(float4*)(x + off) = v;
  float s = v.x + v.y + v.z + v.w;
  float q = v.x * v.x + v.y * v.y + v.z * v.z + v.w * v.w;
#pragma unroll
  for (int off2 = 32; off2 >= 1; off2 >>= 1) {
    s += __shfl_xor(s, off2);
    q += __shfl_xor(q, off2);
  }
  __shared__ float red[8];
  const int w = t >> 6, l = t & 63;
  if (l == 0) { red[w] = s; red[4 + w] = q; }
  __syncthreads();
  s = red[0] + red[1] + red[2] + red[3];
  q = red[4] + red[5] + red[6] + red[7];
  const float mu = s * (1.f / 1024.f);
  const float var = q * (1.f / 1024.f) - mu * mu;
  const float rs = rsqrtf(var + 1e-5f);
  const float4 g = ((const float4*)gamma)[t];
  u16* op = out + (int64_t)r * 1024 + t * 4;
  op[0] = f2bf((v.x - mu) * rs * g.x);
  op[1] = f2bf((v.y - mu) * rs * g.y);
  op[2] = f2bf((v.z - mu) * rs * g.z);
  op[3] = f2bf((v.w - mu) * rs * g.w);
}

// ---------------- MFMA GEMM: C[M,N] = A[M,K](bf16) @ Bt[N,K](bf16) ----------------
enum { EPI_QKV = 0, EPI_KV = 1, EPI_TOKADD = 2, EPI_GG = 3, EPI_DELTA = 4 };

// 512 threads = 8 waves (2M x 4N), wave tile 64x32, acc[4][2].
// Kstr = row stride of A and Bt; per-z K-range = Kstr / gridDim.z (mult of 64).
// 2-phase pipeline: LDS tiles [2][128 rows][64 cols] per operand (64 KiB);
// next K-tile staged via global_load_lds BEFORE the current tile's
// ds_read+MFMA, one __syncthreads per K-step (drains vmcnt+lgkm).
// LDS col swizzle: 16B-column qphys = qlog ^ (row&7), applied by pre-swizzling
// the GLOBAL source column (LDS dest stays wave-linear) and on the read side.
// Grouped block-order remap: linear wg id -> (bx,by) in supertiles of G=4
// B-panels x all M-rows (per-XCD L2 working-set fit).
template <int EPI>
__global__ __launch_bounds__(512) void gemm_bt(
    const u16* __restrict__ A, const u16* __restrict__ Bt,
    int Kstr, int Mreal,
    float* __restrict__ tokens, u16* __restrict__ oq, u16* __restrict__ ok,
    u16* __restrict__ ovT, u16* __restrict__ oh2) {
  __shared__ __align__(16) u16 lA[2][128 * 64];
  __shared__ __align__(16) u16 lB[2][128 * 64];
  const int t = threadIdx.x;
  const int w = t >> 6, l = t & 63;
  const int lane16 = l & 15, quad = l >> 4;

  // ---- grouped block-order remap (bijective) ----
  const int nbx = gridDim.x, nby = gridDim.y;
  const int lin = blockIdx.y * nbx + blockIdx.x;
  const int ngf = nbx >> 2;            // full groups of G=4
  const int base = ngf * 4 * nby;
  int bx, by;
  if (lin < base) {
    const int g = lin / (nby * 4);
    const int r = lin - g * nby * 4;
    bx = (g << 2) + (r & 3);
    by = r >> 2;
  } else {  // tail group (nbx % 4 != 0) — unused for our shapes, kept safe
    const int W = nbx - (ngf << 2);
    const int r = lin - base;
    bx = (ngf << 2) + r % W;
    by = r / W;
  }
  const int m0 = by * 128, n0 = bx * 128;
  const int wm = (w >> 2) * 64, wn = (w & 3) * 32;  // wave tile 64x32

  const int Klen = Kstr / gridDim.z;
  const int koff = blockIdx.z * Klen;

  const floatx4 fz = {0.f, 0.f, 0.f, 0.f};
  floatx4 acc[4][2];
#pragma unroll
  for (int i = 0; i < 4; i++)
#pragma unroll
    for (int j = 0; j < 2; j++) acc[i][j] = fz;

  // Staging (512 thr): thread t -> rows rowS=t>>3 and rowS+64, 16B col (t&7),
  // pre-swizzled source col so lds[row][q] = A[row][ (q ^ (row&7))*8 .. +7 ]
  // ((row+64)&7 == row&7, so one scol serves both rows).
  const int rowS = t >> 3;
  const int scol = (((t & 7) ^ (rowS & 7)) << 3);
  const u16* gAs = A + (int64_t)(m0 + rowS) * Kstr + koff + scol;
  const u16* gBs = Bt + (int64_t)(n0 + rowS) * Kstr + koff + scol;
  const int64_t rsk64 = (int64_t)64 * Kstr;

  // Fragment-read swizzled 16B-column offsets (elements):
  const int rsw = lane16 & 7;
  const int cp0 = ((quad ^ rsw) << 3);        // k-substep 0 (k = quad*8)
  const int cp1 = (((quad + 4) ^ rsw) << 3);  // k-substep 1 (k = 32 + quad*8)

  auto stage = [&](int buf, int kt) {
    const u16* ga = gAs + kt;
    const u16* gb = gBs + kt;
    u16* la = &lA[buf][0] + t * 8;
    u16* lb = &lB[buf][0] + t * 8;
    gld16(ga, la);
    gld16(ga + rsk64, la + 4096);
    gld16(gb, lb);
    gld16(gb + rsk64, lb + 4096);
  };

  stage(0, 0);
  __syncthreads();
  int cur = 0;
  for (int kt = 0; kt < Klen; kt += 64) {
    if (kt + 64 < Klen) stage(cur ^ 1, kt + 64);
    const u16* la = &lA[cur][0] + (wm + lane16) * 64;
    const u16* lb = &lB[cur][0] + (wn + lane16) * 64;
    bf16x8 af[4], bf[2];
#pragma unroll
    for (int i = 0; i < 4; i++) af[i] = *(const bf16x8*)(la + i * 16 * 64 + cp0);
#pragma unroll
    for (int j = 0; j < 2; j++) bf[j] = *(const bf16x8*)(lb + j * 16 * 64 + cp0);
#pragma unroll
    for (int i = 0; i < 4; i++)
#pragma unroll
      for (int j = 0; j < 2; j++) acc[i][j] = MFMA(af[i], bf[j], acc[i][j]);
#pragma unroll
    for (int i = 0; i < 4; i++) af[i] = *(const bf16x8*)(la + i * 16 * 64 + cp1);
#pragma unroll
    for (int j = 0; j < 2; j++) bf[j] = *(const bf16x8*)(lb + j * 16 * 64 + cp1);
#pragma unroll
    for (int i = 0; i < 4; i++)
#pragma unroll
      for (int j = 0; j < 2; j++) acc[i][j] = MFMA(af[i], bf[j], acc[i][j]);
    __syncthreads();
    cur ^= 1;
  }

  // Epilogues. C-layout: lane holds row = quad*4+reg, col = lane16 within frag.
  if constexpr (EPI == EPI_TOKADD) {
    const bool atomic = gridDim.z > 1;
#pragma unroll
    for (int i = 0; i < 4; i++) {
      const int mb = m0 + wm + i * 16 + quad * 4;
#pragma unroll
      for (int reg = 0; reg < 4; reg++) {
        const int m = mb + reg;
        if (m < Mreal) {
          float* tp = tokens + (int64_t)m * 1024;
#pragma unroll
          for (int j = 0; j < 2; j++) {
            const int n = n0 + wn + j * 16 + lane16;
            if (atomic) atomicAdd(tp + n, acc[i][j][reg]);
            else tp[n] += acc[i][j][reg];
          }
        }
      }
    }
  } else if constexpr (EPI == EPI_DELTA) {
    // Plain f32 partial-sum store into per-z delta buffer (no atomics).
    float* dp = tokens + (int64_t)blockIdx.z * MREAL * 1024;
#pragma unroll
    for (int i = 0; i < 4; i++) {
      const int mb = m0 + wm + i * 16 + quad * 4;
#pragma unroll
      for (int reg = 0; reg < 4; reg++) {
        const int m = mb + reg;
        if (m < Mreal) {
          float* tp = dp + (int64_t)m * 1024;
#pragma unroll
          for (int j = 0; j < 2; j++) {
            const int n = n0 + wn + j * 16 + lane16;
            tp[n] = acc[i][j][reg];
          }
        }
      }
    }
  } else if constexpr (EPI == EPI_QKV) {
    // cols [0,1024): Q (scaled), [1024,2048): K, [2048,3072): V^T (permuted cols)
#pragma unroll
    for (int i = 0; i < 4; i++) {
      const int mb = m0 + wm + i * 16 + quad * 4;
#pragma unroll
      for (int reg = 0; reg < 4; reg++) {
        const int m = mb + reg;
        if (m < Mreal) {
          const int b = m / 1040, rb = m % 1040;
          const int rbp = (rb & ~31) | vperm32(rb & 31);
#pragma unroll
          for (int j = 0; j < 2; j++) {
            const int n = n0 + wn + j * 16 + lane16;
            const float v = acc[i][j][reg];
            if (n < 1024) {
              const int hd = n >> 6, d = n & 63;
              oq[(((int64_t)b * 16 + hd) * NPAD + rb) * 64 + d] = f2bf(v * 0.125f);
            } else if (n < 2048) {
              const int n2 = n - 1024;
              const int hd = n2 >> 6, d = n2 & 63;
              ok[(((int64_t)b * 16 + hd) * NPAD + rb) * 64 + d] = f2bf(v);
            } else {
              const int n2 = n - 2048;
              const int hd = n2 >> 6, d = n2 & 63;
              ovT[(((int64_t)b * 16 + hd) * 64 + d) * NPAD + rbp] = f2bf(v);
            }
          }
        }
      }
    }
  } else if constexpr (EPI == EPI_KV) {
#pragma unroll
    for (int i = 0; i < 4; i++) {
      const int mb = m0 + wm + i * 16 + quad * 4;
#pragma unroll
      for (int reg = 0; reg < 4; reg++) {
        const int m = mb + reg;
        if (m < Mreal) {
          const int b = m / 1040, rb = m % 1040;
          const int rbp = (rb & ~31) | vperm32(rb & 31);
#pragma unroll
          for (int j = 0; j < 2; j++) {
            const int n = n0 + wn + j * 16 + lane16;
            const float v = acc[i][j][reg];
            if (n < 1024) {
              const int hd = n >> 6, d = n & 63;
              ok[(((int64_t)b * 16 + hd) * NPAD + rb) * 64 + d] = f2bf(v);
            } else {
              const int n2 = n - 1024;
              const int hd = n2 >> 6, d = n2 & 63;
              ovT[(((int64_t)b * 16 + hd) * 64 + d) * NPAD + rbp] = f2bf(v);
            }
          }
        }
      }
    }
  } else {  // EPI_GG: cols are (val,gate) alternating 16-groups; wave tile has
            // exactly one (val,gate) pair: j=0 val, j=1 gate (wn multiple of 32)
#pragma unroll
    for (int i = 0; i < 4; i++) {
      const int mb = m0 + wm + i * 16 + quad * 4;
#pragma unroll
      for (int reg = 0; reg < 4; reg++) {
        const int m = mb + reg;
        u16* hp = oh2 + (int64_t)m * FFP;
        const float val = acc[i][0][reg];
        const float g = acc[i][1][reg];
        const float ge = 0.5f * g * (1.f + erff(g * 0.70710678118654752f));
        const int vi = (((n0 + wn) >> 5) << 4) + lane16;
        hp[vi] = f2bf(val * ge);
      }
    }
  }
}

// ---------------- block-mask flash attention (swapped QK^T, LDS-free) -------
// S^T = mfma(K, Q): lane (quad,lane16) holds S[kv = c0 + {quad*4+r, 16+quad*4+r}]
// [q = lane16]. Row stats are per-lane; reduce = in-lane tree + shfl_xor(16,32).
// P -> PV A-fragment is a pure register repack (k-slot (quad,e) <-> kv
// pi(quad,e) = quad*4+(e&3)+16*(e>>2)); V^T is stored with sigma=pi^-1
// permuted columns so B-fragments are contiguous b128 loads.
__global__ __launch_bounds__(256) void attn_k(const u16* __restrict__ qb,
                                              const u16* __restrict__ kb,
                                              const u16* __restrict__ vTb,
                                              u16* __restrict__ ao) {
  const int t = threadIdx.x, w = t >> 6, l = t & 63;
  const int lane16 = l & 15, quad = l >> 4;
  const int kvb = quad * 4;
  const int bh = blockIdx.y, b = bh >> 4, h = bh & 15;
  const int row0 = blockIdx.x * 64 + w * 16;
  if (row0 >= 1040) return;
  const int type = (row0 < 512) ? 0 : (row0 < 1024 ? 1 : 2);
  const int cbeg = (type == 1) ? 512 : 0;
  const int cend = (type == 0) ? 512 : (type == 1 ? 1024 : 1040);
  const int niter = (cend - cbeg + 31) >> 5;

  const u16* qp = qb + ((int64_t)bh * NPAD + row0 + lane16) * 64 + quad * 8;
  const bf16x8 a0 = *(const bf16x8*)qp;
  const bf16x8 a1 = *(const bf16x8*)(qp + 32);
  const u16* vbase = vTb + ((int64_t)bh * 64 + lane16) * NPAD + quad * 8;

  const floatx4 fz = {0.f, 0.f, 0.f, 0.f};
  floatx4 O[4] = {fz, fz, fz, fz};
  float mrow = -1e30f, lrow = 0.f;

  for (int it = 0; it < niter; ++it) {
    const int c0 = cbeg + it * 32;
    const u16* kp = kb + ((int64_t)bh * NPAD + c0 + lane16) * 64 + quad * 8;
    const bf16x8 b00 = *(const bf16x8*)kp;
    const bf16x8 b01 = *(const bf16x8*)(kp + 32);
    const bf16x8 b10 = *(const bf16x8*)(kp + 16 * 64);
    const bf16x8 b11 = *(const bf16x8*)(kp + 16 * 64 + 32);
    floatx4 s0 = MFMA(b00, a0, fz); s0 = MFMA(b01, a1, s0);
    floatx4 s1 = MFMA(b10, a0, fz); s1 = MFMA(b11, a1, s1);
    if (c0 + 32 > cend) {  // fusion tail mask (kv >= cend)
#pragma unroll
      for (int r = 0; r < 4; r++) {
        if (c0 + kvb + r >= cend) s0[r] = -1e30f;
        if (c0 + 16 + kvb + r >= cend) s1[r] = -1e30f;
      }
    }
    float tm = fmaxf(fmaxf(fmaxf(s0[0], s0[1]), fmaxf(s0[2], s0[3])),
                     fmaxf(fmaxf(s1[0], s1[1]), fmaxf(s1[2], s1[3])));
    tm = fmaxf(tm, __shfl_xor(tm, 16));
    tm = fmaxf(tm, __shfl_xor(tm, 32));
    if (!__all(tm <= mrow)) {  // exact skip: when taken-not, a_ == 1 exactly
      const float mn = fmaxf(mrow, tm);
      const float a_ = __expf(mrow - mn);
      mrow = mn;
      lrow *= a_;
      const float al0 = __shfl(a_, kvb + 0, 16);
      const float al1 = __shfl(a_, kvb + 1, 16);
      const float al2 = __shfl(a_, kvb + 2, 16);
      const float al3 = __shfl(a_, kvb + 3, 16);
#pragma unroll
      for (int dt = 0; dt < 4; dt++) {
        O[dt][0] *= al0; O[dt][1] *= al1; O[dt][2] *= al2; O[dt][3] *= al3;
      }
    }
    float p0[4], p1[4];
#pragma unroll
    for (int r = 0; r < 4; r++) {
      p0[r] = __expf(s0[r] - mrow);
      p1[r] = __expf(s1[r] - mrow);
    }
    float ps = ((p0[0] + p0[1]) + (p0[2] + p0[3])) +
               ((p1[0] + p1[1]) + (p1[2] + p1[3]));
    ps += __shfl_xor(ps, 16);
    ps += __shfl_xor(ps, 32);
    lrow += ps;
    union { bf16x8 v; u16 s[8]; } pf;
#pragma unroll
    for (int r = 0; r < 4; r++) {
      pf.s[r] = f2bf(p0[r]);
      pf.s[4 + r] = f2bf(p1[r]);
    }
#pragma unroll
    for (int dt = 0; dt < 4; dt++) {
      const bf16x8 bv = *(const bf16x8*)(vbase + (int64_t)dt * 16 * NPAD + c0);
      O[dt] = MFMA(pf.v, bv, O[dt]);
    }
  }
  float lr[4];
#pragma unroll
  for (int r = 0; r < 4; r++) lr[r] = __shfl(lrow, kvb + r, 16);
#pragma unroll
  for (int dt = 0; dt < 4; dt++)
#pragma unroll
    for (int r = 0; r < 4; r++) {
      const int row = row0 + kvb + r;
      ao[((int64_t)b * 1040 + row) * 1024 + h * 64 + dt * 16 + lane16] =
          f2bf(O[dt][r] / lr[r]);
    }
}

// ---------------- pool q, split-K: qpart[kz][r][n] = partial dot ----------------
__global__ __launch_bounds__(256) void poolq_split_k(
    const float* __restrict__ rtk, const float* __restrict__ pwq,
    float* __restrict__ qpart) {
  const int n = blockIdx.x * 256 + threadIdx.x;  // 4 blocks
  const int r = blockIdx.y;                      // 4 real rows
  const int kz = blockIdx.z;                     // 8 K-slices of 128
  const float* x = rtk + (int64_t)r * 1024 + kz * 128;
  const float* wp = pwq + (int64_t)(kz * 128) * 1024 + n;
  float acc = 0.f;
#pragma unroll 8
  for (int k = 0; k < 128; k++) acc += x[k] * wp[(int64_t)k * 1024];
  qpart[((int64_t)kz * 4 + r) * 1024 + n] = acc;
}

// qP rows 4..15 are zeroed (pool_attn pads q-rows to 16; keeps garbage out of
// the wave-uniform defer-max branch).
__global__ __launch_bounds__(256) void poolq_reduce_k(
    const float* __restrict__ qpart, u16* __restrict__ qP) {
  const int n = blockIdx.x * 256 + threadIdx.x;
  const int r = blockIdx.y;  // 16
  if (r >= 4) { qP[(int64_t)r * 1024 + n] = 0; return; }
  float acc = 0.f;
#pragma unroll
  for (int kz = 0; kz < 8; kz++) acc += qpart[((int64_t)kz * 4 + r) * 1024 + n];
  qP[(int64_t)r * 1024 + n] = f2bf(acc * 0.125f);
}

// ---------------- pool attention: 1 wave per (b,h), 4 real q-rows ----------------
DEV bool pvalid(int r, int c) {
  if (r == 0) return c < 512;
  if (r == 1) return (c >= 512) && (c < 1024);
  if (r == 2) return (c >= 1024) && (c < 1040);
  return c < 1040;  // GLOBAL row + pad rows
}

__global__ __launch_bounds__(64) void pool_attn_k(const u16* __restrict__ qP,
                                                  const u16* __restrict__ kb,
                                                  const u16* __restrict__ vTb,
                                                  u16* __restrict__ po) {
  const int l = threadIdx.x;
  const int lane16 = l & 15, quad = l >> 4;
  const int kvb = quad * 4;
  const int bh = blockIdx.x, b = bh >> 4, h = bh & 15;
  const u16* qp = qP + (int64_t)lane16 * 1024 + h * 64 + quad * 8;
  const bf16x8 a0 = *(const bf16x8*)qp;
  const bf16x8 a1 = *(const bf16x8*)(qp + 32);
  const u16* vbase = vTb + ((int64_t)bh * 64 + lane16) * NPAD + quad * 8;
  const floatx4 fz = {0.f, 0.f, 0.f, 0.f};
  floatx4 O[4] = {fz, fz, fz, fz};
  float mrow = -1e30f, lrow = 0.f;
  for (int it = 0; it < 33; ++it) {
    const int c0 = it * 32;
    const u16* kp = kb + ((int64_t)bh * NPAD + c0 + lane16) * 64 + quad * 8;
    const bf16x8 b00 = *(const bf16x8*)kp;
    const bf16x8 b01 = *(const bf16x8*)(kp + 32);
    const bf16x8 b10 = *(const bf16x8*)(kp + 16 * 64);
    const bf16x8 b11 = *(const bf16x8*)(kp + 16 * 64 + 32);
    floatx4 s0 = MFMA(b00, a0, fz); s0 = MFMA(b01, a1, s0);
    floatx4 s1 = MFMA(b10, a0, fz); s1 = MFMA(b11, a1, s1);
#pragma unroll
    for (int r = 0; r < 4; r++) {
      if (!pvalid(lane16, c0 + kvb + r)) s0[r] = -1e30f;
      if (!pvalid(lane16, c0 + 16 + kvb + r)) s1[r] = -1e30f;
    }
    float tm = fmaxf(fmaxf(fmaxf(s0[0], s0[1]), fmaxf(s0[2], s0[3])),
                     fmaxf(fmaxf(s1[0], s1[1]), fmaxf(s1[2], s1[3])));
    tm = fmaxf(tm, __shfl_xor(tm, 16));
    tm = fmaxf(tm, __shfl_xor(tm, 32));
    if (!__all(tm <= mrow)) {
      const float mn = fmaxf(mrow, tm);
      const float a_ = __expf(mrow - mn);
      mrow = mn;
      lrow *= a_;
      const float al0 = __shfl(a_, kvb + 0, 16);
      const float al1 = __shfl(a_, kvb + 1, 16);
      const float al2 = __shfl(a_, kvb + 2, 16);
      const float al3 = __shfl(a_, kvb + 3, 16);
#pragma unroll
      for (int dt = 0; dt < 4; dt++) {
        O[dt][0] *= al0; O[dt][1] *= al1; O[dt][2] *= al2; O[dt][3] *= al3;
      }
    }
    float p0[4], p1[4];
#pragma unroll
    for (int r = 0; r < 4; r++) {
      p0[r] = __expf(s0[r] - mrow);
      p1[r] = __expf(s1[r] - mrow);
    }
    float ps = ((p0[0] + p0[1]) + (p0[2] + p0[3])) +
               ((p1[0] + p1[1]) + (p1[2] + p1[3]));
    ps += __shfl_xor(ps, 16);
    ps += __shfl_xor(ps, 32);
    lrow += ps;
    union { bf16x8 v; u16 s[8]; } pf;
#pragma unroll
    for (int r = 0; r < 4; r++) {
      pf.s[r] = f2bf(p0[r]);
      pf.s[4 + r] = f2bf(p1[r]);
    }
#pragma unroll
    for (int dt = 0; dt < 4; dt++) {
      const bf16x8 bv = *(const bf16x8*)(vbase + (int64_t)dt * 16 * NPAD + c0);
      O[dt] = MFMA(pf.v, bv, O[dt]);
    }
  }
  float lr[4];
#pragma unroll
  for (int r = 0; r < 4; r++) lr[r] = __shfl(lrow, r, 16);
  if (quad == 0) {  // output C rows quad*4+reg -> quad0 holds real rows 0..3
#pragma unroll
    for (int dt = 0; dt < 4; dt++)
#pragma unroll
      for (int r = 0; r < 4; r++)
        po[((int64_t)b * 4 + r) * 1024 + h * 64 + dt * 16 + lane16] =
            f2bf(O[dt][r] / lr[r]);
  }
}

// ---------------- final matvec, split-K: fpart[kz][row][n] ----------------
__global__ __launch_bounds__(256) void fout_split_k(
    const u16* __restrict__ po, const float* __restrict__ pwo,
    float* __restrict__ fpart) {
  const int n = blockIdx.x * 256 + threadIdx.x;  // 4 blocks
  const int row = blockIdx.y;                    // 16 (b*4 + r)
  const int kz = blockIdx.z;                     // 8 K-slices of 128
  const u16* x = po + (int64_t)row * 1024 + kz * 128;
  const float* wp = pwo + (int64_t)(kz * 128) * 1024 + n;
  float acc = 0.f;
#pragma unroll 8
  for (int k = 0; k < 128; k++) acc += bf2f(x[k]) * wp[(int64_t)k * 1024];
  fpart[((int64_t)kz * 16 + row) * 1024 + n] = acc;
}

__global__ __launch_bounds__(256) void fout_reduce_k(
    const float* __restrict__ fpart, const float* __restrict__ rtk,
    float* __restrict__ out) {
  const int n = blockIdx.x * 256 + threadIdx.x;
  const int row = blockIdx.y;  // 16
  float acc = rtk[(int64_t)(row & 3) * 1024 + n];
#pragma unroll
  for (int kz = 0; kz < 8; kz++)
    acc += fpart[((int64_t)kz * 16 + row) * 1024 + n];
  out[(int64_t)row * 1024 + n] = acc;
}

// ---------------------------------------------------------------------------
extern "C" void kernel_launch(void* const* d_in, const int* in_sizes, int n_in,
                              void* d_out, int out_size, void* d_ws, size_t ws_size,
                              hipStream_t stream) {
  (void)in_sizes; (void)n_in; (void)out_size;
  const float* m0p  = (const float*)d_in[0];
  const float* m1p  = (const float*)d_in[1];
  const float* fus  = (const float*)d_in[2];
  const float* rtk  = (const float*)d_in[3];
  const float* lng  = (const float*)d_in[4];
  const float* wq   = (const float*)d_in[5];
  const float* wkv  = (const float*)d_in[6];
  const float* wo   = (const float*)d_in[7];
  const float* w1   = (const float*)d_in[8];
  const float* w2   = (const float*)d_in[9];
  const float* pwq  = (const float*)d_in[10];
  const float* pwkv = (const float*)d_in[11];
  const float* pwo  = (const float*)d_in[12];
  const float* fg   = (const float*)d_in[13];
  float* out = (float*)d_out;

  char* p = (char*)d_ws;
  auto alloc = [&](size_t bytes) -> char* {
    char* r = p;
    p += (bytes + 255) & ~(size_t)255;
    return r;
  };
  // Base footprint ~64 MB.
  u16* warena = (u16*)alloc((size_t)FF2P * 1024 * 2);       // 11.5 MB, per-GEMM weights
  float* tokens = (float*)alloc((size_t)MREAL * 1024 * 4);  // 17.04 MB
  u16* hbuf  = (u16*)alloc((size_t)MPAD * 1024 * 2);        // 8.65 MB (LN out + attn out)
  u16* qb    = (u16*)alloc((size_t)64 * NPAD * 64 * 2);     // 8.65 MB
  u16* kbuf  = (u16*)alloc((size_t)64 * NPAD * 64 * 2);     // 8.65 MB
  u16* vTbuf = (u16*)alloc((size_t)64 * NPAD * 64 * 2);     // 8.65 MB
  u16* h2buf = qb;  // 23.8 MB alias over qb+kbuf+vTbuf (25.95 MB): dead between
                    // attn read and next layer's Q/KV writes; stale k/vT tail
                    // rows [1040,1056) are masked (-1e30) / multiplied by p=0.
  u16* qP    = (u16*)alloc((size_t)16 * 1024 * 2);
  u16* poolO = (u16*)alloc((size_t)16 * 1024 * 2);
  float* qpart = (float*)alloc((size_t)8 * 4 * 1024 * 4);   // 128 KB
  float* fpart = (float*)alloc((size_t)8 * 16 * 1024 * 4);  // 512 KB

  // Residual-delta buffers (mode 2: two z-slices; mode 1: one; mode 0: legacy
  // atomic path). Chosen by available workspace — no risk if ws is tight.
  const size_t DELTA_BYTES = (size_t)MREAL * 1024 * 4;  // 17.04 MB
  const size_t base_used = (size_t)(p - (char*)d_ws);
  int mode = 0;
  float* d0 = nullptr;
  float* d1 = nullptr;
  if (ws_size >= base_used + 2 * DELTA_BYTES + 1024) {
    mode = 2;
    d0 = (float*)alloc(2 * DELTA_BYTES);
    d1 = d0 + (size_t)MREAL * 1024;  // contiguous: blockIdx.z indexes it
  } else if (ws_size >= base_used + DELTA_BYTES + 1024) {
    mode = 1;
    d0 = (float*)alloc(DELTA_BYTES);
    d1 = d0;  // unused (two=0)
  }

  const dim3 tb(32, 8, 1);
  build_tokens_k<<<dim3(1040, 4), 256, 0, stream>>>(m0p, m1p, fus, tokens);

  if (mode) {
    const int zz = mode;  // split-K factor for residual GEMMs
    const int two = (mode == 2);
    for (int lyr = 0; lyr < 4; ++lyr) {
      if (lyr == 0)
        ln_k<<<MREAL, 256, 0, stream>>>(tokens, lng, hbuf);
      else  // fold previous layer's FF2 delta into tokens + this pre-attn LN
        add_ln_k<<<MREAL, 256, 0, stream>>>(tokens, d0, d1, lng + lyr * 1024,
                                            hbuf, two, 1);
      transpose_cvt<<<dim3(32, 32), tb, 0, stream>>>(
          wq + (int64_t)lyr * 1024 * 1024, warena, 1024, 1024, 1024);
      transpose_cvt<<<dim3(32, 64), tb, 0, stream>>>(
          wkv + (int64_t)lyr * 1024 * 2048, warena + (size_t)1024 * 1024, 1024, 2048, 1024);
      gemm_bt<EPI_QKV><<<dim3(24, 33), 512, 0, stream>>>(
          hbuf, warena, 1024, MREAL, nullptr, qb, kbuf, vTbuf, nullptr);
      attn_k<<<dim3(17, 64), 256, 0, stream>>>(qb, kbuf, vTbuf, hbuf);
      transpose_cvt<<<dim3(32, 32), tb, 0, stream>>>(
          wo + (int64_t)lyr * 1024 * 1024, warena, 1024, 1024, 1024);
      gemm_bt<EPI_DELTA><<<dim3(8, 33, zz), 512, 0, stream>>>(
          hbuf, warena, 1024, MREAL, d0, nullptr, nullptr, nullptr, nullptr);
      add_ln_k<<<MREAL, 256, 0, stream>>>(tokens, d0, d1, lng + lyr * 1024,
                                          hbuf, two, 1);
      transpose_w1<<<dim3(32, FF2P / 32), tb, 0, stream>>>(
          w1 + (int64_t)lyr * 1024 * 5460, warena);
      gemm_bt<EPI_GG><<<dim3(FF2P / 128, 33), 512, 0, stream>>>(
          hbuf, warena, 1024, MREAL, nullptr, nullptr, nullptr, nullptr, h2buf);
      transpose_cvt<<<dim3(FFP / 32, 32), tb, 0, stream>>>(
          w2 + (int64_t)lyr * 2730 * 1024, warena, 2730, 1024, FFP);
      gemm_bt<EPI_DELTA><<<dim3(8, 33, zz), 512, 0, stream>>>(
          h2buf, warena, FFP, MREAL, d0, nullptr, nullptr, nullptr, nullptr);
    }
    // final: fold last FF2 delta + final LN (tokens dead after -> no writeback)
    add_ln_k<<<MREAL, 256, 0, stream>>>(tokens, d0, d1, fg, hbuf, two, 0);
  } else {
    for (int lyr = 0; lyr < 4; ++lyr) {
      ln_k<<<MREAL, 256, 0, stream>>>(tokens, lng + lyr * 1024, hbuf);
      transpose_cvt<<<dim3(32, 32), tb, 0, stream>>>(
          wq + (int64_t)lyr * 1024 * 1024, warena, 1024, 1024, 1024);
      transpose_cvt<<<dim3(32, 64), tb, 0, stream>>>(
          wkv + (int64_t)lyr * 1024 * 2048, warena + (size_t)1024 * 1024, 1024, 2048, 1024);
      gemm_bt<EPI_QKV><<<dim3(24, 33), 512, 0, stream>>>(
          hbuf, warena, 1024, MREAL, nullptr, qb, kbuf, vTbuf, nullptr);
      attn_k<<<dim3(17, 64), 256, 0, stream>>>(qb, kbuf, vTbuf, hbuf);
      transpose_cvt<<<dim3(32, 32), tb, 0, stream>>>(
          wo + (int64_t)lyr * 1024 * 1024, warena, 1024, 1024, 1024);
      gemm_bt<EPI_TOKADD><<<dim3(8, 33, 2), 512, 0, stream>>>(
          hbuf, warena, 1024, MREAL, tokens, nullptr, nullptr, nullptr, nullptr);
      ln_k<<<MREAL, 256, 0, stream>>>(tokens, lng + lyr * 1024, hbuf);
      transpose_w1<<<dim3(32, FF2P / 32), tb, 0, stream>>>(
          w1 + (int64_t)lyr * 1024 * 5460, warena);
      gemm_bt<EPI_GG><<<dim3(FF2P / 128, 33), 512, 0, stream>>>(
          hbuf, warena, 1024, MREAL, nullptr, nullptr, nullptr, nullptr, h2buf);
      transpose_cvt<<<dim3(FFP / 32, 32), tb, 0, stream>>>(
          w2 + (int64_t)lyr * 2730 * 1024, warena, 2730, 1024, FFP);
      gemm_bt<EPI_TOKADD><<<dim3(8, 33, 2), 512, 0, stream>>>(
          h2buf, warena, FFP, MREAL, tokens, nullptr, nullptr, nullptr, nullptr);
    }
    ln_k<<<MREAL, 256, 0, stream>>>(tokens, fg, hbuf);
  }

  transpose_cvt<<<dim3(32, 64), tb, 0, stream>>>(pwkv, warena, 1024, 2048, 1024);
  gemm_bt<EPI_KV><<<dim3(16, 33), 512, 0, stream>>>(
      hbuf, warena, 1024, MREAL, nullptr, nullptr, kbuf, vTbuf, nullptr);
  poolq_split_k<<<dim3(4, 4, 8), 256, 0, stream>>>(rtk, pwq, qpart);
  poolq_reduce_k<<<dim3(4, 16), 256, 0, stream>>>(qpart, qP);
  pool_attn_k<<<64, 64, 0, stream>>>(qP, kbuf, vTbuf, poolO);
  fout_split_k<<<dim3(4, 16, 8), 256, 0, stream>>>(poolO, pwo, fpart);
  fout_reduce_k<<<dim3(4, 16), 256, 0, stream>>>(fpart, rtk, out);
}

// Round 11
// 1580.628 us; speedup vs baseline: 1.1876x; 1.0003x over previous
//
#include <hip/hip_runtime.h>
#include <stdint.h>

// ---------------------------------------------------------------------------
// Zorro-style multimodal transformer, B=4, N=1040 (512+512+16 fusion), D=1024,
// H=16, DH=64, L=4, FF=2730 gated-GELU; final LN + 4-token masked pool attn.
// bf16 MFMA GEMMs; block-mask flash attention (contiguous col ranges).
// R5: swapped-operand QK^T attention (S^T = mfma(K,Q)); LDS-free softmax.
// R7: gemm_bt 2-phase pipeline: double-buffered [2][128x64] LDS tiles, XOR
//     column swizzle both-sides (bank conflicts 2.97M -> 0, verified R8).
// R9: EPI_DELTA + add_ln_k kill the atomic residual epilogue (-75 us).
// R11: grouped block-order remap (G=4 supertiles): GG 102->77us, Mfma 10->26%.
// R12: 512-thread gemm_bt (8 waves, wave tile 64x32): total 1767->1703.
// R13: split-K tail matvecs (fout/poolq): total 1703->1581.
// R15: XCD-aware block remap in attn_k. R14 PMC: attn_k @69us, FETCH 75MB
//     vs ~43MB compulsory -> K/V re-fetch misses L2 (grid (17,64) scatters
//     each head's 17 row-blocks over all 8 XCDs; per-XCD KV working set
//     ~17MB >> 4MB L2). Remap: xcd = lin%8 owns 8 whole heads -> ~3.2MB/XCD.
//     Same T1 mechanism that fixed the GEMMs in R11.
// ---------------------------------------------------------------------------

#define DEV __device__ __forceinline__

typedef unsigned short u16;
typedef __attribute__((ext_vector_type(8))) __bf16 bf16x8;
typedef __attribute__((ext_vector_type(4))) float floatx4;

DEV u16 f2bf(float f) {
  union { float f; unsigned u; } v; v.f = f;
  return (u16)((v.u + 0x7fffu + ((v.u >> 16) & 1u)) >> 16);  // RNE
}
DEV float bf2f(u16 s) {
  union { unsigned u; float f; } v; v.u = ((unsigned)s) << 16;
  return v.f;
}

#define MFMA(a, b, c) __builtin_amdgcn_mfma_f32_16x16x32_bf16(a, b, c, 0, 0, 0)

DEV void gld16(const u16* g, u16* l) {
  __builtin_amdgcn_global_load_lds((__attribute__((address_space(1))) void*)g,
                                   (__attribute__((address_space(3))) void*)l,
                                   16, 0, 0);
}

// V^T column permutation: mfma k-slot (quad,e) holds logical kv
// pi(quad,e) = quad*4 + (e&3) + 16*(e>>2). sigma = pi^-1 maps kv offset j
// (within a 32 block) to its k-slot. Writing V[rb][d] at column
// (rb&~31)|sigma(rb&31) makes PV B-fragments contiguous b128 loads.
DEV int vperm32(int j) {
  return (((j >> 2) & 3) << 3) | (j & 3) | (((j >> 4) & 1) << 2);
}

// ---------------- constants ----------------
#define MREAL 4160   /* B*N = 4*1040 */
#define MPAD  4224   /* 33*128 */
#define NPAD  1056   /* 1040 padded to x32 */
#define FFP   2816   /* 2730 padded to x64 (split-K=2 -> 1408 = 22*64) */
#define FF2P  5632

// ---------------- weight conversion ----------------
// out[n*Kstride + k] = (k < Kin) ? bf16(in[k*N + n]) : 0    (B^T bf16 layout)
__global__ __launch_bounds__(256) void transpose_cvt(
    const float* __restrict__ in, u16* __restrict__ out,
    int Kin, int N, int Kstride) {
  __shared__ float tile[32][33];
  const int k0 = blockIdx.x * 32, n0 = blockIdx.y * 32;
  const int tx = threadIdx.x, ty = threadIdx.y;
#pragma unroll
  for (int i = 0; i < 4; i++) {
    int k = k0 + ty + i * 8;
    tile[ty + i * 8][tx] = (k < Kin) ? in[(int64_t)k * N + n0 + tx] : 0.f;
  }
  __syncthreads();
#pragma unroll
  for (int i = 0; i < 4; i++) {
    int n = n0 + ty + i * 8;
    int k = k0 + tx;
    if (k < Kstride) out[(int64_t)n * Kstride + k] = f2bf(tile[tx][ty + i * 8]);
  }
}

// ff_w1 [1024 x 5460] -> w1T [5632 x 1024] bf16 with val/gate 16-col interleave:
// out row r: vi = (r/32)*16 + r%16 ; gate if (r/16)&1 ; src col = gate? 2730+vi : vi
__global__ __launch_bounds__(256) void transpose_w1(
    const float* __restrict__ in, u16* __restrict__ out) {
  __shared__ float tile[32][33];
  const int k0 = blockIdx.x * 32;        // D dim
  const int r0 = blockIdx.y * 32;        // output-row dim
  const int tx = threadIdx.x, ty = threadIdx.y;
  const int vb = (r0 >> 5) << 4;         // = r0/2
  const int vi = vb + (tx & 15);
  const int c = (tx < 16) ? vi : 2730 + vi;
  const bool valid = vi < 2730;
#pragma unroll
  for (int i = 0; i < 4; i++) {
    int k = k0 + ty + i * 8;
    tile[ty + i * 8][tx] = valid ? in[(int64_t)k * 5460 + c] : 0.f;
  }
  __syncthreads();
#pragma unroll
  for (int i = 0; i < 4; i++) {
    int rl = ty + i * 8;
    out[(int64_t)(r0 + rl) * 1024 + k0 + tx] = f2bf(tile[tx][rl]);
  }
}

// ---------------- tokens assembly ----------------
__global__ __launch_bounds__(256) void build_tokens_k(
    const float* __restrict__ m0p, const float* __restrict__ m1p,
    const float* __restrict__ fus, float* __restrict__ tokens) {
  const int n = blockIdx.x, b = blockIdx.y, t = threadIdx.x;
  const float* src = (n < 512) ? m0p + ((int64_t)b * 512 + n) * 1024
                   : (n < 1024) ? m1p + ((int64_t)b * 512 + (n - 512)) * 1024
                                : fus + (int64_t)(n - 1024) * 1024;
  float4 v = ((const float4*)src)[t];
  ((float4*)(tokens + ((int64_t)b * 1040 + n) * 1024))[t] = v;
}

// ---------------- layernorm (f32 in, bf16 out) ----------------
__global__ __launch_bounds__(256) void ln_k(const float* __restrict__ x,
                                            const float* __restrict__ gamma,
                                            u16* __restrict__ out) {
  const int r = blockIdx.x, t = threadIdx.x;
  const float4 v = ((const float4*)(x + (int64_t)r * 1024))[t];
  float s = v.x + v.y + v.z + v.w;
  float q = v.x * v.x + v.y * v.y + v.z * v.z + v.w * v.w;
#pragma unroll
  for (int off = 32; off >= 1; off >>= 1) {
    s += __shfl_xor(s, off);
    q += __shfl_xor(q, off);
  }
  __shared__ float red[8];
  const int w = t >> 6, l = t & 63;
  if (l == 0) { red[w] = s; red[4 + w] = q; }
  __syncthreads();
  s = red[0] + red[1] + red[2] + red[3];
  q = red[4] + red[5] + red[6] + red[7];
  const float mu = s * (1.f / 1024.f);
  const float var = q * (1.f / 1024.f) - mu * mu;
  const float rs = rsqrtf(var + 1e-5f);
  const float4 g = ((const float4*)gamma)[t];
  u16* op = out + (int64_t)r * 1024 + t * 4;
  op[0] = f2bf((v.x - mu) * rs * g.x);
  op[1] = f2bf((v.y - mu) * rs * g.y);
  op[2] = f2bf((v.z - mu) * rs * g.z);
  op[3] = f2bf((v.w - mu) * rs * g.w);
}

// ---------------- fused residual-add + layernorm ----------------
// tokens += d0 (+ d1); optionally write tokens back; LN(tokens)*gamma -> out.
__global__ __launch_bounds__(256) void add_ln_k(
    float* __restrict__ x, const float* __restrict__ d0,
    const float* __restrict__ d1, const float* __restrict__ gamma,
    u16* __restrict__ out, int two, int writeback) {
  const int r = blockIdx.x, t = threadIdx.x;
  const int64_t off = (int64_t)r * 1024 + t * 4;
  float4 v = *(const float4*)(x + off);
  {
    const float4 a = *(const float4*)(d0 + off);
    v.x += a.x; v.y += a.y; v.z += a.z; v.w += a.w;
  }
  if (two) {
    const float4 a = *(const float4*)(d1 + off);
    v.x += a.x; v.y += a.y; v.z += a.z; v.w += a.w;
  }
  if (writeback) *(float4*)(x + off) = v;
  float s = v.x + v.y + v.z + v.w;
  float q = v.x * v.x + v.y * v.y + v.z * v.z + v.w * v.w;
#pragma unroll
  for (int off2 = 32; off2 >= 1; off2 >>= 1) {
    s += __shfl_xor(s, off2);
    q += __shfl_xor(q, off2);
  }
  __shared__ float red[8];
  const int w = t >> 6, l = t & 63;
  if (l == 0) { red[w] = s; red[4 + w] = q; }
  __syncthreads();
  s = red[0] + red[1] + red[2] + red[3];
  q = red[4] + red[5] + red[6] + red[7];
  const float mu = s * (1.f / 1024.f);
  const float var = q * (1.f / 1024.f) - mu * mu;
  const float rs = rsqrtf(var + 1e-5f);
  const float4 g = ((const float4*)gamma)[t];
  u16* op = out + (int64_t)r * 1024 + t * 4;
  op[0] = f2bf((v.x - mu) * rs * g.x);
  op[1] = f2bf((v.y - mu) * rs * g.y);
  op[2] = f2bf((v.z - mu) * rs * g.z);
  op[3] = f2bf((v.w - mu) * rs * g.w);
}

// ---------------- MFMA GEMM: C[M,N] = A[M,K](bf16) @ Bt[N,K](bf16) ----------------
enum { EPI_QKV = 0, EPI_KV = 1, EPI_TOKADD = 2, EPI_GG = 3, EPI_DELTA = 4 };

// 512 threads = 8 waves (2M x 4N), wave tile 64x32, acc[4][2].
// Kstr = row stride of A and Bt; per-z K-range = Kstr / gridDim.z (mult of 64).
// 2-phase pipeline: LDS tiles [2][128 rows][64 cols] per operand (64 KiB);
// next K-tile staged via global_load_lds BEFORE the current tile's
// ds_read+MFMA, one __syncthreads per K-step (drains vmcnt+lgkm).
// LDS col swizzle: 16B-column qphys = qlog ^ (row&7), applied by pre-swizzling
// the GLOBAL source column (LDS dest stays wave-linear) and on the read side.
// Grouped block-order remap: linear wg id -> (bx,by) in supertiles of G=4
// B-panels x all M-rows (per-XCD L2 working-set fit).
template <int EPI>
__global__ __launch_bounds__(512) void gemm_bt(
    const u16* __restrict__ A, const u16* __restrict__ Bt,
    int Kstr, int Mreal,
    float* __restrict__ tokens, u16* __restrict__ oq, u16* __restrict__ ok,
    u16* __restrict__ ovT, u16* __restrict__ oh2) {
  __shared__ __align__(16) u16 lA[2][128 * 64];
  __shared__ __align__(16) u16 lB[2][128 * 64];
  const int t = threadIdx.x;
  const int w = t >> 6, l = t & 63;
  const int lane16 = l & 15, quad = l >> 4;

  // ---- grouped block-order remap (bijective) ----
  const int nbx = gridDim.x, nby = gridDim.y;
  const int lin = blockIdx.y * nbx + blockIdx.x;
  const int ngf = nbx >> 2;            // full groups of G=4
  const int base = ngf * 4 * nby;
  int bx, by;
  if (lin < base) {
    const int g = lin / (nby * 4);
    const int r = lin - g * nby * 4;
    bx = (g << 2) + (r & 3);
    by = r >> 2;
  } else {  // tail group (nbx % 4 != 0) — unused for our shapes, kept safe
    const int W = nbx - (ngf << 2);
    const int r = lin - base;
    bx = (ngf << 2) + r % W;
    by = r / W;
  }
  const int m0 = by * 128, n0 = bx * 128;
  const int wm = (w >> 2) * 64, wn = (w & 3) * 32;  // wave tile 64x32

  const int Klen = Kstr / gridDim.z;
  const int koff = blockIdx.z * Klen;

  const floatx4 fz = {0.f, 0.f, 0.f, 0.f};
  floatx4 acc[4][2];
#pragma unroll
  for (int i = 0; i < 4; i++)
#pragma unroll
    for (int j = 0; j < 2; j++) acc[i][j] = fz;

  // Staging (512 thr): thread t -> rows rowS=t>>3 and rowS+64, 16B col (t&7),
  // pre-swizzled source col so lds[row][q] = A[row][ (q ^ (row&7))*8 .. +7 ]
  // ((row+64)&7 == row&7, so one scol serves both rows).
  const int rowS = t >> 3;
  const int scol = (((t & 7) ^ (rowS & 7)) << 3);
  const u16* gAs = A + (int64_t)(m0 + rowS) * Kstr + koff + scol;
  const u16* gBs = Bt + (int64_t)(n0 + rowS) * Kstr + koff + scol;
  const int64_t rsk64 = (int64_t)64 * Kstr;

  // Fragment-read swizzled 16B-column offsets (elements):
  const int rsw = lane16 & 7;
  const int cp0 = ((quad ^ rsw) << 3);        // k-substep 0 (k = quad*8)
  const int cp1 = (((quad + 4) ^ rsw) << 3);  // k-substep 1 (k = 32 + quad*8)

  auto stage = [&](int buf, int kt) {
    const u16* ga = gAs + kt;
    const u16* gb = gBs + kt;
    u16* la = &lA[buf][0] + t * 8;
    u16* lb = &lB[buf][0] + t * 8;
    gld16(ga, la);
    gld16(ga + rsk64, la + 4096);
    gld16(gb, lb);
    gld16(gb + rsk64, lb + 4096);
  };

  stage(0, 0);
  __syncthreads();
  int cur = 0;
  for (int kt = 0; kt < Klen; kt += 64) {
    if (kt + 64 < Klen) stage(cur ^ 1, kt + 64);
    const u16* la = &lA[cur][0] + (wm + lane16) * 64;
    const u16* lb = &lB[cur][0] + (wn + lane16) * 64;
    bf16x8 af[4], bf[2];
#pragma unroll
    for (int i = 0; i < 4; i++) af[i] = *(const bf16x8*)(la + i * 16 * 64 + cp0);
#pragma unroll
    for (int j = 0; j < 2; j++) bf[j] = *(const bf16x8*)(lb + j * 16 * 64 + cp0);
#pragma unroll
    for (int i = 0; i < 4; i++)
#pragma unroll
      for (int j = 0; j < 2; j++) acc[i][j] = MFMA(af[i], bf[j], acc[i][j]);
#pragma unroll
    for (int i = 0; i < 4; i++) af[i] = *(const bf16x8*)(la + i * 16 * 64 + cp1);
#pragma unroll
    for (int j = 0; j < 2; j++) bf[j] = *(const bf16x8*)(lb + j * 16 * 64 + cp1);
#pragma unroll
    for (int i = 0; i < 4; i++)
#pragma unroll
      for (int j = 0; j < 2; j++) acc[i][j] = MFMA(af[i], bf[j], acc[i][j]);
    __syncthreads();
    cur ^= 1;
  }

  // Epilogues. C-layout: lane holds row = quad*4+reg, col = lane16 within frag.
  if constexpr (EPI == EPI_TOKADD) {
    const bool atomic = gridDim.z > 1;
#pragma unroll
    for (int i = 0; i < 4; i++) {
      const int mb = m0 + wm + i * 16 + quad * 4;
#pragma unroll
      for (int reg = 0; reg < 4; reg++) {
        const int m = mb + reg;
        if (m < Mreal) {
          float* tp = tokens + (int64_t)m * 1024;
#pragma unroll
          for (int j = 0; j < 2; j++) {
            const int n = n0 + wn + j * 16 + lane16;
            if (atomic) atomicAdd(tp + n, acc[i][j][reg]);
            else tp[n] += acc[i][j][reg];
          }
        }
      }
    }
  } else if constexpr (EPI == EPI_DELTA) {
    // Plain f32 partial-sum store into per-z delta buffer (no atomics).
    float* dp = tokens + (int64_t)blockIdx.z * MREAL * 1024;
#pragma unroll
    for (int i = 0; i < 4; i++) {
      const int mb = m0 + wm + i * 16 + quad * 4;
#pragma unroll
      for (int reg = 0; reg < 4; reg++) {
        const int m = mb + reg;
        if (m < Mreal) {
          float* tp = dp + (int64_t)m * 1024;
#pragma unroll
          for (int j = 0; j < 2; j++) {
            const int n = n0 + wn + j * 16 + lane16;
            tp[n] = acc[i][j][reg];
          }
        }
      }
    }
  } else if constexpr (EPI == EPI_QKV) {
    // cols [0,1024): Q (scaled), [1024,2048): K, [2048,3072): V^T (permuted cols)
#pragma unroll
    for (int i = 0; i < 4; i++) {
      const int mb = m0 + wm + i * 16 + quad * 4;
#pragma unroll
      for (int reg = 0; reg < 4; reg++) {
        const int m = mb + reg;
        if (m < Mreal) {
          const int b = m / 1040, rb = m % 1040;
          const int rbp = (rb & ~31) | vperm32(rb & 31);
#pragma unroll
          for (int j = 0; j < 2; j++) {
            const int n = n0 + wn + j * 16 + lane16;
            const float v = acc[i][j][reg];
            if (n < 1024) {
              const int hd = n >> 6, d = n & 63;
              oq[(((int64_t)b * 16 + hd) * NPAD + rb) * 64 + d] = f2bf(v * 0.125f);
            } else if (n < 2048) {
              const int n2 = n - 1024;
              const int hd = n2 >> 6, d = n2 & 63;
              ok[(((int64_t)b * 16 + hd) * NPAD + rb) * 64 + d] = f2bf(v);
            } else {
              const int n2 = n - 2048;
              const int hd = n2 >> 6, d = n2 & 63;
              ovT[(((int64_t)b * 16 + hd) * 64 + d) * NPAD + rbp] = f2bf(v);
            }
          }
        }
      }
    }
  } else if constexpr (EPI == EPI_KV) {
#pragma unroll
    for (int i = 0; i < 4; i++) {
      const int mb = m0 + wm + i * 16 + quad * 4;
#pragma unroll
      for (int reg = 0; reg < 4; reg++) {
        const int m = mb + reg;
        if (m < Mreal) {
          const int b = m / 1040, rb = m % 1040;
          const int rbp = (rb & ~31) | vperm32(rb & 31);
#pragma unroll
          for (int j = 0; j < 2; j++) {
            const int n = n0 + wn + j * 16 + lane16;
            const float v = acc[i][j][reg];
            if (n < 1024) {
              const int hd = n >> 6, d = n & 63;
              ok[(((int64_t)b * 16 + hd) * NPAD + rb) * 64 + d] = f2bf(v);
            } else {
              const int n2 = n - 1024;
              const int hd = n2 >> 6, d = n2 & 63;
              ovT[(((int64_t)b * 16 + hd) * 64 + d) * NPAD + rbp] = f2bf(v);
            }
          }
        }
      }
    }
  } else {  // EPI_GG: cols are (val,gate) alternating 16-groups; wave tile has
            // exactly one (val,gate) pair: j=0 val, j=1 gate (wn multiple of 32)
#pragma unroll
    for (int i = 0; i < 4; i++) {
      const int mb = m0 + wm + i * 16 + quad * 4;
#pragma unroll
      for (int reg = 0; reg < 4; reg++) {
        const int m = mb + reg;
        u16* hp = oh2 + (int64_t)m * FFP;
        const float val = acc[i][0][reg];
        const float g = acc[i][1][reg];
        const float ge = 0.5f * g * (1.f + erff(g * 0.70710678118654752f));
        const int vi = (((n0 + wn) >> 5) << 4) + lane16;
        hp[vi] = f2bf(val * ge);
      }
    }
  }
}

// ---------------- block-mask flash attention (swapped QK^T, LDS-free) -------
// S^T = mfma(K, Q): lane (quad,lane16) holds S[kv = c0 + {quad*4+r, 16+quad*4+r}]
// [q = lane16]. Row stats are per-lane; reduce = in-lane tree + shfl_xor(16,32).
// P -> PV A-fragment is a pure register repack (k-slot (quad,e) <-> kv
// pi(quad,e) = quad*4+(e&3)+16*(e>>2)); V^T is stored with sigma=pi^-1
// permuted columns so B-fragments are contiguous b128 loads.
// R15: XCD-aware 1-D grid (1088 blocks): xcd = lin%8 owns heads
// [xcd*8, xcd*8+8) -> per-XCD K/V working set ~2.1MB fits 4MB L2.
__global__ __launch_bounds__(256) void attn_k(const u16* __restrict__ qb,
                                              const u16* __restrict__ kb,
                                              const u16* __restrict__ vTb,
                                              u16* __restrict__ ao) {
  const int t = threadIdx.x, w = t >> 6, l = t & 63;
  const int lane16 = l & 15, quad = l >> 4;
  const int kvb = quad * 4;
  const int lin = blockIdx.x;          // 1088 = 8 xcd * 8 heads * 17 rowblocks
  const int xcd = lin & 7;
  const int idx = lin >> 3;            // [0,136)
  const int bh = xcd * 8 + idx / 17;   // [0,64)
  const int rbb = idx % 17;            // [0,17)
  const int b = bh >> 4, h = bh & 15;
  const int row0 = rbb * 64 + w * 16;
  if (row0 >= 1040) return;
  const int type = (row0 < 512) ? 0 : (row0 < 1024 ? 1 : 2);
  const int cbeg = (type == 1) ? 512 : 0;
  const int cend = (type == 0) ? 512 : (type == 1 ? 1024 : 1040);
  const int niter = (cend - cbeg + 31) >> 5;

  const u16* qp = qb + ((int64_t)bh * NPAD + row0 + lane16) * 64 + quad * 8;
  const bf16x8 a0 = *(const bf16x8*)qp;
  const bf16x8 a1 = *(const bf16x8*)(qp + 32);
  const u16* vbase = vTb + ((int64_t)bh * 64 + lane16) * NPAD + quad * 8;

  const floatx4 fz = {0.f, 0.f, 0.f, 0.f};
  floatx4 O[4] = {fz, fz, fz, fz};
  float mrow = -1e30f, lrow = 0.f;

  for (int it = 0; it < niter; ++it) {
    const int c0 = cbeg + it * 32;
    const u16* kp = kb + ((int64_t)bh * NPAD + c0 + lane16) * 64 + quad * 8;
    const bf16x8 b00 = *(const bf16x8*)kp;
    const bf16x8 b01 = *(const bf16x8*)(kp + 32);
    const bf16x8 b10 = *(const bf16x8*)(kp + 16 * 64);
    const bf16x8 b11 = *(const bf16x8*)(kp + 16 * 64 + 32);
    floatx4 s0 = MFMA(b00, a0, fz); s0 = MFMA(b01, a1, s0);
    floatx4 s1 = MFMA(b10, a0, fz); s1 = MFMA(b11, a1, s1);
    if (c0 + 32 > cend) {  // fusion tail mask (kv >= cend)
#pragma unroll
      for (int r = 0; r < 4; r++) {
        if (c0 + kvb + r >= cend) s0[r] = -1e30f;
        if (c0 + 16 + kvb + r >= cend) s1[r] = -1e30f;
      }
    }
    float tm = fmaxf(fmaxf(fmaxf(s0[0], s0[1]), fmaxf(s0[2], s0[3])),
                     fmaxf(fmaxf(s1[0], s1[1]), fmaxf(s1[2], s1[3])));
    tm = fmaxf(tm, __shfl_xor(tm, 16));
    tm = fmaxf(tm, __shfl_xor(tm, 32));
    if (!__all(tm <= mrow)) {  // exact skip: when taken-not, a_ == 1 exactly
      const float mn = fmaxf(mrow, tm);
      const float a_ = __expf(mrow - mn);
      mrow = mn;
      lrow *= a_;
      const float al0 = __shfl(a_, kvb + 0, 16);
      const float al1 = __shfl(a_, kvb + 1, 16);
      const float al2 = __shfl(a_, kvb + 2, 16);
      const float al3 = __shfl(a_, kvb + 3, 16);
#pragma unroll
      for (int dt = 0; dt < 4; dt++) {
        O[dt][0] *= al0; O[dt][1] *= al1; O[dt][2] *= al2; O[dt][3] *= al3;
      }
    }
    float p0[4], p1[4];
#pragma unroll
    for (int r = 0; r < 4; r++) {
      p0[r] = __expf(s0[r] - mrow);
      p1[r] = __expf(s1[r] - mrow);
    }
    float ps = ((p0[0] + p0[1]) + (p0[2] + p0[3])) +
               ((p1[0] + p1[1]) + (p1[2] + p1[3]));
    ps += __shfl_xor(ps, 16);
    ps += __shfl_xor(ps, 32);
    lrow += ps;
    union { bf16x8 v; u16 s[8]; } pf;
#pragma unroll
    for (int r = 0; r < 4; r++) {
      pf.s[r] = f2bf(p0[r]);
      pf.s[4 + r] = f2bf(p1[r]);
    }
#pragma unroll
    for (int dt = 0; dt < 4; dt++) {
      const bf16x8 bv = *(const bf16x8*)(vbase + (int64_t)dt * 16 * NPAD + c0);
      O[dt] = MFMA(pf.v, bv, O[dt]);
    }
  }
  float lr[4];
#pragma unroll
  for (int r = 0; r < 4; r++) lr[r] = __shfl(lrow, kvb + r, 16);
#pragma unroll
  for (int dt = 0; dt < 4; dt++)
#pragma unroll
    for (int r = 0; r < 4; r++) {
      const int row = row0 + kvb + r;
      ao[((int64_t)b * 1040 + row) * 1024 + h * 64 + dt * 16 + lane16] =
          f2bf(O[dt][r] / lr[r]);
    }
}

// ---------------- pool q, split-K: qpart[kz][r][n] = partial dot ----------------
__global__ __launch_bounds__(256) void poolq_split_k(
    const float* __restrict__ rtk, const float* __restrict__ pwq,
    float* __restrict__ qpart) {
  const int n = blockIdx.x * 256 + threadIdx.x;  // 4 blocks
  const int r = blockIdx.y;                      // 4 real rows
  const int kz = blockIdx.z;                     // 8 K-slices of 128
  const float* x = rtk + (int64_t)r * 1024 + kz * 128;
  const float* wp = pwq + (int64_t)(kz * 128) * 1024 + n;
  float acc = 0.f;
#pragma unroll 8
  for (int k = 0; k < 128; k++) acc += x[k] * wp[(int64_t)k * 1024];
  qpart[((int64_t)kz * 4 + r) * 1024 + n] = acc;
}

// qP rows 4..15 are zeroed (pool_attn pads q-rows to 16; keeps garbage out of
// the wave-uniform defer-max branch).
__global__ __launch_bounds__(256) void poolq_reduce_k(
    const float* __restrict__ qpart, u16* __restrict__ qP) {
  const int n = blockIdx.x * 256 + threadIdx.x;
  const int r = blockIdx.y;  // 16
  if (r >= 4) { qP[(int64_t)r * 1024 + n] = 0; return; }
  float acc = 0.f;
#pragma unroll
  for (int kz = 0; kz < 8; kz++) acc += qpart[((int64_t)kz * 4 + r) * 1024 + n];
  qP[(int64_t)r * 1024 + n] = f2bf(acc * 0.125f);
}

// ---------------- pool attention: 1 wave per (b,h), 4 real q-rows ----------------
DEV bool pvalid(int r, int c) {
  if (r == 0) return c < 512;
  if (r == 1) return (c >= 512) && (c < 1024);
  if (r == 2) return (c >= 1024) && (c < 1040);
  return c < 1040;  // GLOBAL row + pad rows
}

__global__ __launch_bounds__(64) void pool_attn_k(const u16* __restrict__ qP,
                                                  const u16* __restrict__ kb,
                                                  const u16* __restrict__ vTb,
                                                  u16* __restrict__ po) {
  const int l = threadIdx.x;
  const int lane16 = l & 15, quad = l >> 4;
  const int kvb = quad * 4;
  const int bh = blockIdx.x, b = bh >> 4, h = bh & 15;
  const u16* qp = qP + (int64_t)lane16 * 1024 + h * 64 + quad * 8;
  const bf16x8 a0 = *(const bf16x8*)qp;
  const bf16x8 a1 = *(const bf16x8*)(qp + 32);
  const u16* vbase = vTb + ((int64_t)bh * 64 + lane16) * NPAD + quad * 8;
  const floatx4 fz = {0.f, 0.f, 0.f, 0.f};
  floatx4 O[4] = {fz, fz, fz, fz};
  float mrow = -1e30f, lrow = 0.f;
  for (int it = 0; it < 33; ++it) {
    const int c0 = it * 32;
    const u16* kp = kb + ((int64_t)bh * NPAD + c0 + lane16) * 64 + quad * 8;
    const bf16x8 b00 = *(const bf16x8*)kp;
    const bf16x8 b01 = *(const bf16x8*)(kp + 32);
    const bf16x8 b10 = *(const bf16x8*)(kp + 16 * 64);
    const bf16x8 b11 = *(const bf16x8*)(kp + 16 * 64 + 32);
    floatx4 s0 = MFMA(b00, a0, fz); s0 = MFMA(b01, a1, s0);
    floatx4 s1 = MFMA(b10, a0, fz); s1 = MFMA(b11, a1, s1);
#pragma unroll
    for (int r = 0; r < 4; r++) {
      if (!pvalid(lane16, c0 + kvb + r)) s0[r] = -1e30f;
      if (!pvalid(lane16, c0 + 16 + kvb + r)) s1[r] = -1e30f;
    }
    float tm = fmaxf(fmaxf(fmaxf(s0[0], s0[1]), fmaxf(s0[2], s0[3])),
                     fmaxf(fmaxf(s1[0], s1[1]), fmaxf(s1[2], s1[3])));
    tm = fmaxf(tm, __shfl_xor(tm, 16));
    tm = fmaxf(tm, __shfl_xor(tm, 32));
    if (!__all(tm <= mrow)) {
      const float mn = fmaxf(mrow, tm);
      const float a_ = __expf(mrow - mn);
      mrow = mn;
      lrow *= a_;
      const float al0 = __shfl(a_, kvb + 0, 16);
      const float al1 = __shfl(a_, kvb + 1, 16);
      const float al2 = __shfl(a_, kvb + 2, 16);
      const float al3 = __shfl(a_, kvb + 3, 16);
#pragma unroll
      for (int dt = 0; dt < 4; dt++) {
        O[dt][0] *= al0; O[dt][1] *= al1; O[dt][2] *= al2; O[dt][3] *= al3;
      }
    }
    float p0[4], p1[4];
#pragma unroll
    for (int r = 0; r < 4; r++) {
      p0[r] = __expf(s0[r] - mrow);
      p1[r] = __expf(s1[r] - mrow);
    }
    float ps = ((p0[0] + p0[1]) + (p0[2] + p0[3])) +
               ((p1[0] + p1[1]) + (p1[2] + p1[3]));
    ps += __shfl_xor(ps, 16);
    ps += __shfl_xor(ps, 32);
    lrow += ps;
    union { bf16x8 v; u16 s[8]; } pf;
#pragma unroll
    for (int r = 0; r < 4; r++) {
      pf.s[r] = f2bf(p0[r]);
      pf.s[4 + r] = f2bf(p1[r]);
    }
#pragma unroll
    for (int dt = 0; dt < 4; dt++) {
      const bf16x8 bv = *(const bf16x8*)(vbase + (int64_t)dt * 16 * NPAD + c0);
      O[dt] = MFMA(pf.v, bv, O[dt]);
    }
  }
  float lr[4];
#pragma unroll
  for (int r = 0; r < 4; r++) lr[r] = __shfl(lrow, r, 16);
  if (quad == 0) {  // output C rows quad*4+reg -> quad0 holds real rows 0..3
#pragma unroll
    for (int dt = 0; dt < 4; dt++)
#pragma unroll
      for (int r = 0; r < 4; r++)
        po[((int64_t)b * 4 + r) * 1024 + h * 64 + dt * 16 + lane16] =
            f2bf(O[dt][r] / lr[r]);
  }
}

// ---------------- final matvec, split-K: fpart[kz][row][n] ----------------
__global__ __launch_bounds__(256) void fout_split_k(
    const u16* __restrict__ po, const float* __restrict__ pwo,
    float* __restrict__ fpart) {
  const int n = blockIdx.x * 256 + threadIdx.x;  // 4 blocks
  const int row = blockIdx.y;                    // 16 (b*4 + r)
  const int kz = blockIdx.z;                     // 8 K-slices of 128
  const u16* x = po + (int64_t)row * 1024 + kz * 128;
  const float* wp = pwo + (int64_t)(kz * 128) * 1024 + n;
  float acc = 0.f;
#pragma unroll 8
  for (int k = 0; k < 128; k++) acc += bf2f(x[k]) * wp[(int64_t)k * 1024];
  fpart[((int64_t)kz * 16 + row) * 1024 + n] = acc;
}

__global__ __launch_bounds__(256) void fout_reduce_k(
    const float* __restrict__ fpart, const float* __restrict__ rtk,
    float* __restrict__ out) {
  const int n = blockIdx.x * 256 + threadIdx.x;
  const int row = blockIdx.y;  // 16
  float acc = rtk[(int64_t)(row & 3) * 1024 + n];
#pragma unroll
  for (int kz = 0; kz < 8; kz++)
    acc += fpart[((int64_t)kz * 16 + row) * 1024 + n];
  out[(int64_t)row * 1024 + n] = acc;
}

// ---------------------------------------------------------------------------
extern "C" void kernel_launch(void* const* d_in, const int* in_sizes, int n_in,
                              void* d_out, int out_size, void* d_ws, size_t ws_size,
                              hipStream_t stream) {
  (void)in_sizes; (void)n_in; (void)out_size;
  const float* m0p  = (const float*)d_in[0];
  const float* m1p  = (const float*)d_in[1];
  const float* fus  = (const float*)d_in[2];
  const float* rtk  = (const float*)d_in[3];
  const float* lng  = (const float*)d_in[4];
  const float* wq   = (const float*)d_in[5];
  const float* wkv  = (const float*)d_in[6];
  const float* wo   = (const float*)d_in[7];
  const float* w1   = (const float*)d_in[8];
  const float* w2   = (const float*)d_in[9];
  const float* pwq  = (const float*)d_in[10];
  const float* pwkv = (const float*)d_in[11];
  const float* pwo  = (const float*)d_in[12];
  const float* fg   = (const float*)d_in[13];
  float* out = (float*)d_out;

  char* p = (char*)d_ws;
  auto alloc = [&](size_t bytes) -> char* {
    char* r = p;
    p += (bytes + 255) & ~(size_t)255;
    return r;
  };
  // Base footprint ~64 MB.
  u16* warena = (u16*)alloc((size_t)FF2P * 1024 * 2);       // 11.5 MB, per-GEMM weights
  float* tokens = (float*)alloc((size_t)MREAL * 1024 * 4);  // 17.04 MB
  u16* hbuf  = (u16*)alloc((size_t)MPAD * 1024 * 2);        // 8.65 MB (LN out + attn out)
  u16* qb    = (u16*)alloc((size_t)64 * NPAD * 64 * 2);     // 8.65 MB
  u16* kbuf  = (u16*)alloc((size_t)64 * NPAD * 64 * 2);     // 8.65 MB
  u16* vTbuf = (u16*)alloc((size_t)64 * NPAD * 64 * 2);     // 8.65 MB
  u16* h2buf = qb;  // 23.8 MB alias over qb+kbuf+vTbuf (25.95 MB): dead between
                    // attn read and next layer's Q/KV writes; stale k/vT tail
                    // rows [1040,1056) are masked (-1e30) / multiplied by p=0.
  u16* qP    = (u16*)alloc((size_t)16 * 1024 * 2);
  u16* poolO = (u16*)alloc((size_t)16 * 1024 * 2);
  float* qpart = (float*)alloc((size_t)8 * 4 * 1024 * 4);   // 128 KB
  float* fpart = (float*)alloc((size_t)8 * 16 * 1024 * 4);  // 512 KB

  // Residual-delta buffers (mode 2: two z-slices; mode 1: one; mode 0: legacy
  // atomic path). Chosen by available workspace — no risk if ws is tight.
  const size_t DELTA_BYTES = (size_t)MREAL * 1024 * 4;  // 17.04 MB
  const size_t base_used = (size_t)(p - (char*)d_ws);
  int mode = 0;
  float* d0 = nullptr;
  float* d1 = nullptr;
  if (ws_size >= base_used + 2 * DELTA_BYTES + 1024) {
    mode = 2;
    d0 = (float*)alloc(2 * DELTA_BYTES);
    d1 = d0 + (size_t)MREAL * 1024;  // contiguous: blockIdx.z indexes it
  } else if (ws_size >= base_used + DELTA_BYTES + 1024) {
    mode = 1;
    d0 = (float*)alloc(DELTA_BYTES);
    d1 = d0;  // unused (two=0)
  }

  const dim3 tb(32, 8, 1);
  build_tokens_k<<<dim3(1040, 4), 256, 0, stream>>>(m0p, m1p, fus, tokens);

  if (mode) {
    const int zz = mode;  // split-K factor for residual GEMMs
    const int two = (mode == 2);
    for (int lyr = 0; lyr < 4; ++lyr) {
      if (lyr == 0)
        ln_k<<<MREAL, 256, 0, stream>>>(tokens, lng, hbuf);
      else  // fold previous layer's FF2 delta into tokens + this pre-attn LN
        add_ln_k<<<MREAL, 256, 0, stream>>>(tokens, d0, d1, lng + lyr * 1024,
                                            hbuf, two, 1);
      transpose_cvt<<<dim3(32, 32), tb, 0, stream>>>(
          wq + (int64_t)lyr * 1024 * 1024, warena, 1024, 1024, 1024);
      transpose_cvt<<<dim3(32, 64), tb, 0, stream>>>(
          wkv + (int64_t)lyr * 1024 * 2048, warena + (size_t)1024 * 1024, 1024, 2048, 1024);
      gemm_bt<EPI_QKV><<<dim3(24, 33), 512, 0, stream>>>(
          hbuf, warena, 1024, MREAL, nullptr, qb, kbuf, vTbuf, nullptr);
      attn_k<<<dim3(1088), 256, 0, stream>>>(qb, kbuf, vTbuf, hbuf);
      transpose_cvt<<<dim3(32, 32), tb, 0, stream>>>(
          wo + (int64_t)lyr * 1024 * 1024, warena, 1024, 1024, 1024);
      gemm_bt<EPI_DELTA><<<dim3(8, 33, zz), 512, 0, stream>>>(
          hbuf, warena, 1024, MREAL, d0, nullptr, nullptr, nullptr, nullptr);
      add_ln_k<<<MREAL, 256, 0, stream>>>(tokens, d0, d1, lng + lyr * 1024,
                                          hbuf, two, 1);
      transpose_w1<<<dim3(32, FF2P / 32), tb, 0, stream>>>(
          w1 + (int64_t)lyr * 1024 * 5460, warena);
      gemm_bt<EPI_GG><<<dim3(FF2P / 128, 33), 512, 0, stream>>>(
          hbuf, warena, 1024, MREAL, nullptr, nullptr, nullptr, nullptr, h2buf);
      transpose_cvt<<<dim3(FFP / 32, 32), tb, 0, stream>>>(
          w2 + (int64_t)lyr * 2730 * 1024, warena, 2730, 1024, FFP);
      gemm_bt<EPI_DELTA><<<dim3(8, 33, zz), 512, 0, stream>>>(
          h2buf, warena, FFP, MREAL, d0, nullptr, nullptr, nullptr, nullptr);
    }
    // final: fold last FF2 delta + final LN (tokens dead after -> no writeback)
    add_ln_k<<<MREAL, 256, 0, stream>>>(tokens, d0, d1, fg, hbuf, two, 0);
  } else {
    for (int lyr = 0; lyr < 4; ++lyr) {
      ln_k<<<MREAL, 256, 0, stream>>>(tokens, lng + lyr * 1024, hbuf);
      transpose_cvt<<<dim3(32, 32), tb, 0, stream>>>(
          wq + (int64_t)lyr * 1024 * 1024, warena, 1024, 1024, 1024);
      transpose_cvt<<<dim3(32, 64), tb, 0, stream>>>(
          wkv + (int64_t)lyr * 1024 * 2048, warena + (size_t)1024 * 1024, 1024, 2048, 1024);
      gemm_bt<EPI_QKV><<<dim3(24, 33), 512, 0, stream>>>(
          hbuf, warena, 1024, MREAL, nullptr, qb, kbuf, vTbuf, nullptr);
      attn_k<<<dim3(1088), 256, 0, stream>>>(qb, kbuf, vTbuf, hbuf);
      transpose_cvt<<<dim3(32, 32), tb, 0, stream>>>(
          wo + (int64_t)lyr * 1024 * 1024, warena, 1024, 1024, 1024);
      gemm_bt<EPI_TOKADD><<<dim3(8, 33, 2), 512, 0, stream>>>(
          hbuf, warena, 1024, MREAL, tokens, nullptr, nullptr, nullptr, nullptr);
      ln_k<<<MREAL, 256, 0, stream>>>(tokens, lng + lyr * 1024, hbuf);
      transpose_w1<<<dim3(32, FF2P / 32), tb, 0, stream>>>(
          w1 + (int64_t)lyr * 1024 * 5460, warena);
      gemm_bt<EPI_GG><<<dim3(FF2P / 128, 33), 512, 0, stream>>>(
          hbuf, warena, 1024, MREAL, nullptr, nullptr, nullptr, nullptr, h2buf);
      transpose_cvt<<<dim3(FFP / 32, 32), tb, 0, stream>>>(
          w2 + (int64_t)lyr * 2730 * 1024, warena, 2730, 1024, FFP);
      gemm_bt<EPI_TOKADD><<<dim3(8, 33, 2), 512, 0, stream>>>(
          h2buf, warena, FFP, MREAL, tokens, nullptr, nullptr, nullptr, nullptr);
    }
    ln_k<<<MREAL, 256, 0, stream>>>(tokens, fg, hbuf);
  }

  transpose_cvt<<<dim3(32, 64), tb, 0, stream>>>(pwkv, warena, 1024, 2048, 1024);
  gemm_bt<EPI_KV><<<dim3(16, 33), 512, 0, stream>>>(
      hbuf, warena, 1024, MREAL, nullptr, nullptr, kbuf, vTbuf, nullptr);
  poolq_split_k<<<dim3(4, 4, 8), 256, 0, stream>>>(rtk, pwq, qpart);
  poolq_reduce_k<<<dim3(4, 16), 256, 0, stream>>>(qpart, qP);
  pool_attn_k<<<64, 64, 0, stream>>>(qP, kbuf, vTbuf, poolO);
  fout_split_k<<<dim3(4, 16, 8), 256, 0, stream>>>(poolO, pwo, fpart);
  fout_reduce_k<<<dim3(4, 16), 256, 0, stream>>>(fpart, rtk, out);
}